// Round 2
// baseline (1432.314 us; speedup 1.0000x reference)
//
#include <hip/hip_runtime.h>
#include <math.h>

// Problem constants
static constexpr int BB   = 256;   // batch
static constexpr int NN   = 128;   // nodes
static constexpr int LL   = 2048;  // protein length
static constexpr int NF   = 75;
static constexpr int AC   = 3;
static constexpr int HID  = 256;
static constexpr int DIM  = 128;
static constexpr int NHEAD= 8;
static constexpr int FPD  = 679;
static constexpr int NWORD= 8600;

// ---------------------------------------------------------------------------
// fp chain: FP1 = relu(fp @ W1 + b1); FP2 = relu(FP1 @ W2 + b2)
// grid: (B), block: 128
__global__ __launch_bounds__(128)
void fp_kernel(const float* __restrict__ fp,
               const float* __restrict__ W1, const float* __restrict__ b1,
               const float* __restrict__ W2, const float* __restrict__ b2,
               float* __restrict__ FP2)
{
    int b = blockIdx.x, t = threadIdx.x;
    __shared__ float s_fp[FPD];
    __shared__ float s_fp1[DIM];
    for (int i = t; i < FPD; i += 128) s_fp[i] = fp[(size_t)b * FPD + i];
    __syncthreads();
    float acc = 0.f;
    for (int k = 0; k < FPD; ++k) acc += s_fp[k] * W1[k * DIM + t];
    s_fp1[t] = fmaxf(acc + b1[t], 0.f);
    __syncthreads();
    float acc2 = 0.f;
    for (int k = 0; k < DIM; ++k) acc2 += s_fp1[k] * W2[k * DIM + t];
    FP2[(size_t)b * DIM + t] = fmaxf(acc2 + b2[t], 0.f);
}

// ---------------------------------------------------------------------------
// HS tables: HS[t][d] = relu(emb[t] @ W + b), per branch.
// grid: (NWORD/2, 2), block: 256 (2 rows x 128)
__global__ __launch_bounds__(256)
void hs_kernel(const float* __restrict__ emb,
               const float* __restrict__ Wa, const float* __restrict__ ba,
               const float* __restrict__ Wb, const float* __restrict__ bb_,
               float* __restrict__ HS1, float* __restrict__ HS2)
{
    int br = blockIdx.y;
    const float* W  = br ? Wb : Wa;
    const float* bi = br ? bb_ : ba;
    float* HS = br ? HS2 : HS1;
    int half = threadIdx.x >> 7;          // 0..1
    int d = threadIdx.x & 127;
    int r = blockIdx.x * 2 + half;
    __shared__ float se[2][DIM];
    se[half][d] = emb[(size_t)r * DIM + d];
    __syncthreads();
    const float* er = se[half];
    float acc = 0.f;
    for (int k = 0; k < DIM; ++k) acc += er[k] * W[k * DIM + d];
    HS[(size_t)r * DIM + d] = fmaxf(acc + bi[d], 0.f);
}

// ---------------------------------------------------------------------------
// GConv step A: AV[b,c][n][f] = sum_m A[b,c][n][m] * H[b][m][f]
// Generic GEMM M=128 (n), K=128 (m), N=F (f). 64x64 tile, 4x4 micro.
// grid: (tM*tN, AC, CB), block: 256
__global__ __launch_bounds__(256)
void gA_kernel(const float* __restrict__ Abase,
               const float* __restrict__ Bbase,
               float* __restrict__ Cbase,
               int F, int b0, int tN)
{
    int tm = blockIdx.x / tN, tn = blockIdx.x % tN;
    int c = blockIdx.y, bl = blockIdx.z;
    int bbg = b0 + bl;
    const float* Ap = Abase + ((size_t)(bbg * AC + c)) * (NN * NN);
    const float* Bp = Bbase + (size_t)bbg * NN * F;
    float* Cp = Cbase + ((size_t)(bl * AC + c)) * NN * F;
    int m0 = tm * 64, n0 = tn * 64;

    __shared__ float As[16][64];
    __shared__ float Bs[16][64];

    int t = threadIdx.x;
    int tx = t & 15, ty = t >> 4;
    int ar = t >> 2, akq = (t & 3) * 4;   // A staging: row, k-quad
    int bk = t >> 4, bnq = (t & 15) * 4;  // B staging: k-row, n-quad
    float acc[4][4] = {};
    bool aligned = (F % 4 == 0);

    for (int k0 = 0; k0 < 128; k0 += 16) {
        float4 av = *(const float4*)(Ap + (size_t)(m0 + ar) * NN + k0 + akq);
        As[akq + 0][ar] = av.x; As[akq + 1][ar] = av.y;
        As[akq + 2][ar] = av.z; As[akq + 3][ar] = av.w;
        if (aligned) {
            float4 bv = *(const float4*)(Bp + (size_t)(k0 + bk) * F + n0 + bnq);
            *(float4*)&Bs[bk][bnq] = bv;
        } else {
            #pragma unroll
            for (int j = 0; j < 4; ++j) {
                int n = n0 + bnq + j;
                Bs[bk][bnq + j] = (n < F) ? Bp[(size_t)(k0 + bk) * F + n] : 0.f;
            }
        }
        __syncthreads();
        #pragma unroll
        for (int kk = 0; kk < 16; ++kk) {
            float4 af = *(const float4*)&As[kk][ty * 4];
            float4 bf = *(const float4*)&Bs[kk][tx * 4];
            float a[4] = {af.x, af.y, af.z, af.w};
            float bv[4] = {bf.x, bf.y, bf.z, bf.w};
            #pragma unroll
            for (int i = 0; i < 4; ++i)
                #pragma unroll
                for (int j = 0; j < 4; ++j) acc[i][j] += a[i] * bv[j];
        }
        __syncthreads();
    }
    if (aligned) {
        #pragma unroll
        for (int i = 0; i < 4; ++i) {
            float4 v = make_float4(acc[i][0], acc[i][1], acc[i][2], acc[i][3]);
            *(float4*)(Cp + (size_t)(m0 + ty * 4 + i) * F + n0 + tx * 4) = v;
        }
    } else {
        #pragma unroll
        for (int i = 0; i < 4; ++i)
            #pragma unroll
            for (int j = 0; j < 4; ++j) {
                int n = n0 + tx * 4 + j;
                if (n < F) Cp[(size_t)(m0 + ty * 4 + i) * F + n] = acc[i][j];
            }
    }
}

// ---------------------------------------------------------------------------
// GConv step B: H_out[b][n][o] = relu(sum_{c,f} AV[b,c][n][f]*W[c][f][o] + bias[o])
// GEMM rows = CB*128, cols = 256, K = 3F. W is contiguous [3F][256].
// grid: (CB*2, 4), block 256
__global__ __launch_bounds__(256)
void gB_kernel(const float* __restrict__ AV,
               const float* __restrict__ W,
               const float* __restrict__ bias,
               float* __restrict__ Hout,
               int F, int b0)
{
    int K = AC * F;
    int r0 = blockIdx.x * 64;
    int o0 = blockIdx.y * 64;
    int bl = r0 >> 7, n0 = r0 & 127;
    int bg = b0 + bl;

    __shared__ float As[16][64];
    __shared__ float Bs[16][64];

    int t = threadIdx.x;
    int tx = t & 15, ty = t >> 4;
    int ar = t >> 2, akq = (t & 3) * 4;
    int bk = t >> 4, bnq = (t & 15) * 4;
    float acc[4][4] = {};
    int kTiles = (K + 15) / 16;

    for (int kt = 0; kt < kTiles; ++kt) {
        int k0 = kt * 16;
        if (F == HID) {
            int c = k0 >> 8;
            int fb = (k0 & 255) + akq;
            float4 av = *(const float4*)(AV + (((size_t)(bl * AC + c)) * NN + n0 + ar) * HID + fb);
            As[akq + 0][ar] = av.x; As[akq + 1][ar] = av.y;
            As[akq + 2][ar] = av.z; As[akq + 3][ar] = av.w;
        } else {
            #pragma unroll
            for (int j = 0; j < 4; ++j) {
                int k = k0 + akq + j;
                float v = 0.f;
                if (k < K) {
                    int c = k / F, f = k - c * F;
                    v = AV[(((size_t)(bl * AC + c)) * NN + n0 + ar) * F + f];
                }
                As[akq + j][ar] = v;
            }
        }
        {
            int k = k0 + bk;
            float4 bv = make_float4(0.f, 0.f, 0.f, 0.f);
            if (k < K) bv = *(const float4*)(W + (size_t)k * HID + o0 + bnq);
            *(float4*)&Bs[bk][bnq] = bv;
        }
        __syncthreads();
        #pragma unroll
        for (int kk = 0; kk < 16; ++kk) {
            float4 af = *(const float4*)&As[kk][ty * 4];
            float4 bf = *(const float4*)&Bs[kk][tx * 4];
            float a[4] = {af.x, af.y, af.z, af.w};
            float bv[4] = {bf.x, bf.y, bf.z, bf.w};
            #pragma unroll
            for (int i = 0; i < 4; ++i)
                #pragma unroll
                for (int j = 0; j < 4; ++j) acc[i][j] += a[i] * bv[j];
        }
        __syncthreads();
    }
    #pragma unroll
    for (int i = 0; i < 4; ++i) {
        int n = n0 + ty * 4 + i;
        float* orow = Hout + ((size_t)bg * NN + n) * HID + o0 + tx * 4;
        float4 v;
        v.x = fmaxf(acc[i][0] + bias[o0 + tx * 4 + 0], 0.f);
        v.y = fmaxf(acc[i][1] + bias[o0 + tx * 4 + 1], 0.f);
        v.z = fmaxf(acc[i][2] + bias[o0 + tx * 4 + 2], 0.f);
        v.w = fmaxf(acc[i][3] + bias[o0 + tx * 4 + 3], 0.f);
        *(float4*)orow = v;
    }
}

// ---------------------------------------------------------------------------
// Masked multi-head attention pooling. grid: (B), block: 256
__global__ __launch_bounds__(256)
void pool_kernel(const float* __restrict__ H3,
                 const float* __restrict__ attW,
                 const int* __restrict__ msz,
                 float* __restrict__ pooled)
{
    int b = blockIdx.x, t = threadIdx.x;
    __shared__ float sW[HID * NHEAD];   // [f][h]
    __shared__ float sS[NN * NHEAD];    // scores -> att, [n][h]
    __shared__ float sT[16][257];       // H3 tile
    for (int i = t; i < HID * NHEAD; i += 256) sW[i] = attW[i];
    __syncthreads();
    const float* Hb = H3 + (size_t)b * NN * HID;

    for (int n0 = 0; n0 < NN; n0 += 16) {
        for (int i = t; i < 16 * 64; i += 256) {
            int row = i >> 6, fq = (i & 63) * 4;
            float4 v = *(const float4*)(Hb + (size_t)(n0 + row) * HID + fq);
            sT[row][fq] = v.x; sT[row][fq + 1] = v.y;
            sT[row][fq + 2] = v.z; sT[row][fq + 3] = v.w;
        }
        __syncthreads();
        if (t < 128) {
            int nl = t >> 3, h = t & 7;
            float s = 0.f;
            for (int f = 0; f < HID; ++f) s += sT[nl][f] * sW[f * NHEAD + h];
            sS[(n0 + nl) * NHEAD + h] = s;
        }
        __syncthreads();
    }
    // masked softmax over n per head
    int ms = msz[b];
    int h = t >> 5, ln = t & 31;
    float mx = -1e9f;
    for (int n = ln; n < NN; n += 32) {
        float s = (n < ms) ? sS[n * NHEAD + h] : -1e9f;
        mx = fmaxf(mx, s);
    }
    #pragma unroll
    for (int off = 16; off; off >>= 1) mx = fmaxf(mx, __shfl_xor(mx, off, 32));
    float sum = 0.f;
    for (int n = ln; n < NN; n += 32) {
        float s = (n < ms) ? sS[n * NHEAD + h] : -1e9f;
        sum += expf(s - mx);
    }
    #pragma unroll
    for (int off = 16; off; off >>= 1) sum += __shfl_xor(sum, off, 32);
    float inv = 1.f / sum;
    for (int n = ln; n < NN; n += 32) {
        float s = (n < ms) ? sS[n * NHEAD + h] : -1e9f;
        sS[n * NHEAD + h] = expf(s - mx) * inv;   // disjoint slots per thread
    }
    __syncthreads();
    // pooled[h][f] = sum_n att[n][h] * H3[n][f]; thread owns f = t
    float accp[NHEAD] = {};
    for (int n = 0; n < NN; ++n) {
        float hv = Hb[(size_t)n * HID + t];
        #pragma unroll
        for (int hh = 0; hh < NHEAD; ++hh) accp[hh] += sS[n * NHEAD + hh] * hv;
    }
    #pragma unroll
    for (int hh = 0; hh < NHEAD; ++hh)
        pooled[(size_t)b * (HID * NHEAD) + hh * HID + t] = accp[hh];
}

// ---------------------------------------------------------------------------
// Readout: Vr = relu(pooled @ roW + rob). grid: (B), block: 128
__global__ __launch_bounds__(128)
void readout_kernel(const float* __restrict__ pooled,
                    const float* __restrict__ roW, const float* __restrict__ rob,
                    float* __restrict__ Vr)
{
    int b = blockIdx.x, t = threadIdx.x;
    __shared__ float sp[HID * NHEAD];
    for (int i = t; i < HID * NHEAD; i += 128) sp[i] = pooled[(size_t)b * (HID * NHEAD) + i];
    __syncthreads();
    float acc = 0.f;
    for (int j = 0; j < HID * NHEAD; ++j) acc += sp[j] * roW[(size_t)j * DIM + t];
    Vr[(size_t)b * DIM + t] = fmaxf(acc + rob[t], 0.f);
}

// ---------------------------------------------------------------------------
// h-vectors for cross-attn: h = relu(x @ W + b). grid: (B, 2), block: 128
__global__ __launch_bounds__(128)
void atth_kernel(const float* __restrict__ FP2, const float* __restrict__ VR,
                 const float* __restrict__ mfpW, const float* __restrict__ mfpb,
                 const float* __restrict__ mvW,  const float* __restrict__ mvb,
                 float* __restrict__ h1v, float* __restrict__ h2v)
{
    int b = blockIdx.x, z = blockIdx.y, t = threadIdx.x;
    const float* in = z ? VR : FP2;
    const float* W  = z ? mvW : mfpW;
    const float* bi = z ? mvb : mfpb;
    float* out = z ? h2v : h1v;
    __shared__ float sx[DIM];
    sx[t] = in[(size_t)b * DIM + t];
    __syncthreads();
    float acc = 0.f;
    for (int k = 0; k < DIM; ++k) acc += sx[k] * W[k * DIM + t];
    out[(size_t)b * DIM + t] = fmaxf(acc + bi[t], 0.f);
}

// ---------------------------------------------------------------------------
// Cross-attn scan: it[b][d] = max_l tanh(h . HS[tok]) * HS[tok][d], both branches.
// grid: (B), block: 256 (4 waves, each a strided quarter of L)
__global__ __launch_bounds__(256)
void cross_kernel(const int* __restrict__ seq,
                  const float* __restrict__ HS1, const float* __restrict__ HS2,
                  const float* __restrict__ h1v, const float* __restrict__ h2v,
                  float* __restrict__ IT1, float* __restrict__ IT2)
{
    int b = blockIdx.x, t = threadIdx.x;
    int wv = t >> 6, ln = t & 63;
    __shared__ float sh1[DIM], sh2[DIM];
    __shared__ float rb[4][4][64];
    if (t < DIM) { sh1[t] = h1v[(size_t)b * DIM + t]; sh2[t] = h2v[(size_t)b * DIM + t]; }
    __syncthreads();
    float h1a = sh1[ln], h1b = sh1[ln + 64];
    float h2a = sh2[ln], h2b = sh2[ln + 64];
    float m1a = -INFINITY, m1b = -INFINITY, m2a = -INFINITY, m2b = -INFINITY;
    const int* sq = seq + (size_t)b * LL;
    for (int l = wv; l < LL; l += 4) {
        int tok = sq[l];
        const float* r1 = HS1 + (size_t)tok * DIM;
        const float* r2 = HS2 + (size_t)tok * DIM;
        float v1a = r1[ln], v1b = r1[ln + 64];
        float v2a = r2[ln], v2b = r2[ln + 64];
        float p1 = h1a * v1a + h1b * v1b;
        float p2 = h2a * v2a + h2b * v2b;
        #pragma unroll
        for (int off = 32; off; off >>= 1) { p1 += __shfl_xor(p1, off); p2 += __shfl_xor(p2, off); }
        float w1 = tanhf(p1), w2 = tanhf(p2);
        m1a = fmaxf(m1a, w1 * v1a); m1b = fmaxf(m1b, w1 * v1b);
        m2a = fmaxf(m2a, w2 * v2a); m2b = fmaxf(m2b, w2 * v2b);
    }
    rb[wv][0][ln] = m1a; rb[wv][1][ln] = m1b;
    rb[wv][2][ln] = m2a; rb[wv][3][ln] = m2b;
    __syncthreads();
    if (t < DIM) {
        int lo = t & 63, hi = (t >= 64) ? 1 : 0;
        float a = fmaxf(fmaxf(rb[0][hi][lo], rb[1][hi][lo]),
                        fmaxf(rb[2][hi][lo], rb[3][hi][lo]));
        IT1[(size_t)b * DIM + t] = a;
        float c = fmaxf(fmaxf(rb[0][2 + hi][lo], rb[1][2 + hi][lo]),
                        fmaxf(rb[2][2 + hi][lo], rb[3][2 + hi][lo]));
        IT2[(size_t)b * DIM + t] = c;
    }
}

// ---------------------------------------------------------------------------
// MLP heads + outputs. grid: (B), block: 256
__global__ __launch_bounds__(256)
void mlp_kernel(const float* __restrict__ FP2, const float* __restrict__ VR,
                const float* __restrict__ IT1, const float* __restrict__ IT2,
                const float* __restrict__ m1W, const float* __restrict__ m1b,
                const float* __restrict__ m2W, const float* __restrict__ m2b,
                const float* __restrict__ o1W, const float* __restrict__ o1b,
                const float* __restrict__ o2W, const float* __restrict__ o2b,
                const int* __restrict__ label,
                float* __restrict__ dout)
{
    int b = blockIdx.x, t = threadIdx.x;
    __shared__ float x1[2 * DIM], x2[2 * DIM], y1[2 * DIM], y2[2 * DIM];
    __shared__ float pl[2][128];
    x1[t] = (t < DIM) ? FP2[(size_t)b * DIM + t] : IT1[(size_t)b * DIM + t - DIM];
    x2[t] = (t < DIM) ? VR[(size_t)b * DIM + t]  : IT2[(size_t)b * DIM + t - DIM];
    __syncthreads();
    for (int Lr = 0; Lr < 3; ++Lr) {
        const float* W1 = m1W + (size_t)Lr * 256 * 256;
        const float* B1 = m1b + (size_t)Lr * 256;
        const float* W2 = m2W + (size_t)Lr * 256 * 256;
        const float* B2 = m2b + (size_t)Lr * 256;
        float a1 = 0.f, a2 = 0.f;
        for (int k = 0; k < 256; ++k) {
            a1 += x1[k] * W1[k * 256 + t];
            a2 += x2[k] * W2[k * 256 + t];
        }
        y1[t] = fmaxf(a1 + B1[t], 0.f);
        y2[t] = fmaxf(a2 + B2[t], 0.f);
        __syncthreads();
        x1[t] = y1[t]; x2[t] = y2[t];
        __syncthreads();
    }
    int j = t & 1, k2 = t >> 1;
    float p = x1[k2] * o1W[k2 * 2 + j] + x1[k2 + 128] * o1W[(k2 + 128) * 2 + j]
            + x2[k2] * o2W[k2 * 2 + j] + x2[k2 + 128] * o2W[(k2 + 128) * 2 + j];
    pl[j][k2] = p;
    __syncthreads();
    for (int s = 64; s > 0; s >>= 1) {
        if (k2 < s) pl[j][k2] += pl[j][k2 + s];
        __syncthreads();
    }
    if (t == 0) {
        float l0 = pl[0][0] + o1b[0] + o2b[0];
        float l1 = pl[1][0] + o1b[1] + o2b[1];
        dout[(size_t)b * 2 + 0] = l0;
        dout[(size_t)b * 2 + 1] = l1;
        dout[2 * BB + b] = (float)label[b];
        dout[3 * BB + b] = (float)((l1 > l0) ? 1 : 0);
        float mx = fmaxf(l0, l1);
        float e0 = expf(l0 - mx), e1 = expf(l1 - mx);
        dout[4 * BB + b] = e1 / (e0 + e1);
    }
}

// ---------------------------------------------------------------------------
extern "C" void kernel_launch(void* const* d_in, const int* in_sizes, int n_in,
                              void* d_out, int out_size, void* d_ws, size_t ws_size,
                              hipStream_t stream)
{
    const float* V    = (const float*)d_in[0];
    const float* A    = (const float*)d_in[1];
    const float* fp   = (const float*)d_in[2];
    const int*   msz  = (const int*)  d_in[3];
    const int*   seq  = (const int*)  d_in[4];
    const int*   lab  = (const int*)  d_in[5];
    const float* gcW1 = (const float*)d_in[6];  const float* gcb1 = (const float*)d_in[7];
    const float* gcW2 = (const float*)d_in[8];  const float* gcb2 = (const float*)d_in[9];
    const float* gcW3 = (const float*)d_in[10]; const float* gcb3 = (const float*)d_in[11];
    const float* fpW1 = (const float*)d_in[12]; const float* fpb1 = (const float*)d_in[13];
    const float* fpW2 = (const float*)d_in[14]; const float* fpb2 = (const float*)d_in[15];
    const float* attW = (const float*)d_in[16];
    const float* roW  = (const float*)d_in[17]; const float* rob  = (const float*)d_in[18];
    const float* emb  = (const float*)d_in[19];
    const float* mfpW = (const float*)d_in[20]; const float* mfpb = (const float*)d_in[21];
    const float* pfpW = (const float*)d_in[22]; const float* pfpb = (const float*)d_in[23];
    const float* mvW  = (const float*)d_in[24]; const float* mvb  = (const float*)d_in[25];
    const float* pvW  = (const float*)d_in[26]; const float* pvb  = (const float*)d_in[27];
    const float* m1W  = (const float*)d_in[28]; const float* m1b  = (const float*)d_in[29];
    const float* m2W  = (const float*)d_in[30]; const float* m2b  = (const float*)d_in[31];
    const float* o1W  = (const float*)d_in[32]; const float* o1b  = (const float*)d_in[33];
    const float* o2W  = (const float*)d_in[34]; const float* o2b  = (const float*)d_in[35];
    float* dout = (float*)d_out;

    // workspace layout (all fp32)
    char* ws = (char*)d_ws;
    size_t off = 0;
    float* Ha  = (float*)(ws + off); off += (size_t)BB * NN * HID * 4;   // 33.5 MB
    float* Hb  = (float*)(ws + off); off += (size_t)BB * NN * HID * 4;   // 33.5 MB
    float* FP2 = (float*)(ws + off); off += (size_t)BB * DIM * 4;
    float* HS1 = (float*)(ws + off); off += (size_t)NWORD * DIM * 4;
    float* HS2 = (float*)(ws + off); off += (size_t)NWORD * DIM * 4;
    float* PO  = (float*)(ws + off); off += (size_t)BB * HID * NHEAD * 4;
    float* VR  = (float*)(ws + off); off += (size_t)BB * DIM * 4;
    float* H1V = (float*)(ws + off); off += (size_t)BB * DIM * 4;
    float* H2V = (float*)(ws + off); off += (size_t)BB * DIM * 4;
    float* IT1 = (float*)(ws + off); off += (size_t)BB * DIM * 4;
    float* IT2 = (float*)(ws + off); off += (size_t)BB * DIM * 4;
    float* AV  = (float*)(ws + off);
    size_t fixedBytes = off;

    // batch-chunk size for the AV scratch (0.375 MB per b)
    int CBc = 1;
    size_t perB = (size_t)AC * NN * HID * 4;
    {
        const int tiers[] = {256, 128, 64, 32, 16, 8, 4, 2, 1};
        for (int i = 0; i < 9; ++i) {
            if (fixedBytes + (size_t)tiers[i] * perB <= ws_size) { CBc = tiers[i]; break; }
        }
    }

    // independent front-end
    fp_kernel<<<BB, 128, 0, stream>>>(fp, fpW1, fpb1, fpW2, fpb2, FP2);
    hs_kernel<<<dim3(NWORD / 2, 2), 256, 0, stream>>>(emb, pfpW, pfpb, pvW, pvb, HS1, HS2);

    // GConv stack, b-chunked
    for (int b0 = 0; b0 < BB; b0 += CBc) {
        gA_kernel<<<dim3(2 * 2, AC, CBc), 256, 0, stream>>>(A, V,  AV, NF,  b0, 2);
        gB_kernel<<<dim3(CBc * 2, 4), 256, 0, stream>>>(AV, gcW1, gcb1, Ha, NF,  b0);
        gA_kernel<<<dim3(2 * 4, AC, CBc), 256, 0, stream>>>(A, Ha, AV, HID, b0, 4);
        gB_kernel<<<dim3(CBc * 2, 4), 256, 0, stream>>>(AV, gcW2, gcb2, Hb, HID, b0);
        gA_kernel<<<dim3(2 * 4, AC, CBc), 256, 0, stream>>>(A, Hb, AV, HID, b0, 4);
        gB_kernel<<<dim3(CBc * 2, 4), 256, 0, stream>>>(AV, gcW3, gcb3, Ha, HID, b0);
    }

    pool_kernel<<<BB, 256, 0, stream>>>(Ha, attW, msz, PO);
    readout_kernel<<<BB, 128, 0, stream>>>(PO, roW, rob, VR);
    atth_kernel<<<dim3(BB, 2), 128, 0, stream>>>(FP2, VR, mfpW, mfpb, mvW, mvb, H1V, H2V);
    cross_kernel<<<BB, 256, 0, stream>>>(seq, HS1, HS2, H1V, H2V, IT1, IT2);
    mlp_kernel<<<BB, 256, 0, stream>>>(FP2, VR, IT1, IT2, m1W, m1b, m2W, m2b,
                                       o1W, o1b, o2W, o2b, lab, dout);
}

// Round 4
// 636.895 us; speedup vs baseline: 2.2489x; 2.2489x over previous
//
#include <hip/hip_runtime.h>
#include <math.h>

// Problem constants
static constexpr int BB   = 256;   // batch
static constexpr int NN   = 128;   // nodes
static constexpr int LL   = 2048;  // protein length
static constexpr int NF   = 75;
static constexpr int AC   = 3;
static constexpr int HID  = 256;
static constexpr int DIM  = 128;
static constexpr int NHEAD= 8;
static constexpr int FPD  = 679;
static constexpr int NWORD= 8600;
static constexpr int KB   = 768;   // AV row stride (3*256)

typedef __attribute__((ext_vector_type(8))) _Float16 f16x8;
typedef __attribute__((ext_vector_type(4))) float f32x4;
typedef unsigned int u32;
typedef unsigned short u16;

__device__ __forceinline__ u16 f2h(float x) {
    _Float16 h = (_Float16)x;       // RNE
    return *(u16*)&h;
}

// AV intermediate is stored as fp16 scaled by 1/16 for overflow headroom.
static constexpr float AV_SCALE    = 0.0625f;
static constexpr float AV_UNSCALE  = 16.0f;

// ---------------------------------------------------------------------------
// fp chain: FP1 = relu(fp @ W1 + b1); FP2 = relu(FP1 @ W2 + b2)
__global__ __launch_bounds__(128)
void fp_kernel(const float* __restrict__ fp,
               const float* __restrict__ W1, const float* __restrict__ b1,
               const float* __restrict__ W2, const float* __restrict__ b2,
               float* __restrict__ FP2)
{
    int b = blockIdx.x, t = threadIdx.x;
    __shared__ float s_fp[FPD];
    __shared__ float s_fp1[DIM];
    for (int i = t; i < FPD; i += 128) s_fp[i] = fp[(size_t)b * FPD + i];
    __syncthreads();
    float acc = 0.f;
    for (int k = 0; k < FPD; ++k) acc += s_fp[k] * W1[k * DIM + t];
    s_fp1[t] = fmaxf(acc + b1[t], 0.f);
    __syncthreads();
    float acc2 = 0.f;
    for (int k = 0; k < DIM; ++k) acc2 += s_fp1[k] * W2[k * DIM + t];
    FP2[(size_t)b * DIM + t] = fmaxf(acc2 + b2[t], 0.f);
}

// ---------------------------------------------------------------------------
// HS tables: HS[t][d] = relu(emb[t] @ W + b), per branch.
__global__ __launch_bounds__(256)
void hs_kernel(const float* __restrict__ emb,
               const float* __restrict__ Wa, const float* __restrict__ ba,
               const float* __restrict__ Wb, const float* __restrict__ bb_,
               float* __restrict__ HS1, float* __restrict__ HS2)
{
    int br = blockIdx.y;
    const float* W  = br ? Wb : Wa;
    const float* bi = br ? bb_ : ba;
    float* HS = br ? HS2 : HS1;
    int half = threadIdx.x >> 7;
    int d = threadIdx.x & 127;
    int r = blockIdx.x * 2 + half;
    __shared__ float se[2][DIM];
    se[half][d] = emb[(size_t)r * DIM + d];
    __syncthreads();
    const float* er = se[half];
    float acc = 0.f;
    for (int k = 0; k < DIM; ++k) acc += er[k] * W[k * DIM + d];
    HS[(size_t)r * DIM + d] = fmaxf(acc + bi[d], 0.f);
}

// ---------------------------------------------------------------------------
// prep: V fp32 [b][128][75] -> Vt fp16 [b][80][128] (transposed, rows 75..79 = 0)
__global__ __launch_bounds__(256)
void prepVt_kernel(const float* __restrict__ V, u16* __restrict__ Vt)
{
    int b = blockIdx.x, t = threadIdx.x;
    __shared__ float sV[NN * NF];
    for (int i = t; i < NN * NF; i += 256) sV[i] = V[(size_t)b * (NN * NF) + i];
    __syncthreads();
    for (int i = t; i < 80 * 128; i += 256) {
        int f = i >> 7, n = i & 127;
        float v = (f < NF) ? sV[n * NF + f] : 0.f;
        Vt[(size_t)b * (80 * 128) + i] = f2h(v);
    }
}

// ---------------------------------------------------------------------------
// prep weights transposed fp16: Wt[o][k].
// z=0: Wt1[256][256] from W1[3][75][256], k=(c*80+f), pads zero.
// z=1/2: Wt2/Wt3[256][768] from W[3][256][256], k=(c*256+f).
__global__ __launch_bounds__(256)
void prepW_kernel(const float* __restrict__ W1, const float* __restrict__ W2,
                  const float* __restrict__ W3, u16* __restrict__ Wt1,
                  u16* __restrict__ Wt2, u16* __restrict__ Wt3)
{
    int o = blockIdx.x, z = blockIdx.y, t = threadIdx.x;
    if (z == 0) {
        int k = t;   // 0..255
        int c = k / 80, f = k - c * 80;
        float v = (c < 3 && f < NF) ? W1[((size_t)c * NF + f) * HID + o] : 0.f;
        Wt1[(size_t)o * 256 + k] = f2h(v);
    } else {
        const float* W = (z == 1) ? W2 : W3;
        u16* Wt = (z == 1) ? Wt2 : Wt3;
        for (int k = t; k < KB; k += 256) {
            int c = k >> 8, f = k & 255;
            Wt[(size_t)o * KB + k] = f2h(W[((size_t)c * HID + f) * HID + o]);
        }
    }
}

// ---------------------------------------------------------------------------
// transpose: H fp32 [b][128][256] -> Ht fp16 [b][256][128]
__global__ __launch_bounds__(256)
void transp_kernel(const float* __restrict__ H, u16* __restrict__ Ht)
{
    __shared__ float s[32][33];
    int o0 = blockIdx.x * 32, n0 = blockIdx.y * 32, b = blockIdx.z;
    int tx = threadIdx.x & 31, ty = threadIdx.x >> 5;   // ty 0..7
    const float* Hp = H + (size_t)b * (NN * HID);
    #pragma unroll
    for (int j = 0; j < 4; ++j)
        s[ty + 8 * j][tx] = Hp[(size_t)(n0 + ty + 8 * j) * HID + o0 + tx];
    __syncthreads();
    u16* Hto = Ht + (size_t)b * (HID * NN);
    #pragma unroll
    for (int j = 0; j < 4; ++j)
        Hto[(size_t)(o0 + ty + 8 * j) * NN + n0 + tx] = f2h(s[tx][ty + 8 * j]);
}

// ---------------------------------------------------------------------------
// gA (MFMA): AV[bl][n][c*fpMul + ft*128 + f] = (1/16) * sum_m A[b][c][n][m] * Htr[b][f'][m]
// NT-GEMM: Aop = graph A rows [n][m] (fp32->fp16 in staging), Bop = Htr rows [f][m] fp16.
// grid (ftiles, AC, CB), block 256 (4 waves, 2x2 of 64x64).
__global__ __launch_bounds__(256)
void gA_mfma(const float* __restrict__ Agr, const u16* __restrict__ Htr,
             u16* __restrict__ AV, int b0, int htStride, int fpMul, int Fvalid)
{
    __shared__ u16 As[128 * 40];
    __shared__ u16 Bs[128 * 40];
    int ft = blockIdx.x, c = blockIdx.y, bl = blockIdx.z;
    int b = b0 + bl;
    const float* Ap = Agr + ((size_t)b * AC + c) * (NN * NN);
    const u16* Bp = Htr + (size_t)b * htStride + ft * (128 * 128);
    u16* Cp = AV + (size_t)bl * (NN * KB) + c * fpMul + ft * 128;

    int t = threadIdx.x;
    int l = t & 63, wid = t >> 6;
    int rb = (wid >> 1) * 64, cb = (wid & 1) * 64;
    int ln = l & 15, q = l >> 4;

    f32x4 acc[4][4] = {};

    for (int kt = 0; kt < 4; ++kt) {
        // stage A tile 128x32 fp32 -> fp16
        #pragma unroll
        for (int i = 0; i < 4; ++i) {
            int id = t + i * 256;            // 0..1023
            int row = id >> 3, qf = id & 7;
            float4 v = *(const float4*)(Ap + (size_t)row * NN + kt * 32 + qf * 4);
            u32 p0 = (u32)f2h(v.x) | ((u32)f2h(v.y) << 16);
            u32 p1 = (u32)f2h(v.z) | ((u32)f2h(v.w) << 16);
            u32* dst = (u32*)&As[row * 40 + qf * 4];
            dst[0] = p0; dst[1] = p1;
        }
        // stage B tile 128x32 fp16 (rows >= Fvalid -> 0)
        #pragma unroll
        for (int i = 0; i < 2; ++i) {
            int id = t + i * 256;            // 0..511
            int row = id >> 2, qh = id & 3;
            uint4 v = make_uint4(0, 0, 0, 0);
            if (row < Fvalid) v = *(const uint4*)(Bp + (size_t)row * 128 + kt * 32 + qh * 8);
            *(uint4*)&Bs[row * 40 + qh * 8] = v;
        }
        __syncthreads();
        f16x8 af[4], bfr[4];
        #pragma unroll
        for (int fr = 0; fr < 4; ++fr)
            af[fr] = *(const f16x8*)&As[(rb + fr * 16 + ln) * 40 + q * 8];
        #pragma unroll
        for (int fc = 0; fc < 4; ++fc)
            bfr[fc] = *(const f16x8*)&Bs[(cb + fc * 16 + ln) * 40 + q * 8];
        #pragma unroll
        for (int fr = 0; fr < 4; ++fr)
            #pragma unroll
            for (int fc = 0; fc < 4; ++fc)
                acc[fr][fc] = __builtin_amdgcn_mfma_f32_16x16x32_f16(
                    af[fr], bfr[fc], acc[fr][fc], 0, 0, 0);
        __syncthreads();
    }
    #pragma unroll
    for (int fr = 0; fr < 4; ++fr) {
        #pragma unroll
        for (int fc = 0; fc < 4; ++fc) {
            int fcol = cb + fc * 16 + ln;
            if (fcol < Fvalid) {
                #pragma unroll
                for (int r = 0; r < 4; ++r) {
                    int n = rb + fr * 16 + q * 4 + r;
                    Cp[(size_t)n * KB + fcol] = f2h(acc[fr][fc][r] * AV_SCALE);
                }
            }
        }
    }
}

// ---------------------------------------------------------------------------
// gB (MFMA): H[b][n][o] = relu( 16 * sum_k AVs[bl][n][k] * Wt[o][k] + bias[o] )
// grid (2 otiles, CB), block 256.
__global__ __launch_bounds__(256)
void gB_mfma(const u16* __restrict__ AV, const u16* __restrict__ Wt,
             const float* __restrict__ bias, float* __restrict__ H,
             int b0, int kTiles, int Ks)
{
    __shared__ u16 As[128 * 40];
    __shared__ u16 Bs[128 * 40];
    int ot = blockIdx.x, bl = blockIdx.y;
    int b = b0 + bl;
    const u16* Ap = AV + (size_t)bl * (NN * KB);
    const u16* Bp = Wt + (size_t)ot * 128 * Ks;
    float* Hp = H + (size_t)b * (NN * HID) + ot * 128;

    int t = threadIdx.x;
    int l = t & 63, wid = t >> 6;
    int rb = (wid >> 1) * 64, cb = (wid & 1) * 64;
    int ln = l & 15, q = l >> 4;

    f32x4 acc[4][4] = {};

    for (int kt = 0; kt < kTiles; ++kt) {
        #pragma unroll
        for (int i = 0; i < 2; ++i) {
            int id = t + i * 256;
            int row = id >> 2, qh = id & 3;
            *(uint4*)&As[row * 40 + qh * 8] =
                *(const uint4*)(Ap + (size_t)row * KB + kt * 32 + qh * 8);
        }
        #pragma unroll
        for (int i = 0; i < 2; ++i) {
            int id = t + i * 256;
            int row = id >> 2, qh = id & 3;
            *(uint4*)&Bs[row * 40 + qh * 8] =
                *(const uint4*)(Bp + (size_t)row * Ks + kt * 32 + qh * 8);
        }
        __syncthreads();
        f16x8 af[4], bfr[4];
        #pragma unroll
        for (int fr = 0; fr < 4; ++fr)
            af[fr] = *(const f16x8*)&As[(rb + fr * 16 + ln) * 40 + q * 8];
        #pragma unroll
        for (int fc = 0; fc < 4; ++fc)
            bfr[fc] = *(const f16x8*)&Bs[(cb + fc * 16 + ln) * 40 + q * 8];
        #pragma unroll
        for (int fr = 0; fr < 4; ++fr)
            #pragma unroll
            for (int fc = 0; fc < 4; ++fc)
                acc[fr][fc] = __builtin_amdgcn_mfma_f32_16x16x32_f16(
                    af[fr], bfr[fc], acc[fr][fc], 0, 0, 0);
        __syncthreads();
    }
    #pragma unroll
    for (int fr = 0; fr < 4; ++fr) {
        #pragma unroll
        for (int fc = 0; fc < 4; ++fc) {
            int oc = cb + fc * 16 + ln;
            float bv = bias[ot * 128 + oc];
            #pragma unroll
            for (int r = 0; r < 4; ++r) {
                int n = rb + fr * 16 + q * 4 + r;
                Hp[(size_t)n * HID + oc] = fmaxf(acc[fr][fc][r] * AV_UNSCALE + bv, 0.f);
            }
        }
    }
}

// ---------------------------------------------------------------------------
// Masked multi-head attention pooling. grid: (B), block: 256
__global__ __launch_bounds__(256)
void pool_kernel(const float* __restrict__ H3,
                 const float* __restrict__ attW,
                 const int* __restrict__ msz,
                 float* __restrict__ pooled)
{
    int b = blockIdx.x, t = threadIdx.x;
    __shared__ float sW[HID * NHEAD];
    __shared__ float sS[NN * NHEAD];
    __shared__ float sT[16][257];
    for (int i = t; i < HID * NHEAD; i += 256) sW[i] = attW[i];
    __syncthreads();
    const float* Hb = H3 + (size_t)b * NN * HID;

    for (int n0 = 0; n0 < NN; n0 += 16) {
        for (int i = t; i < 16 * 64; i += 256) {
            int row = i >> 6, fq = (i & 63) * 4;
            float4 v = *(const float4*)(Hb + (size_t)(n0 + row) * HID + fq);
            sT[row][fq] = v.x; sT[row][fq + 1] = v.y;
            sT[row][fq + 2] = v.z; sT[row][fq + 3] = v.w;
        }
        __syncthreads();
        if (t < 128) {
            int nl = t >> 3, h = t & 7;
            float s = 0.f;
            for (int f = 0; f < HID; ++f) s += sT[nl][f] * sW[f * NHEAD + h];
            sS[(n0 + nl) * NHEAD + h] = s;
        }
        __syncthreads();
    }
    int ms = msz[b];
    int h = t >> 5, ln = t & 31;
    float mx = -1e9f;
    for (int n = ln; n < NN; n += 32) {
        float s = (n < ms) ? sS[n * NHEAD + h] : -1e9f;
        mx = fmaxf(mx, s);
    }
    #pragma unroll
    for (int off = 16; off; off >>= 1) mx = fmaxf(mx, __shfl_xor(mx, off, 32));
    float sum = 0.f;
    for (int n = ln; n < NN; n += 32) {
        float s = (n < ms) ? sS[n * NHEAD + h] : -1e9f;
        sum += expf(s - mx);
    }
    #pragma unroll
    for (int off = 16; off; off >>= 1) sum += __shfl_xor(sum, off, 32);
    float inv = 1.f / sum;
    for (int n = ln; n < NN; n += 32) {
        float s = (n < ms) ? sS[n * NHEAD + h] : -1e9f;
        sS[n * NHEAD + h] = expf(s - mx) * inv;
    }
    __syncthreads();
    float accp[NHEAD] = {};
    for (int n = 0; n < NN; ++n) {
        float hv = Hb[(size_t)n * HID + t];
        #pragma unroll
        for (int hh = 0; hh < NHEAD; ++hh) accp[hh] += sS[n * NHEAD + hh] * hv;
    }
    #pragma unroll
    for (int hh = 0; hh < NHEAD; ++hh)
        pooled[(size_t)b * (HID * NHEAD) + hh * HID + t] = accp[hh];
}

// ---------------------------------------------------------------------------
__global__ __launch_bounds__(128)
void readout_kernel(const float* __restrict__ pooled,
                    const float* __restrict__ roW, const float* __restrict__ rob,
                    float* __restrict__ Vr)
{
    int b = blockIdx.x, t = threadIdx.x;
    __shared__ float sp[HID * NHEAD];
    for (int i = t; i < HID * NHEAD; i += 128) sp[i] = pooled[(size_t)b * (HID * NHEAD) + i];
    __syncthreads();
    float acc = 0.f;
    for (int j = 0; j < HID * NHEAD; ++j) acc += sp[j] * roW[(size_t)j * DIM + t];
    Vr[(size_t)b * DIM + t] = fmaxf(acc + rob[t], 0.f);
}

// ---------------------------------------------------------------------------
__global__ __launch_bounds__(128)
void atth_kernel(const float* __restrict__ FP2, const float* __restrict__ VR,
                 const float* __restrict__ mfpW, const float* __restrict__ mfpb,
                 const float* __restrict__ mvW,  const float* __restrict__ mvb,
                 float* __restrict__ h1v, float* __restrict__ h2v)
{
    int b = blockIdx.x, z = blockIdx.y, t = threadIdx.x;
    const float* in = z ? VR : FP2;
    const float* W  = z ? mvW : mfpW;
    const float* bi = z ? mvb : mfpb;
    float* out = z ? h2v : h1v;
    __shared__ float sx[DIM];
    sx[t] = in[(size_t)b * DIM + t];
    __syncthreads();
    float acc = 0.f;
    for (int k = 0; k < DIM; ++k) acc += sx[k] * W[k * DIM + t];
    out[(size_t)b * DIM + t] = fmaxf(acc + bi[t], 0.f);
}

// ---------------------------------------------------------------------------
// Cross-attn partial scan: grid (B, 8). 16 groups of 16 lanes; group handles
// 16 tokens of its 256-token slice; lane owns 8 dims.
__global__ __launch_bounds__(256)
void cross_part_kernel(const int* __restrict__ seq,
                       const float* __restrict__ HS1, const float* __restrict__ HS2,
                       const float* __restrict__ h1v, const float* __restrict__ h2v,
                       float* __restrict__ Pc)   // [8][B][2][128]
{
    int b = blockIdx.x, s = blockIdx.y, t = threadIdx.x;
    int g = t >> 4, gl = t & 15;
    int d0 = gl * 8;
    float4 h1a = *(const float4*)(h1v + (size_t)b * DIM + d0);
    float4 h1b = *(const float4*)(h1v + (size_t)b * DIM + d0 + 4);
    float4 h2a = *(const float4*)(h2v + (size_t)b * DIM + d0);
    float4 h2b = *(const float4*)(h2v + (size_t)b * DIM + d0 + 4);
    float m1[8], m2[8];
    #pragma unroll
    for (int j = 0; j < 8; ++j) { m1[j] = -INFINITY; m2[j] = -INFINITY; }
    const int* sq = seq + (size_t)b * LL + s * 256;
    for (int it = 0; it < 16; ++it) {
        int tok = sq[g + 16 * it];
        const float4* r1 = (const float4*)(HS1 + (size_t)tok * DIM + d0);
        float4 va = r1[0], vb = r1[1];
        const float4* r2 = (const float4*)(HS2 + (size_t)tok * DIM + d0);
        float4 wa = r2[0], wb = r2[1];
        float p1 = h1a.x * va.x + h1a.y * va.y + h1a.z * va.z + h1a.w * va.w
                 + h1b.x * vb.x + h1b.y * vb.y + h1b.z * vb.z + h1b.w * vb.w;
        float p2 = h2a.x * wa.x + h2a.y * wa.y + h2a.z * wa.z + h2a.w * wa.w
                 + h2b.x * wb.x + h2b.y * wb.y + h2b.z * wb.z + h2b.w * wb.w;
        #pragma unroll
        for (int off = 8; off; off >>= 1) {
            p1 += __shfl_xor(p1, off);
            p2 += __shfl_xor(p2, off);
        }
        float w1 = tanhf(p1), w2 = tanhf(p2);
        m1[0] = fmaxf(m1[0], w1 * va.x); m1[1] = fmaxf(m1[1], w1 * va.y);
        m1[2] = fmaxf(m1[2], w1 * va.z); m1[3] = fmaxf(m1[3], w1 * va.w);
        m1[4] = fmaxf(m1[4], w1 * vb.x); m1[5] = fmaxf(m1[5], w1 * vb.y);
        m1[6] = fmaxf(m1[6], w1 * vb.z); m1[7] = fmaxf(m1[7], w1 * vb.w);
        m2[0] = fmaxf(m2[0], w2 * wa.x); m2[1] = fmaxf(m2[1], w2 * wa.y);
        m2[2] = fmaxf(m2[2], w2 * wa.z); m2[3] = fmaxf(m2[3], w2 * wa.w);
        m2[4] = fmaxf(m2[4], w2 * wb.x); m2[5] = fmaxf(m2[5], w2 * wb.y);
        m2[6] = fmaxf(m2[6], w2 * wb.z); m2[7] = fmaxf(m2[7], w2 * wb.w);
    }
    __shared__ float red[16][2][DIM];
    #pragma unroll
    for (int j = 0; j < 8; ++j) { red[g][0][d0 + j] = m1[j]; red[g][1][d0 + j] = m2[j]; }
    __syncthreads();
    int tb = t >> 7, d = t & 127;
    float mx = red[0][tb][d];
    #pragma unroll
    for (int gg = 1; gg < 16; ++gg) mx = fmaxf(mx, red[gg][tb][d]);
    Pc[(((size_t)s * BB + b) * 2 + tb) * DIM + d] = mx;
}

__global__ __launch_bounds__(256)
void cross_merge_kernel(const float* __restrict__ Pc,
                        float* __restrict__ IT1, float* __restrict__ IT2)
{
    int b = blockIdx.x, t = threadIdx.x;
    float m = -INFINITY;
    for (int s = 0; s < 8; ++s)
        m = fmaxf(m, Pc[((size_t)s * BB + b) * 256 + t]);
    if (t < DIM) IT1[(size_t)b * DIM + t] = m;
    else         IT2[(size_t)b * DIM + t - DIM] = m;
}

// ---------------------------------------------------------------------------
// MLP heads + outputs. grid: (B), block: 256
__global__ __launch_bounds__(256)
void mlp_kernel(const float* __restrict__ FP2, const float* __restrict__ VR,
                const float* __restrict__ IT1, const float* __restrict__ IT2,
                const float* __restrict__ m1W, const float* __restrict__ m1b,
                const float* __restrict__ m2W, const float* __restrict__ m2b,
                const float* __restrict__ o1W, const float* __restrict__ o1b,
                const float* __restrict__ o2W, const float* __restrict__ o2b,
                const int* __restrict__ label,
                float* __restrict__ dout)
{
    int b = blockIdx.x, t = threadIdx.x;
    __shared__ float x1[2 * DIM], x2[2 * DIM], y1[2 * DIM], y2[2 * DIM];
    __shared__ float pl[2][128];
    x1[t] = (t < DIM) ? FP2[(size_t)b * DIM + t] : IT1[(size_t)b * DIM + t - DIM];
    x2[t] = (t < DIM) ? VR[(size_t)b * DIM + t]  : IT2[(size_t)b * DIM + t - DIM];
    __syncthreads();
    for (int Lr = 0; Lr < 3; ++Lr) {
        const float* W1 = m1W + (size_t)Lr * 256 * 256;
        const float* B1 = m1b + (size_t)Lr * 256;
        const float* W2 = m2W + (size_t)Lr * 256 * 256;
        const float* B2 = m2b + (size_t)Lr * 256;
        float a1 = 0.f, a2 = 0.f;
        for (int k = 0; k < 256; ++k) {
            a1 += x1[k] * W1[k * 256 + t];
            a2 += x2[k] * W2[k * 256 + t];
        }
        y1[t] = fmaxf(a1 + B1[t], 0.f);
        y2[t] = fmaxf(a2 + B2[t], 0.f);
        __syncthreads();
        x1[t] = y1[t]; x2[t] = y2[t];
        __syncthreads();
    }
    int j = t & 1, k2 = t >> 1;
    float p = x1[k2] * o1W[k2 * 2 + j] + x1[k2 + 128] * o1W[(k2 + 128) * 2 + j]
            + x2[k2] * o2W[k2 * 2 + j] + x2[k2 + 128] * o2W[(k2 + 128) * 2 + j];
    pl[j][k2] = p;
    __syncthreads();
    for (int s = 64; s > 0; s >>= 1) {
        if (k2 < s) pl[j][k2] += pl[j][k2 + s];
        __syncthreads();
    }
    if (t == 0) {
        float l0 = pl[0][0] + o1b[0] + o2b[0];
        float l1 = pl[1][0] + o1b[1] + o2b[1];
        dout[(size_t)b * 2 + 0] = l0;
        dout[(size_t)b * 2 + 1] = l1;
        dout[2 * BB + b] = (float)label[b];
        dout[3 * BB + b] = (float)((l1 > l0) ? 1 : 0);
        float mx = fmaxf(l0, l1);
        float e0 = expf(l0 - mx), e1 = expf(l1 - mx);
        dout[4 * BB + b] = e1 / (e0 + e1);
    }
}

// ---------------------------------------------------------------------------
extern "C" void kernel_launch(void* const* d_in, const int* in_sizes, int n_in,
                              void* d_out, int out_size, void* d_ws, size_t ws_size,
                              hipStream_t stream)
{
    const float* V    = (const float*)d_in[0];
    const float* A    = (const float*)d_in[1];
    const float* fp   = (const float*)d_in[2];
    const int*   msz  = (const int*)  d_in[3];
    const int*   seq  = (const int*)  d_in[4];
    const int*   lab  = (const int*)  d_in[5];
    const float* gcW1 = (const float*)d_in[6];  const float* gcb1 = (const float*)d_in[7];
    const float* gcW2 = (const float*)d_in[8];  const float* gcb2 = (const float*)d_in[9];
    const float* gcW3 = (const float*)d_in[10]; const float* gcb3 = (const float*)d_in[11];
    const float* fpW1 = (const float*)d_in[12]; const float* fpb1 = (const float*)d_in[13];
    const float* fpW2 = (const float*)d_in[14]; const float* fpb2 = (const float*)d_in[15];
    const float* attW = (const float*)d_in[16];
    const float* roW  = (const float*)d_in[17]; const float* rob  = (const float*)d_in[18];
    const float* emb  = (const float*)d_in[19];
    const float* mfpW = (const float*)d_in[20]; const float* mfpb = (const float*)d_in[21];
    const float* pfpW = (const float*)d_in[22]; const float* pfpb = (const float*)d_in[23];
    const float* mvW  = (const float*)d_in[24]; const float* mvb  = (const float*)d_in[25];
    const float* pvW  = (const float*)d_in[26]; const float* pvb  = (const float*)d_in[27];
    const float* m1W  = (const float*)d_in[28]; const float* m1b  = (const float*)d_in[29];
    const float* m2W  = (const float*)d_in[30]; const float* m2b  = (const float*)d_in[31];
    const float* o1W  = (const float*)d_in[32]; const float* o1b  = (const float*)d_in[33];
    const float* o2W  = (const float*)d_in[34]; const float* o2b  = (const float*)d_in[35];
    float* dout = (float*)d_out;

    // workspace layout
    char* ws = (char*)d_ws;
    size_t off = 0;
    auto alloc = [&](size_t bytes) -> char* {
        char* p = ws + off;
        off += (bytes + 255) & ~(size_t)255;
        return p;
    };
    u16*   Vt  = (u16*)  alloc((size_t)BB * 80 * 128 * 2);       // 5.24 MB
    u16*   Wt1 = (u16*)  alloc((size_t)256 * 256 * 2);
    u16*   Wt2 = (u16*)  alloc((size_t)256 * KB * 2);
    u16*   Wt3 = (u16*)  alloc((size_t)256 * KB * 2);
    float* H   = (float*)alloc((size_t)BB * NN * HID * 4);       // 33.5 MB
    u16*   Ht  = (u16*)  alloc((size_t)BB * HID * NN * 2);       // 16.8 MB
    float* FP2 = (float*)alloc((size_t)BB * DIM * 4);
    float* HS1 = (float*)alloc((size_t)NWORD * DIM * 4);
    float* HS2 = (float*)alloc((size_t)NWORD * DIM * 4);
    float* PO  = (float*)alloc((size_t)BB * HID * NHEAD * 4);
    float* VR  = (float*)alloc((size_t)BB * DIM * 4);
    float* H1V = (float*)alloc((size_t)BB * DIM * 4);
    float* H2V = (float*)alloc((size_t)BB * DIM * 4);
    float* IT1 = (float*)alloc((size_t)BB * DIM * 4);
    float* IT2 = (float*)alloc((size_t)BB * DIM * 4);
    float* Pc  = (float*)alloc((size_t)8 * BB * 2 * DIM * 4);    // 2.1 MB
    size_t fixedBytes = off;

    // AV tier (fp16, per-b 128*768*2 = 196608 B)
    int CB = 8;
    size_t perB = (size_t)NN * KB * 2;
    {
        const int tiers[] = {256, 128, 64, 32, 16, 8, 4, 2, 1};
        for (int i = 0; i < 9; ++i)
            if (fixedBytes + (size_t)tiers[i] * perB <= ws_size) { CB = tiers[i]; break; }
    }
    u16* AV = (u16*)(ws + fixedBytes);

    // prep + independent front-end
    prepVt_kernel<<<BB, 256, 0, stream>>>(V, Vt);
    prepW_kernel<<<dim3(256, 3), 256, 0, stream>>>(gcW1, gcW2, gcW3, Wt1, Wt2, Wt3);
    fp_kernel<<<BB, 128, 0, stream>>>(fp, fpW1, fpb1, fpW2, fpb2, FP2);
    hs_kernel<<<dim3(NWORD / 2, 2), 256, 0, stream>>>(emb, pfpW, pfpb, pvW, pvb, HS1, HS2);

    // GConv layer 1 (K=128 over m; F=75 padded to 80; gB K=240(+16 pad) -> kTiles 8)
    for (int b0 = 0; b0 < BB; b0 += CB) {
        gA_mfma<<<dim3(1, AC, CB), 256, 0, stream>>>(A, Vt, AV, b0, 80 * 128, 80, 80);
        gB_mfma<<<dim3(2, CB), 256, 0, stream>>>(AV, Wt1, gcb1, H, b0, 8, 256);
    }
    transp_kernel<<<dim3(8, 4, BB), 256, 0, stream>>>(H, Ht);
    // layer 2
    for (int b0 = 0; b0 < BB; b0 += CB) {
        gA_mfma<<<dim3(2, AC, CB), 256, 0, stream>>>(A, Ht, AV, b0, HID * NN, 256, 128);
        gB_mfma<<<dim3(2, CB), 256, 0, stream>>>(AV, Wt2, gcb2, H, b0, 24, KB);
    }
    transp_kernel<<<dim3(8, 4, BB), 256, 0, stream>>>(H, Ht);
    // layer 3
    for (int b0 = 0; b0 < BB; b0 += CB) {
        gA_mfma<<<dim3(2, AC, CB), 256, 0, stream>>>(A, Ht, AV, b0, HID * NN, 256, 128);
        gB_mfma<<<dim3(2, CB), 256, 0, stream>>>(AV, Wt3, gcb3, H, b0, 24, KB);
    }

    pool_kernel<<<BB, 256, 0, stream>>>(H, attW, msz, PO);
    readout_kernel<<<BB, 128, 0, stream>>>(PO, roW, rob, VR);
    atth_kernel<<<dim3(BB, 2), 128, 0, stream>>>(FP2, VR, mfpW, mfpb, mvW, mvb, H1V, H2V);
    cross_part_kernel<<<dim3(BB, 8), 256, 0, stream>>>(seq, HS1, HS2, H1V, H2V, Pc);
    cross_merge_kernel<<<BB, 256, 0, stream>>>(Pc, IT1, IT2);
    mlp_kernel<<<BB, 256, 0, stream>>>(FP2, VR, IT1, IT2, m1W, m1b, m2W, m2b,
                                       o1W, o1b, o2W, o2b, lab, dout);
}

// Round 6
// 623.129 us; speedup vs baseline: 2.2986x; 1.0221x over previous
//
#include <hip/hip_runtime.h>
#include <math.h>

// Problem constants
static constexpr int BB   = 256;   // batch
static constexpr int NN   = 128;   // nodes
static constexpr int LL   = 2048;  // protein length
static constexpr int NF   = 75;
static constexpr int AC   = 3;
static constexpr int HID  = 256;
static constexpr int DIM  = 128;
static constexpr int NHEAD= 8;
static constexpr int FPD  = 679;
static constexpr int NWORD= 8600;
static constexpr int KB   = 768;   // AV row stride (3*256)

typedef __attribute__((ext_vector_type(8))) _Float16 f16x8;
typedef __attribute__((ext_vector_type(4))) float f32x4;
typedef unsigned int u32;
typedef unsigned short u16;

__device__ __forceinline__ u16 f2h(float x) {
    _Float16 h = (_Float16)x;       // RNE
    return *(u16*)&h;
}
// saturating fp32->fp16 (avoid inf from rare tail values; clamped value is
// strictly closer to the true one than inf would be)
__device__ __forceinline__ u16 f2h_sat(float x) {
    x = fminf(fmaxf(x, -65000.f), 65000.f);
    _Float16 h = (_Float16)x;
    return *(u16*)&h;
}
__device__ __forceinline__ float h2f(u16 x) {
    return (float)(*(_Float16*)&x);
}

// AV intermediate is stored as fp16 scaled by 1/16 for overflow headroom.
static constexpr float AV_SCALE    = 0.0625f;
static constexpr float AV_UNSCALE  = 16.0f;

// ---------------------------------------------------------------------------
// fp chain, 2-way k-split: FP2 = relu(relu(fp@W1+b1)@W2+b2). grid (B), block 256
__global__ __launch_bounds__(256)
void fp_kernel(const float* __restrict__ fp,
               const float* __restrict__ W1, const float* __restrict__ b1,
               const float* __restrict__ W2, const float* __restrict__ b2,
               float* __restrict__ FP2)
{
    int b = blockIdx.x, t = threadIdx.x;
    int d = t & 127, kg = t >> 7;
    __shared__ float s_fp[FPD];
    __shared__ float part[2][DIM];
    __shared__ float s_fp1[DIM];
    for (int i = t; i < FPD; i += 256) s_fp[i] = fp[(size_t)b * FPD + i];
    __syncthreads();
    float acc = 0.f;
    int k0 = kg ? 340 : 0, k1 = kg ? FPD : 340;
    for (int k = k0; k < k1; ++k) acc += s_fp[k] * W1[k * DIM + d];
    part[kg][d] = acc;
    __syncthreads();
    if (t < 128) s_fp1[t] = fmaxf(part[0][t] + part[1][t] + b1[t], 0.f);
    __syncthreads();
    float acc2 = 0.f;
    for (int k = kg * 64; k < kg * 64 + 64; ++k) acc2 += s_fp1[k] * W2[k * DIM + d];
    part[kg][d] = acc2;
    __syncthreads();
    if (t < 128) FP2[(size_t)b * DIM + t] = fmaxf(part[0][t] + part[1][t] + b2[t], 0.f);
}

// ---------------------------------------------------------------------------
// HS tables: HS[t][d] = relu(emb[t] @ W + b), per branch.
__global__ __launch_bounds__(256)
void hs_kernel(const float* __restrict__ emb,
               const float* __restrict__ Wa, const float* __restrict__ ba,
               const float* __restrict__ Wb, const float* __restrict__ bb_,
               float* __restrict__ HS1, float* __restrict__ HS2)
{
    int br = blockIdx.y;
    const float* W  = br ? Wb : Wa;
    const float* bi = br ? bb_ : ba;
    float* HS = br ? HS2 : HS1;
    int half = threadIdx.x >> 7;
    int d = threadIdx.x & 127;
    int r = blockIdx.x * 2 + half;
    __shared__ float se[2][DIM];
    se[half][d] = emb[(size_t)r * DIM + d];
    __syncthreads();
    const float* er = se[half];
    float acc = 0.f;
    for (int k = 0; k < DIM; ++k) acc += er[k] * W[k * DIM + d];
    HS[(size_t)r * DIM + d] = fmaxf(acc + bi[d], 0.f);
}

// ---------------------------------------------------------------------------
// prep: V fp32 [b][128][75] -> Vt fp16 [b][80][128] (transposed, rows 75..79 = 0)
__global__ __launch_bounds__(256)
void prepVt_kernel(const float* __restrict__ V, u16* __restrict__ Vt)
{
    int b = blockIdx.x, t = threadIdx.x;
    __shared__ float sV[NN * NF];
    for (int i = t; i < NN * NF; i += 256) sV[i] = V[(size_t)b * (NN * NF) + i];
    __syncthreads();
    for (int i = t; i < 80 * 128; i += 256) {
        int f = i >> 7, n = i & 127;
        float v = (f < NF) ? sV[n * NF + f] : 0.f;
        Vt[(size_t)b * (80 * 128) + i] = f2h(v);
    }
}

// ---------------------------------------------------------------------------
// prep weights transposed fp16: Wt[o][k].
__global__ __launch_bounds__(256)
void prepW_kernel(const float* __restrict__ W1, const float* __restrict__ W2,
                  const float* __restrict__ W3, u16* __restrict__ Wt1,
                  u16* __restrict__ Wt2, u16* __restrict__ Wt3)
{
    int o = blockIdx.x, z = blockIdx.y, t = threadIdx.x;
    if (z == 0) {
        int k = t;   // 0..255
        int c = k / 80, f = k - c * 80;
        float v = (c < 3 && f < NF) ? W1[((size_t)c * NF + f) * HID + o] : 0.f;
        Wt1[(size_t)o * 256 + k] = f2h(v);
    } else {
        const float* W = (z == 1) ? W2 : W3;
        u16* Wt = (z == 1) ? Wt2 : Wt3;
        for (int k = t; k < KB; k += 256) {
            int c = k >> 8, f = k & 255;
            Wt[(size_t)o * KB + k] = f2h(W[((size_t)c * HID + f) * HID + o]);
        }
    }
}

// ---------------------------------------------------------------------------
// transpose: H fp16 [b][128][256] -> Ht fp16 [b][256][128]
__global__ __launch_bounds__(256)
void transp_kernel(const u16* __restrict__ H, u16* __restrict__ Ht)
{
    __shared__ u16 s[32][34];   // stride 17 banks -> conflict-free column read
    int o0 = blockIdx.x * 32, n0 = blockIdx.y * 32, b = blockIdx.z;
    int tx = threadIdx.x & 31, ty = threadIdx.x >> 5;   // ty 0..7
    const u16* Hp = H + (size_t)b * (NN * HID);
    #pragma unroll
    for (int j = 0; j < 4; ++j)
        s[ty + 8 * j][tx] = Hp[(size_t)(n0 + ty + 8 * j) * HID + o0 + tx];
    __syncthreads();
    u16* Hto = Ht + (size_t)b * (HID * NN);
    #pragma unroll
    for (int j = 0; j < 4; ++j)
        Hto[(size_t)(o0 + ty + 8 * j) * NN + n0 + tx] = s[tx][ty + 8 * j];
}

// ---------------------------------------------------------------------------
// gA (MFMA): AV[bl][n][c*fpMul + ft*128 + f] = (1/16) * sum_m A[b][c][n][m] * Htr[b][f'][m]
__global__ __launch_bounds__(256)
void gA_mfma(const float* __restrict__ Agr, const u16* __restrict__ Htr,
             u16* __restrict__ AV, int b0, int htStride, int fpMul, int Fvalid)
{
    __shared__ u16 As[128 * 40];
    __shared__ u16 Bs[128 * 40];
    int ft = blockIdx.x, c = blockIdx.y, bl = blockIdx.z;
    int b = b0 + bl;
    const float* Ap = Agr + ((size_t)b * AC + c) * (NN * NN);
    const u16* Bp = Htr + (size_t)b * htStride + ft * (128 * 128);
    u16* Cp = AV + (size_t)bl * (NN * KB) + c * fpMul + ft * 128;

    int t = threadIdx.x;
    int l = t & 63, wid = t >> 6;
    int rb = (wid >> 1) * 64, cb = (wid & 1) * 64;
    int ln = l & 15, q = l >> 4;

    f32x4 acc[4][4] = {};

    for (int kt = 0; kt < 4; ++kt) {
        // stage A tile 128x32 fp32 -> fp16
        #pragma unroll
        for (int i = 0; i < 4; ++i) {
            int id = t + i * 256;            // 0..1023
            int row = id >> 3, qf = id & 7;
            float4 v = *(const float4*)(Ap + (size_t)row * NN + kt * 32 + qf * 4);
            u32 p0 = (u32)f2h(v.x) | ((u32)f2h(v.y) << 16);
            u32 p1 = (u32)f2h(v.z) | ((u32)f2h(v.w) << 16);
            u32* dst = (u32*)&As[row * 40 + qf * 4];
            dst[0] = p0; dst[1] = p1;
        }
        // stage B tile 128x32 fp16 (rows >= Fvalid -> 0)
        #pragma unroll
        for (int i = 0; i < 2; ++i) {
            int id = t + i * 256;            // 0..511
            int row = id >> 2, qh = id & 3;
            uint4 v = make_uint4(0, 0, 0, 0);
            if (row < Fvalid) v = *(const uint4*)(Bp + (size_t)row * 128 + kt * 32 + qh * 8);
            *(uint4*)&Bs[row * 40 + qh * 8] = v;
        }
        __syncthreads();
        f16x8 af[4], bfr[4];
        #pragma unroll
        for (int fr = 0; fr < 4; ++fr)
            af[fr] = *(const f16x8*)&As[(rb + fr * 16 + ln) * 40 + q * 8];
        #pragma unroll
        for (int fc = 0; fc < 4; ++fc)
            bfr[fc] = *(const f16x8*)&Bs[(cb + fc * 16 + ln) * 40 + q * 8];
        #pragma unroll
        for (int fr = 0; fr < 4; ++fr)
            #pragma unroll
            for (int fc = 0; fc < 4; ++fc)
                acc[fr][fc] = __builtin_amdgcn_mfma_f32_16x16x32_f16(
                    af[fr], bfr[fc], acc[fr][fc], 0, 0, 0);
        __syncthreads();
    }
    #pragma unroll
    for (int fr = 0; fr < 4; ++fr) {
        #pragma unroll
        for (int fc = 0; fc < 4; ++fc) {
            int fcol = cb + fc * 16 + ln;
            if (fcol < Fvalid) {
                #pragma unroll
                for (int r = 0; r < 4; ++r) {
                    int n = rb + fr * 16 + q * 4 + r;
                    Cp[(size_t)n * KB + fcol] = f2h_sat(acc[fr][fc][r] * AV_SCALE);
                }
            }
        }
    }
}

// ---------------------------------------------------------------------------
// gB (MFMA): out[b][n][o] = relu( 16 * sum_k AVs[bl][n][k] * Wt[o][k] + bias[o] )
// outF32=0 -> fp16 store to H16 (layers 1,2); outF32=1 -> fp32 store to H32 (layer 3).
__global__ __launch_bounds__(256)
void gB_mfma(const u16* __restrict__ AV, const u16* __restrict__ Wt,
             const float* __restrict__ bias, u16* __restrict__ H16,
             float* __restrict__ H32,
             int b0, int kTiles, int Ks, int outF32)
{
    __shared__ u16 As[128 * 40];
    __shared__ u16 Bs[128 * 40];
    int ot = blockIdx.x, bl = blockIdx.y;
    int b = b0 + bl;
    const u16* Ap = AV + (size_t)bl * (NN * KB);
    const u16* Bp = Wt + (size_t)ot * 128 * Ks;

    int t = threadIdx.x;
    int l = t & 63, wid = t >> 6;
    int rb = (wid >> 1) * 64, cb = (wid & 1) * 64;
    int ln = l & 15, q = l >> 4;

    f32x4 acc[4][4] = {};

    for (int kt = 0; kt < kTiles; ++kt) {
        #pragma unroll
        for (int i = 0; i < 2; ++i) {
            int id = t + i * 256;
            int row = id >> 2, qh = id & 3;
            *(uint4*)&As[row * 40 + qh * 8] =
                *(const uint4*)(Ap + (size_t)row * KB + kt * 32 + qh * 8);
        }
        #pragma unroll
        for (int i = 0; i < 2; ++i) {
            int id = t + i * 256;
            int row = id >> 2, qh = id & 3;
            *(uint4*)&Bs[row * 40 + qh * 8] =
                *(const uint4*)(Bp + (size_t)row * Ks + kt * 32 + qh * 8);
        }
        __syncthreads();
        f16x8 af[4], bfr[4];
        #pragma unroll
        for (int fr = 0; fr < 4; ++fr)
            af[fr] = *(const f16x8*)&As[(rb + fr * 16 + ln) * 40 + q * 8];
        #pragma unroll
        for (int fc = 0; fc < 4; ++fc)
            bfr[fc] = *(const f16x8*)&Bs[(cb + fc * 16 + ln) * 40 + q * 8];
        #pragma unroll
        for (int fr = 0; fr < 4; ++fr)
            #pragma unroll
            for (int fc = 0; fc < 4; ++fc)
                acc[fr][fc] = __builtin_amdgcn_mfma_f32_16x16x32_f16(
                    af[fr], bfr[fc], acc[fr][fc], 0, 0, 0);
        __syncthreads();
    }
    #pragma unroll
    for (int fr = 0; fr < 4; ++fr) {
        #pragma unroll
        for (int fc = 0; fc < 4; ++fc) {
            int oc = cb + fc * 16 + ln;
            float bv = bias[ot * 128 + oc];
            #pragma unroll
            for (int r = 0; r < 4; ++r) {
                int n = rb + fr * 16 + q * 4 + r;
                float val = fmaxf(acc[fr][fc][r] * AV_UNSCALE + bv, 0.f);
                if (outF32)
                    H32[((size_t)b * NN + n) * HID + ot * 128 + oc] = val;
                else
                    H16[((size_t)b * NN + n) * HID + ot * 128 + oc] = f2h_sat(val);
            }
        }
    }
}

// ---------------------------------------------------------------------------
// Masked multi-head attention pooling (H3 fp32). grid: (B), block: 256
__global__ __launch_bounds__(256)
void pool_kernel(const float* __restrict__ H3,
                 const float* __restrict__ attW,
                 const int* __restrict__ msz,
                 float* __restrict__ pooled)
{
    int b = blockIdx.x, t = threadIdx.x;
    __shared__ float sW[HID * NHEAD];
    __shared__ float sS[NN * NHEAD];
    __shared__ float sT[16][264];
    __shared__ float sP[16][NHEAD][2];
    for (int i = t; i < HID * NHEAD; i += 256) sW[i] = attW[i];
    __syncthreads();
    const float* Hb = H3 + (size_t)b * NN * HID;

    for (int n0 = 0; n0 < NN; n0 += 16) {
        for (int i = t; i < 16 * 64; i += 256) {
            int row = i >> 6, fq = (i & 63) * 4;
            float4 v = *(const float4*)(Hb + (size_t)(n0 + row) * HID + fq);
            *(float4*)&sT[row][fq] = v;
        }
        __syncthreads();
        {
            int nl = t >> 4, h = (t >> 1) & 7, fh = t & 1;
            float s = 0.f;
            for (int f = fh * 128; f < fh * 128 + 128; ++f)
                s += sT[nl][f] * sW[f * NHEAD + h];
            sP[nl][h][fh] = s;
        }
        __syncthreads();
        if (t < 128) {
            int n2 = t >> 3, h2 = t & 7;
            sS[(n0 + n2) * NHEAD + h2] = sP[n2][h2][0] + sP[n2][h2][1];
        }
        __syncthreads();
    }
    int ms = msz[b];
    int h = t >> 5, ln = t & 31;
    float mx = -1e9f;
    for (int n = ln; n < NN; n += 32) {
        float s = (n < ms) ? sS[n * NHEAD + h] : -1e9f;
        mx = fmaxf(mx, s);
    }
    #pragma unroll
    for (int off = 16; off; off >>= 1) mx = fmaxf(mx, __shfl_xor(mx, off, 32));
    float sum = 0.f;
    for (int n = ln; n < NN; n += 32) {
        float s = (n < ms) ? sS[n * NHEAD + h] : -1e9f;
        sum += expf(s - mx);
    }
    #pragma unroll
    for (int off = 16; off; off >>= 1) sum += __shfl_xor(sum, off, 32);
    float inv = 1.f / sum;
    for (int n = ln; n < NN; n += 32) {
        float s = (n < ms) ? sS[n * NHEAD + h] : -1e9f;
        sS[n * NHEAD + h] = expf(s - mx) * inv;
    }
    __syncthreads();
    float accp[NHEAD] = {};
    for (int n = 0; n < NN; ++n) {
        float hv = Hb[(size_t)n * HID + t];
        #pragma unroll
        for (int hh = 0; hh < NHEAD; ++hh) accp[hh] += sS[n * NHEAD + hh] * hv;
    }
    #pragma unroll
    for (int hh = 0; hh < NHEAD; ++hh)
        pooled[(size_t)b * (HID * NHEAD) + hh * HID + t] = accp[hh];
}

// ---------------------------------------------------------------------------
// Readout, k-split: Rp[s][b][d] = sum_{k in chunk s} pooled[b][k]*roW[k][d]
__global__ __launch_bounds__(128)
void readout_part(const float* __restrict__ pooled,
                  const float* __restrict__ roW,
                  float* __restrict__ Rp)
{
    int b = blockIdx.x, s = blockIdx.y, t = threadIdx.x;
    __shared__ float sx[256];
    const float* sp = pooled + (size_t)b * (HID * NHEAD) + s * 256;
    sx[t] = sp[t];
    sx[t + 128] = sp[t + 128];
    __syncthreads();
    float acc = 0.f;
    const float* W = roW + (size_t)(s * 256) * DIM + t;
    for (int k = 0; k < 256; ++k) acc += sx[k] * W[(size_t)k * DIM];
    Rp[((size_t)s * BB + b) * DIM + t] = acc;
}

__global__ __launch_bounds__(128)
void readout_merge(const float* __restrict__ Rp,
                   const float* __restrict__ rob,
                   float* __restrict__ Vr)
{
    int b = blockIdx.x, t = threadIdx.x;
    float a = rob[t];
    #pragma unroll
    for (int s = 0; s < 8; ++s) a += Rp[((size_t)s * BB + b) * DIM + t];
    Vr[(size_t)b * DIM + t] = fmaxf(a, 0.f);
}

// ---------------------------------------------------------------------------
__global__ __launch_bounds__(128)
void atth_kernel(const float* __restrict__ FP2, const float* __restrict__ VR,
                 const float* __restrict__ mfpW, const float* __restrict__ mfpb,
                 const float* __restrict__ mvW,  const float* __restrict__ mvb,
                 float* __restrict__ h1v, float* __restrict__ h2v)
{
    int b = blockIdx.x, z = blockIdx.y, t = threadIdx.x;
    const float* in = z ? VR : FP2;
    const float* W  = z ? mvW : mfpW;
    const float* bi = z ? mvb : mfpb;
    float* out = z ? h2v : h1v;
    __shared__ float sx[DIM];
    sx[t] = in[(size_t)b * DIM + t];
    __syncthreads();
    float acc = 0.f;
    for (int k = 0; k < DIM; ++k) acc += sx[k] * W[k * DIM + t];
    out[(size_t)b * DIM + t] = fmaxf(acc + bi[t], 0.f);
}

// ---------------------------------------------------------------------------
// Cross-attn partial scan: grid (B, 8). 16 groups of 16 lanes.
__global__ __launch_bounds__(256)
void cross_part_kernel(const int* __restrict__ seq,
                       const float* __restrict__ HS1, const float* __restrict__ HS2,
                       const float* __restrict__ h1v, const float* __restrict__ h2v,
                       float* __restrict__ Pc)   // [8][B][2][128]
{
    int b = blockIdx.x, s = blockIdx.y, t = threadIdx.x;
    int g = t >> 4, gl = t & 15;
    int d0 = gl * 8;
    float4 h1a = *(const float4*)(h1v + (size_t)b * DIM + d0);
    float4 h1b = *(const float4*)(h1v + (size_t)b * DIM + d0 + 4);
    float4 h2a = *(const float4*)(h2v + (size_t)b * DIM + d0);
    float4 h2b = *(const float4*)(h2v + (size_t)b * DIM + d0 + 4);
    float m1[8], m2[8];
    #pragma unroll
    for (int j = 0; j < 8; ++j) { m1[j] = -INFINITY; m2[j] = -INFINITY; }
    const int* sq = seq + (size_t)b * LL + s * 256;
    for (int it = 0; it < 16; ++it) {
        int tok = sq[g + 16 * it];
        const float4* r1 = (const float4*)(HS1 + (size_t)tok * DIM + d0);
        float4 va = r1[0], vb = r1[1];
        const float4* r2 = (const float4*)(HS2 + (size_t)tok * DIM + d0);
        float4 wa = r2[0], wb = r2[1];
        float p1 = h1a.x * va.x + h1a.y * va.y + h1a.z * va.z + h1a.w * va.w
                 + h1b.x * vb.x + h1b.y * vb.y + h1b.z * vb.z + h1b.w * vb.w;
        float p2 = h2a.x * wa.x + h2a.y * wa.y + h2a.z * wa.z + h2a.w * wa.w
                 + h2b.x * wb.x + h2b.y * wb.y + h2b.z * wb.z + h2b.w * wb.w;
        #pragma unroll
        for (int off = 8; off; off >>= 1) {
            p1 += __shfl_xor(p1, off);
            p2 += __shfl_xor(p2, off);
        }
        float w1 = tanhf(p1), w2 = tanhf(p2);
        m1[0] = fmaxf(m1[0], w1 * va.x); m1[1] = fmaxf(m1[1], w1 * va.y);
        m1[2] = fmaxf(m1[2], w1 * va.z); m1[3] = fmaxf(m1[3], w1 * va.w);
        m1[4] = fmaxf(m1[4], w1 * vb.x); m1[5] = fmaxf(m1[5], w1 * vb.y);
        m1[6] = fmaxf(m1[6], w1 * vb.z); m1[7] = fmaxf(m1[7], w1 * vb.w);
        m2[0] = fmaxf(m2[0], w2 * wa.x); m2[1] = fmaxf(m2[1], w2 * wa.y);
        m2[2] = fmaxf(m2[2], w2 * wa.z); m2[3] = fmaxf(m2[3], w2 * wa.w);
        m2[4] = fmaxf(m2[4], w2 * wb.x); m2[5] = fmaxf(m2[5], w2 * wb.y);
        m2[6] = fmaxf(m2[6], w2 * wb.z); m2[7] = fmaxf(m2[7], w2 * wb.w);
    }
    __shared__ float red[16][2][DIM];
    #pragma unroll
    for (int j = 0; j < 8; ++j) { red[g][0][d0 + j] = m1[j]; red[g][1][d0 + j] = m2[j]; }
    __syncthreads();
    int tb = t >> 7, d = t & 127;
    float mx = red[0][tb][d];
    #pragma unroll
    for (int gg = 1; gg < 16; ++gg) mx = fmaxf(mx, red[gg][tb][d]);
    Pc[(((size_t)s * BB + b) * 2 + tb) * DIM + d] = mx;
}

__global__ __launch_bounds__(256)
void cross_merge_kernel(const float* __restrict__ Pc,
                        float* __restrict__ IT1, float* __restrict__ IT2)
{
    int b = blockIdx.x, t = threadIdx.x;
    float m = -INFINITY;
    for (int s = 0; s < 8; ++s)
        m = fmaxf(m, Pc[((size_t)s * BB + b) * 256 + t]);
    if (t < DIM) IT1[(size_t)b * DIM + t] = m;
    else         IT2[(size_t)b * DIM + t - DIM] = m;
}

// ---------------------------------------------------------------------------
// MLP heads + outputs. grid: (B), block: 512 (branch z = t>>8)
__global__ __launch_bounds__(512)
void mlp_kernel(const float* __restrict__ FP2, const float* __restrict__ VR,
                const float* __restrict__ IT1, const float* __restrict__ IT2,
                const float* __restrict__ m1W, const float* __restrict__ m1b,
                const float* __restrict__ m2W, const float* __restrict__ m2b,
                const float* __restrict__ o1W, const float* __restrict__ o1b,
                const float* __restrict__ o2W, const float* __restrict__ o2b,
                const int* __restrict__ label,
                float* __restrict__ dout)
{
    int b = blockIdx.x, t = threadIdx.x;
    int z = t >> 8, tt = t & 255;
    __shared__ float x[2][256], y[2][256];
    __shared__ float pl[2][256];
    {
        const float* a0 = z ? VR : FP2;
        const float* a1 = z ? IT2 : IT1;
        x[z][tt] = (tt < 128) ? a0[(size_t)b * 128 + tt] : a1[(size_t)b * 128 + tt - 128];
    }
    __syncthreads();
    for (int Lr = 0; Lr < 3; ++Lr) {
        const float* W  = (z ? m2W : m1W) + (size_t)Lr * 256 * 256;
        const float* Bv = (z ? m2b : m1b) + (size_t)Lr * 256;
        float a = 0.f;
        for (int k = 0; k < 256; ++k) a += x[z][k] * W[k * 256 + tt];
        y[z][tt] = fmaxf(a + Bv[tt], 0.f);
        __syncthreads();
        x[z][tt] = y[z][tt];
        __syncthreads();
    }
    int j = t & 1, k2 = t >> 1;   // k2 in [0,256)
    pl[j][k2] = x[0][k2] * o1W[k2 * 2 + j] + x[1][k2] * o2W[k2 * 2 + j];
    __syncthreads();
    for (int s = 128; s > 0; s >>= 1) {
        if (k2 < s) pl[j][k2] += pl[j][k2 + s];
        __syncthreads();
    }
    if (t == 0) {
        float l0 = pl[0][0] + o1b[0] + o2b[0];
        float l1 = pl[1][0] + o1b[1] + o2b[1];
        dout[(size_t)b * 2 + 0] = l0;
        dout[(size_t)b * 2 + 1] = l1;
        dout[2 * BB + b] = (float)label[b];
        dout[3 * BB + b] = (float)((l1 > l0) ? 1 : 0);
        float mx = fmaxf(l0, l1);
        float e0 = expf(l0 - mx), e1 = expf(l1 - mx);
        dout[4 * BB + b] = e1 / (e0 + e1);
    }
}

// ---------------------------------------------------------------------------
extern "C" void kernel_launch(void* const* d_in, const int* in_sizes, int n_in,
                              void* d_out, int out_size, void* d_ws, size_t ws_size,
                              hipStream_t stream)
{
    const float* V    = (const float*)d_in[0];
    const float* A    = (const float*)d_in[1];
    const float* fp   = (const float*)d_in[2];
    const int*   msz  = (const int*)  d_in[3];
    const int*   seq  = (const int*)  d_in[4];
    const int*   lab  = (const int*)  d_in[5];
    const float* gcW1 = (const float*)d_in[6];  const float* gcb1 = (const float*)d_in[7];
    const float* gcW2 = (const float*)d_in[8];  const float* gcb2 = (const float*)d_in[9];
    const float* gcW3 = (const float*)d_in[10]; const float* gcb3 = (const float*)d_in[11];
    const float* fpW1 = (const float*)d_in[12]; const float* fpb1 = (const float*)d_in[13];
    const float* fpW2 = (const float*)d_in[14]; const float* fpb2 = (const float*)d_in[15];
    const float* attW = (const float*)d_in[16];
    const float* roW  = (const float*)d_in[17]; const float* rob  = (const float*)d_in[18];
    const float* emb  = (const float*)d_in[19];
    const float* mfpW = (const float*)d_in[20]; const float* mfpb = (const float*)d_in[21];
    const float* pfpW = (const float*)d_in[22]; const float* pfpb = (const float*)d_in[23];
    const float* mvW  = (const float*)d_in[24]; const float* mvb  = (const float*)d_in[25];
    const float* pvW  = (const float*)d_in[26]; const float* pvb  = (const float*)d_in[27];
    const float* m1W  = (const float*)d_in[28]; const float* m1b  = (const float*)d_in[29];
    const float* m2W  = (const float*)d_in[30]; const float* m2b  = (const float*)d_in[31];
    const float* o1W  = (const float*)d_in[32]; const float* o1b  = (const float*)d_in[33];
    const float* o2W  = (const float*)d_in[34]; const float* o2b  = (const float*)d_in[35];
    float* dout = (float*)d_out;

    // workspace layout
    char* ws = (char*)d_ws;
    size_t off = 0;
    auto alloc = [&](size_t bytes) -> char* {
        char* p = ws + off;
        off += (bytes + 255) & ~(size_t)255;
        return p;
    };
    u16*   Vt  = (u16*)  alloc((size_t)BB * 80 * 128 * 2);       // 5.24 MB
    u16*   Wt1 = (u16*)  alloc((size_t)256 * 256 * 2);
    u16*   Wt2 = (u16*)  alloc((size_t)256 * KB * 2);
    u16*   Wt3 = (u16*)  alloc((size_t)256 * KB * 2);
    u16*   H16 = (u16*)  alloc((size_t)BB * NN * HID * 2);       // 16.8 MB (fp16, layers 1-2)
    float* H3f = (float*)alloc((size_t)BB * NN * HID * 4);       // 33.5 MB (fp32, layer 3)
    u16*   Ht  = (u16*)  alloc((size_t)BB * HID * NN * 2);       // 16.8 MB
    float* FP2 = (float*)alloc((size_t)BB * DIM * 4);
    float* HS1 = (float*)alloc((size_t)NWORD * DIM * 4);
    float* HS2 = (float*)alloc((size_t)NWORD * DIM * 4);
    float* PO  = (float*)alloc((size_t)BB * HID * NHEAD * 4);
    float* VR  = (float*)alloc((size_t)BB * DIM * 4);
    float* H1V = (float*)alloc((size_t)BB * DIM * 4);
    float* H2V = (float*)alloc((size_t)BB * DIM * 4);
    float* IT1 = (float*)alloc((size_t)BB * DIM * 4);
    float* IT2 = (float*)alloc((size_t)BB * DIM * 4);
    float* Pc  = (float*)alloc((size_t)8 * BB * 2 * DIM * 4);    // 2.1 MB
    float* Rp  = (float*)alloc((size_t)8 * BB * DIM * 4);        // 1.0 MB
    size_t fixedBytes = off;

    // AV tier (fp16, per-b 128*768*2 = 196608 B)
    int CB = 8;
    size_t perB = (size_t)NN * KB * 2;
    {
        const int tiers[] = {256, 128, 64, 32, 16, 8, 4, 2, 1};
        for (int i = 0; i < 9; ++i)
            if (fixedBytes + (size_t)tiers[i] * perB <= ws_size) { CB = tiers[i]; break; }
    }
    u16* AV = (u16*)(ws + fixedBytes);

    // prep + independent front-end
    prepVt_kernel<<<BB, 256, 0, stream>>>(V, Vt);
    prepW_kernel<<<dim3(256, 3), 256, 0, stream>>>(gcW1, gcW2, gcW3, Wt1, Wt2, Wt3);
    fp_kernel<<<BB, 256, 0, stream>>>(fp, fpW1, fpb1, fpW2, fpb2, FP2);
    hs_kernel<<<dim3(NWORD / 2, 2), 256, 0, stream>>>(emb, pfpW, pfpb, pvW, pvb, HS1, HS2);

    // GConv layer 1 (F=75 padded to 80; gB K=240(+16 pad) -> kTiles 8)
    for (int b0 = 0; b0 < BB; b0 += CB) {
        gA_mfma<<<dim3(1, AC, CB), 256, 0, stream>>>(A, Vt, AV, b0, 80 * 128, 80, 80);
        gB_mfma<<<dim3(2, CB), 256, 0, stream>>>(AV, Wt1, gcb1, H16, H3f, b0, 8, 256, 0);
    }
    transp_kernel<<<dim3(8, 4, BB), 256, 0, stream>>>(H16, Ht);
    // layer 2
    for (int b0 = 0; b0 < BB; b0 += CB) {
        gA_mfma<<<dim3(2, AC, CB), 256, 0, stream>>>(A, Ht, AV, b0, HID * NN, 256, 128);
        gB_mfma<<<dim3(2, CB), 256, 0, stream>>>(AV, Wt2, gcb2, H16, H3f, b0, 24, KB, 0);
    }
    transp_kernel<<<dim3(8, 4, BB), 256, 0, stream>>>(H16, Ht);
    // layer 3 -> fp32 (tail of H3 exceeds fp16 max; overflow->inf->NaN flush was R5's failure)
    for (int b0 = 0; b0 < BB; b0 += CB) {
        gA_mfma<<<dim3(2, AC, CB), 256, 0, stream>>>(A, Ht, AV, b0, HID * NN, 256, 128);
        gB_mfma<<<dim3(2, CB), 256, 0, stream>>>(AV, Wt3, gcb3, H16, H3f, b0, 24, KB, 1);
    }

    pool_kernel<<<BB, 256, 0, stream>>>(H3f, attW, msz, PO);
    readout_part<<<dim3(BB, 8), 128, 0, stream>>>(PO, roW, Rp);
    readout_merge<<<BB, 128, 0, stream>>>(Rp, rob, VR);
    atth_kernel<<<dim3(BB, 2), 128, 0, stream>>>(FP2, VR, mfpW, mfpb, mvW, mvb, H1V, H2V);
    cross_part_kernel<<<dim3(BB, 8), 256, 0, stream>>>(seq, HS1, HS2, H1V, H2V, Pc);
    cross_merge_kernel<<<BB, 256, 0, stream>>>(Pc, IT1, IT2);
    mlp_kernel<<<BB, 512, 0, stream>>>(FP2, VR, IT1, IT2, m1W, m1b, m2W, m2b,
                                       o1W, o1b, o2W, o2b, lab, dout);
}

// Round 7
// 559.365 us; speedup vs baseline: 2.5606x; 1.1140x over previous
//
#include <hip/hip_runtime.h>
#include <math.h>

// Problem constants
static constexpr int BB   = 256;   // batch
static constexpr int NN   = 128;   // nodes
static constexpr int LL   = 2048;  // protein length
static constexpr int NF   = 75;
static constexpr int AC   = 3;
static constexpr int HID  = 256;
static constexpr int DIM  = 128;
static constexpr int NHEAD= 8;
static constexpr int FPD  = 679;
static constexpr int FPDP = 704;   // FPD padded to multiple of 32
static constexpr int NWORD= 8600;
static constexpr int KB   = 768;   // AV row stride (3*256)

typedef __attribute__((ext_vector_type(8))) _Float16 f16x8;
typedef __attribute__((ext_vector_type(4))) float f32x4;
typedef unsigned int u32;
typedef unsigned short u16;

__device__ __forceinline__ u16 f2h(float x) {
    _Float16 h = (_Float16)x;       // RNE
    return *(u16*)&h;
}
// saturating fp32->fp16 (avoid inf from rare tail values)
__device__ __forceinline__ u16 f2h_sat(float x) {
    x = fminf(fmaxf(x, -65000.f), 65000.f);
    _Float16 h = (_Float16)x;
    return *(u16*)&h;
}
__device__ __forceinline__ float h2f(u16 x) {
    return (float)(*(_Float16*)&x);
}

// AV intermediate is stored as fp16 scaled by 1/16 for overflow headroom.
static constexpr float AV_SCALE    = 0.0625f;
static constexpr float AV_UNSCALE  = 16.0f;

// ---------------------------------------------------------------------------
// prep: A fp32 -> fp16, same layout. grid (BB*AC), block 256.
__global__ __launch_bounds__(256)
void prepA_kernel(const float* __restrict__ A, u16* __restrict__ Ah)
{
    size_t base = (size_t)blockIdx.x * (NN * NN);
    int t = threadIdx.x;
    #pragma unroll
    for (int i = 0; i < 16; ++i) {
        int id = t + i * 256;          // 0..4095 float4s
        float4 v = *(const float4*)(A + base + (size_t)id * 4);
        u32 p0 = (u32)f2h(v.x) | ((u32)f2h(v.y) << 16);
        u32 p1 = (u32)f2h(v.z) | ((u32)f2h(v.w) << 16);
        *(uint2*)(Ah + base + (size_t)id * 4) = make_uint2(p0, p1);
    }
}

// ---------------------------------------------------------------------------
// prep: fp fp32 [256][679] -> fph fp16 [256][704] (pad 0)
__global__ __launch_bounds__(256)
void prepFp_kernel(const float* __restrict__ fp, u16* __restrict__ fph)
{
    int b = blockIdx.x, t = threadIdx.x;
    for (int i = t; i < FPDP; i += 256) {
        float v = (i < FPD) ? fp[(size_t)b * FPD + i] : 0.f;
        fph[(size_t)b * FPDP + i] = f2h(v);
    }
}

// prep: W1t fp16 [128][704], W2t fp16 [128][128] (transposed from fpW1/fpW2)
__global__ __launch_bounds__(256)
void prepFpW_kernel(const float* __restrict__ fpW1, const float* __restrict__ fpW2,
                    u16* __restrict__ W1t, u16* __restrict__ W2t)
{
    int o = blockIdx.x, z = blockIdx.y, t = threadIdx.x;
    if (z == 0) {
        for (int k = t; k < FPDP; k += 256) {
            float v = (k < FPD) ? fpW1[(size_t)k * DIM + o] : 0.f;
            W1t[(size_t)o * FPDP + k] = f2h(v);
        }
    } else {
        if (t < 128) W2t[(size_t)o * 128 + t] = f2h(fpW2[(size_t)t * DIM + o]);
    }
}

// ---------------------------------------------------------------------------
// fp chain layer 1 (MFMA): FP1h[m][d] = fp16(relu(sum_k fph[m][k]*W1t[d][k] + b1[d]))
// grid (2), block 256 (2x2 waves of 64x64).
__global__ __launch_bounds__(256)
void fp1_mfma(const u16* __restrict__ fph, const u16* __restrict__ W1t,
              const float* __restrict__ b1, u16* __restrict__ FP1h)
{
    __shared__ u16 As[128 * 40];
    __shared__ u16 Bs[128 * 40];
    int mt = blockIdx.x;
    const u16* Ap = fph + (size_t)(mt * 128) * FPDP;

    int t = threadIdx.x;
    int l = t & 63, wid = t >> 6;
    int rb = (wid >> 1) * 64, cb = (wid & 1) * 64;
    int ln = l & 15, q = l >> 4;

    f32x4 acc[4][4] = {};

    for (int kt = 0; kt < FPDP / 32; ++kt) {
        #pragma unroll
        for (int i = 0; i < 2; ++i) {
            int id = t + i * 256;
            int row = id >> 2, qh = id & 3;
            *(uint4*)&As[row * 40 + qh * 8] =
                *(const uint4*)(Ap + (size_t)row * FPDP + kt * 32 + qh * 8);
            *(uint4*)&Bs[row * 40 + qh * 8] =
                *(const uint4*)(W1t + (size_t)row * FPDP + kt * 32 + qh * 8);
        }
        __syncthreads();
        f16x8 af[4], bfr[4];
        #pragma unroll
        for (int fr = 0; fr < 4; ++fr)
            af[fr] = *(const f16x8*)&As[(rb + fr * 16 + ln) * 40 + q * 8];
        #pragma unroll
        for (int fc = 0; fc < 4; ++fc)
            bfr[fc] = *(const f16x8*)&Bs[(cb + fc * 16 + ln) * 40 + q * 8];
        #pragma unroll
        for (int fr = 0; fr < 4; ++fr)
            #pragma unroll
            for (int fc = 0; fc < 4; ++fc)
                acc[fr][fc] = __builtin_amdgcn_mfma_f32_16x16x32_f16(
                    af[fr], bfr[fc], acc[fr][fc], 0, 0, 0);
        __syncthreads();
    }
    #pragma unroll
    for (int fr = 0; fr < 4; ++fr)
        #pragma unroll
        for (int fc = 0; fc < 4; ++fc) {
            int d = cb + fc * 16 + ln;
            float bv = b1[d];
            #pragma unroll
            for (int r = 0; r < 4; ++r) {
                int m = rb + fr * 16 + q * 4 + r;
                FP1h[(size_t)(mt * 128 + m) * 128 + d] = f2h(fmaxf(acc[fr][fc][r] + bv, 0.f));
            }
        }
}

// fp chain layer 2 (MFMA): FP2[m][d] = relu(sum_k FP1h[m][k]*W2t[d][k] + b2[d])
__global__ __launch_bounds__(256)
void fp2_mfma(const u16* __restrict__ FP1h, const u16* __restrict__ W2t,
              const float* __restrict__ b2, float* __restrict__ FP2)
{
    __shared__ u16 As[128 * 40];
    __shared__ u16 Bs[128 * 40];
    int mt = blockIdx.x;
    const u16* Ap = FP1h + (size_t)(mt * 128) * 128;

    int t = threadIdx.x;
    int l = t & 63, wid = t >> 6;
    int rb = (wid >> 1) * 64, cb = (wid & 1) * 64;
    int ln = l & 15, q = l >> 4;

    f32x4 acc[4][4] = {};

    for (int kt = 0; kt < 4; ++kt) {
        #pragma unroll
        for (int i = 0; i < 2; ++i) {
            int id = t + i * 256;
            int row = id >> 2, qh = id & 3;
            *(uint4*)&As[row * 40 + qh * 8] =
                *(const uint4*)(Ap + (size_t)row * 128 + kt * 32 + qh * 8);
            *(uint4*)&Bs[row * 40 + qh * 8] =
                *(const uint4*)(W2t + (size_t)row * 128 + kt * 32 + qh * 8);
        }
        __syncthreads();
        f16x8 af[4], bfr[4];
        #pragma unroll
        for (int fr = 0; fr < 4; ++fr)
            af[fr] = *(const f16x8*)&As[(rb + fr * 16 + ln) * 40 + q * 8];
        #pragma unroll
        for (int fc = 0; fc < 4; ++fc)
            bfr[fc] = *(const f16x8*)&Bs[(cb + fc * 16 + ln) * 40 + q * 8];
        #pragma unroll
        for (int fr = 0; fr < 4; ++fr)
            #pragma unroll
            for (int fc = 0; fc < 4; ++fc)
                acc[fr][fc] = __builtin_amdgcn_mfma_f32_16x16x32_f16(
                    af[fr], bfr[fc], acc[fr][fc], 0, 0, 0);
        __syncthreads();
    }
    #pragma unroll
    for (int fr = 0; fr < 4; ++fr)
        #pragma unroll
        for (int fc = 0; fc < 4; ++fc) {
            int d = cb + fc * 16 + ln;
            float bv = b2[d];
            #pragma unroll
            for (int r = 0; r < 4; ++r) {
                int m = rb + fr * 16 + q * 4 + r;
                FP2[(size_t)(mt * 128 + m) * 128 + d] = fmaxf(acc[fr][fc][r] + bv, 0.f);
            }
        }
}

// ---------------------------------------------------------------------------
// HS tables: HS[t][d] = relu(emb[t] @ W + b), per branch.
__global__ __launch_bounds__(256)
void hs_kernel(const float* __restrict__ emb,
               const float* __restrict__ Wa, const float* __restrict__ ba,
               const float* __restrict__ Wb, const float* __restrict__ bb_,
               float* __restrict__ HS1, float* __restrict__ HS2)
{
    int br = blockIdx.y;
    const float* W  = br ? Wb : Wa;
    const float* bi = br ? bb_ : ba;
    float* HS = br ? HS2 : HS1;
    int half = threadIdx.x >> 7;
    int d = threadIdx.x & 127;
    int r = blockIdx.x * 2 + half;
    __shared__ float se[2][DIM];
    se[half][d] = emb[(size_t)r * DIM + d];
    __syncthreads();
    const float* er = se[half];
    float acc = 0.f;
    for (int k = 0; k < DIM; ++k) acc += er[k] * W[k * DIM + d];
    HS[(size_t)r * DIM + d] = fmaxf(acc + bi[d], 0.f);
}

// ---------------------------------------------------------------------------
// prep: V fp32 [b][128][75] -> Vt fp16 [b][80][128] (transposed, rows 75..79 = 0)
__global__ __launch_bounds__(256)
void prepVt_kernel(const float* __restrict__ V, u16* __restrict__ Vt)
{
    int b = blockIdx.x, t = threadIdx.x;
    __shared__ float sV[NN * NF];
    for (int i = t; i < NN * NF; i += 256) sV[i] = V[(size_t)b * (NN * NF) + i];
    __syncthreads();
    for (int i = t; i < 80 * 128; i += 256) {
        int f = i >> 7, n = i & 127;
        float v = (f < NF) ? sV[n * NF + f] : 0.f;
        Vt[(size_t)b * (80 * 128) + i] = f2h(v);
    }
}

// ---------------------------------------------------------------------------
// prep weights transposed fp16: Wt[o][k].
__global__ __launch_bounds__(256)
void prepW_kernel(const float* __restrict__ W1, const float* __restrict__ W2,
                  const float* __restrict__ W3, u16* __restrict__ Wt1,
                  u16* __restrict__ Wt2, u16* __restrict__ Wt3)
{
    int o = blockIdx.x, z = blockIdx.y, t = threadIdx.x;
    if (z == 0) {
        int k = t;   // 0..255
        int c = k / 80, f = k - c * 80;
        float v = (c < 3 && f < NF) ? W1[((size_t)c * NF + f) * HID + o] : 0.f;
        Wt1[(size_t)o * 256 + k] = f2h(v);
    } else {
        const float* W = (z == 1) ? W2 : W3;
        u16* Wt = (z == 1) ? Wt2 : Wt3;
        for (int k = t; k < KB; k += 256) {
            int c = k >> 8, f = k & 255;
            Wt[(size_t)o * KB + k] = f2h(W[((size_t)c * HID + f) * HID + o]);
        }
    }
}

// ---------------------------------------------------------------------------
// transpose: H fp16 [b][128][256] -> Ht fp16 [b][256][128]
__global__ __launch_bounds__(256)
void transp_kernel(const u16* __restrict__ H, u16* __restrict__ Ht)
{
    __shared__ u16 s[32][34];   // stride 17 banks -> conflict-free column read
    int o0 = blockIdx.x * 32, n0 = blockIdx.y * 32, b = blockIdx.z;
    int tx = threadIdx.x & 31, ty = threadIdx.x >> 5;   // ty 0..7
    const u16* Hp = H + (size_t)b * (NN * HID);
    #pragma unroll
    for (int j = 0; j < 4; ++j)
        s[ty + 8 * j][tx] = Hp[(size_t)(n0 + ty + 8 * j) * HID + o0 + tx];
    __syncthreads();
    u16* Hto = Ht + (size_t)b * (HID * NN);
    #pragma unroll
    for (int j = 0; j < 4; ++j)
        Hto[(size_t)(o0 + ty + 8 * j) * NN + n0 + tx] = s[tx][ty + 8 * j];
}

// ---------------------------------------------------------------------------
// gA (MFMA): AV[bl][n][c*fpMul + ft*128 + f] = (1/16) * sum_m Ah[b][c][n][m] * Htr[b][f'][m]
__global__ __launch_bounds__(256)
void gA_mfma(const u16* __restrict__ Agr, const u16* __restrict__ Htr,
             u16* __restrict__ AV, int b0, int htStride, int fpMul, int Fvalid)
{
    __shared__ u16 As[128 * 40];
    __shared__ u16 Bs[128 * 40];
    int ft = blockIdx.x, c = blockIdx.y, bl = blockIdx.z;
    int b = b0 + bl;
    const u16* Ap = Agr + ((size_t)b * AC + c) * (NN * NN);
    const u16* Bp = Htr + (size_t)b * htStride + ft * (128 * 128);
    u16* Cp = AV + (size_t)bl * (NN * KB) + c * fpMul + ft * 128;

    int t = threadIdx.x;
    int l = t & 63, wid = t >> 6;
    int rb = (wid >> 1) * 64, cb = (wid & 1) * 64;
    int ln = l & 15, q = l >> 4;

    f32x4 acc[4][4] = {};

    for (int kt = 0; kt < 4; ++kt) {
        // stage A tile 128x32 fp16
        #pragma unroll
        for (int i = 0; i < 2; ++i) {
            int id = t + i * 256;
            int row = id >> 2, qh = id & 3;
            *(uint4*)&As[row * 40 + qh * 8] =
                *(const uint4*)(Ap + (size_t)row * NN + kt * 32 + qh * 8);
        }
        // stage B tile 128x32 fp16 (rows >= Fvalid -> 0)
        #pragma unroll
        for (int i = 0; i < 2; ++i) {
            int id = t + i * 256;            // 0..511
            int row = id >> 2, qh = id & 3;
            uint4 v = make_uint4(0, 0, 0, 0);
            if (row < Fvalid) v = *(const uint4*)(Bp + (size_t)row * 128 + kt * 32 + qh * 8);
            *(uint4*)&Bs[row * 40 + qh * 8] = v;
        }
        __syncthreads();
        f16x8 af[4], bfr[4];
        #pragma unroll
        for (int fr = 0; fr < 4; ++fr)
            af[fr] = *(const f16x8*)&As[(rb + fr * 16 + ln) * 40 + q * 8];
        #pragma unroll
        for (int fc = 0; fc < 4; ++fc)
            bfr[fc] = *(const f16x8*)&Bs[(cb + fc * 16 + ln) * 40 + q * 8];
        #pragma unroll
        for (int fr = 0; fr < 4; ++fr)
            #pragma unroll
            for (int fc = 0; fc < 4; ++fc)
                acc[fr][fc] = __builtin_amdgcn_mfma_f32_16x16x32_f16(
                    af[fr], bfr[fc], acc[fr][fc], 0, 0, 0);
        __syncthreads();
    }
    #pragma unroll
    for (int fr = 0; fr < 4; ++fr) {
        #pragma unroll
        for (int fc = 0; fc < 4; ++fc) {
            int fcol = cb + fc * 16 + ln;
            if (fcol < Fvalid) {
                #pragma unroll
                for (int r = 0; r < 4; ++r) {
                    int n = rb + fr * 16 + q * 4 + r;
                    Cp[(size_t)n * KB + fcol] = f2h_sat(acc[fr][fc][r] * AV_SCALE);
                }
            }
        }
    }
}

// ---------------------------------------------------------------------------
// gB (MFMA): out[b][n][o] = relu( 16 * sum_k AVs[bl][n][k] * Wt[o][k] + bias[o] )
// outF32=0 -> fp16 store to H16 (layers 1,2); outF32=1 -> fp32 store to H32 (layer 3).
__global__ __launch_bounds__(256)
void gB_mfma(const u16* __restrict__ AV, const u16* __restrict__ Wt,
             const float* __restrict__ bias, u16* __restrict__ H16,
             float* __restrict__ H32,
             int b0, int kTiles, int Ks, int outF32)
{
    __shared__ u16 As[128 * 40];
    __shared__ u16 Bs[128 * 40];
    int ot = blockIdx.x, bl = blockIdx.y;
    int b = b0 + bl;
    const u16* Ap = AV + (size_t)bl * (NN * KB);
    const u16* Bp = Wt + (size_t)ot * 128 * Ks;

    int t = threadIdx.x;
    int l = t & 63, wid = t >> 6;
    int rb = (wid >> 1) * 64, cb = (wid & 1) * 64;
    int ln = l & 15, q = l >> 4;

    f32x4 acc[4][4] = {};

    for (int kt = 0; kt < kTiles; ++kt) {
        #pragma unroll
        for (int i = 0; i < 2; ++i) {
            int id = t + i * 256;
            int row = id >> 2, qh = id & 3;
            *(uint4*)&As[row * 40 + qh * 8] =
                *(const uint4*)(Ap + (size_t)row * KB + kt * 32 + qh * 8);
            *(uint4*)&Bs[row * 40 + qh * 8] =
                *(const uint4*)(Bp + (size_t)row * Ks + kt * 32 + qh * 8);
        }
        __syncthreads();
        f16x8 af[4], bfr[4];
        #pragma unroll
        for (int fr = 0; fr < 4; ++fr)
            af[fr] = *(const f16x8*)&As[(rb + fr * 16 + ln) * 40 + q * 8];
        #pragma unroll
        for (int fc = 0; fc < 4; ++fc)
            bfr[fc] = *(const f16x8*)&Bs[(cb + fc * 16 + ln) * 40 + q * 8];
        #pragma unroll
        for (int fr = 0; fr < 4; ++fr)
            #pragma unroll
            for (int fc = 0; fc < 4; ++fc)
                acc[fr][fc] = __builtin_amdgcn_mfma_f32_16x16x32_f16(
                    af[fr], bfr[fc], acc[fr][fc], 0, 0, 0);
        __syncthreads();
    }
    #pragma unroll
    for (int fr = 0; fr < 4; ++fr) {
        #pragma unroll
        for (int fc = 0; fc < 4; ++fc) {
            int oc = cb + fc * 16 + ln;
            float bv = bias[ot * 128 + oc];
            #pragma unroll
            for (int r = 0; r < 4; ++r) {
                int n = rb + fr * 16 + q * 4 + r;
                float val = fmaxf(acc[fr][fc][r] * AV_UNSCALE + bv, 0.f);
                if (outF32)
                    H32[((size_t)b * NN + n) * HID + ot * 128 + oc] = val;
                else
                    H16[((size_t)b * NN + n) * HID + ot * 128 + oc] = f2h_sat(val);
            }
        }
    }
}

// ---------------------------------------------------------------------------
// Masked multi-head attention pooling (H3 fp32). grid: (B), block: 256
__global__ __launch_bounds__(256)
void pool_kernel(const float* __restrict__ H3,
                 const float* __restrict__ attW,
                 const int* __restrict__ msz,
                 float* __restrict__ pooled)
{
    int b = blockIdx.x, t = threadIdx.x;
    __shared__ float sW[HID * NHEAD];
    __shared__ float sS[NN * NHEAD];
    __shared__ float sT[16][264];
    __shared__ float sP[16][NHEAD][2];
    for (int i = t; i < HID * NHEAD; i += 256) sW[i] = attW[i];
    __syncthreads();
    const float* Hb = H3 + (size_t)b * NN * HID;

    for (int n0 = 0; n0 < NN; n0 += 16) {
        for (int i = t; i < 16 * 64; i += 256) {
            int row = i >> 6, fq = (i & 63) * 4;
            float4 v = *(const float4*)(Hb + (size_t)(n0 + row) * HID + fq);
            *(float4*)&sT[row][fq] = v;
        }
        __syncthreads();
        {
            int nl = t >> 4, h = (t >> 1) & 7, fh = t & 1;
            float s = 0.f;
            for (int f = fh * 128; f < fh * 128 + 128; ++f)
                s += sT[nl][f] * sW[f * NHEAD + h];
            sP[nl][h][fh] = s;
        }
        __syncthreads();
        if (t < 128) {
            int n2 = t >> 3, h2 = t & 7;
            sS[(n0 + n2) * NHEAD + h2] = sP[n2][h2][0] + sP[n2][h2][1];
        }
        __syncthreads();
    }
    int ms = msz[b];
    int h = t >> 5, ln = t & 31;
    float mx = -1e9f;
    for (int n = ln; n < NN; n += 32) {
        float s = (n < ms) ? sS[n * NHEAD + h] : -1e9f;
        mx = fmaxf(mx, s);
    }
    #pragma unroll
    for (int off = 16; off; off >>= 1) mx = fmaxf(mx, __shfl_xor(mx, off, 32));
    float sum = 0.f;
    for (int n = ln; n < NN; n += 32) {
        float s = (n < ms) ? sS[n * NHEAD + h] : -1e9f;
        sum += expf(s - mx);
    }
    #pragma unroll
    for (int off = 16; off; off >>= 1) sum += __shfl_xor(sum, off, 32);
    float inv = 1.f / sum;
    for (int n = ln; n < NN; n += 32) {
        float s = (n < ms) ? sS[n * NHEAD + h] : -1e9f;
        sS[n * NHEAD + h] = expf(s - mx) * inv;
    }
    __syncthreads();
    float accp[NHEAD] = {};
    for (int n = 0; n < NN; ++n) {
        float hv = Hb[(size_t)n * HID + t];
        #pragma unroll
        for (int hh = 0; hh < NHEAD; ++hh) accp[hh] += sS[n * NHEAD + hh] * hv;
    }
    #pragma unroll
    for (int hh = 0; hh < NHEAD; ++hh)
        pooled[(size_t)b * (HID * NHEAD) + hh * HID + t] = accp[hh];
}

// ---------------------------------------------------------------------------
// Readout, k-split: Rp[s][b][d] = sum_{k in chunk s} pooled[b][k]*roW[k][d]
__global__ __launch_bounds__(128)
void readout_part(const float* __restrict__ pooled,
                  const float* __restrict__ roW,
                  float* __restrict__ Rp)
{
    int b = blockIdx.x, s = blockIdx.y, t = threadIdx.x;
    __shared__ float sx[256];
    const float* sp = pooled + (size_t)b * (HID * NHEAD) + s * 256;
    sx[t] = sp[t];
    sx[t + 128] = sp[t + 128];
    __syncthreads();
    float acc = 0.f;
    const float* W = roW + (size_t)(s * 256) * DIM + t;
    for (int k = 0; k < 256; ++k) acc += sx[k] * W[(size_t)k * DIM];
    Rp[((size_t)s * BB + b) * DIM + t] = acc;
}

__global__ __launch_bounds__(128)
void readout_merge(const float* __restrict__ Rp,
                   const float* __restrict__ rob,
                   float* __restrict__ Vr)
{
    int b = blockIdx.x, t = threadIdx.x;
    float a = rob[t];
    #pragma unroll
    for (int s = 0; s < 8; ++s) a += Rp[((size_t)s * BB + b) * DIM + t];
    Vr[(size_t)b * DIM + t] = fmaxf(a, 0.f);
}

// ---------------------------------------------------------------------------
__global__ __launch_bounds__(128)
void atth_kernel(const float* __restrict__ FP2, const float* __restrict__ VR,
                 const float* __restrict__ mfpW, const float* __restrict__ mfpb,
                 const float* __restrict__ mvW,  const float* __restrict__ mvb,
                 float* __restrict__ h1v, float* __restrict__ h2v)
{
    int b = blockIdx.x, z = blockIdx.y, t = threadIdx.x;
    const float* in = z ? VR : FP2;
    const float* W  = z ? mvW : mfpW;
    const float* bi = z ? mvb : mfpb;
    float* out = z ? h2v : h1v;
    __shared__ float sx[DIM];
    sx[t] = in[(size_t)b * DIM + t];
    __syncthreads();
    float acc = 0.f;
    for (int k = 0; k < DIM; ++k) acc += sx[k] * W[k * DIM + t];
    out[(size_t)b * DIM + t] = fmaxf(acc + bi[t], 0.f);
}

// ---------------------------------------------------------------------------
// Cross-attn partial scan: grid (B, 8). 16 groups of 16 lanes.
__global__ __launch_bounds__(256)
void cross_part_kernel(const int* __restrict__ seq,
                       const float* __restrict__ HS1, const float* __restrict__ HS2,
                       const float* __restrict__ h1v, const float* __restrict__ h2v,
                       float* __restrict__ Pc)   // [8][B][2][128]
{
    int b = blockIdx.x, s = blockIdx.y, t = threadIdx.x;
    int g = t >> 4, gl = t & 15;
    int d0 = gl * 8;
    float4 h1a = *(const float4*)(h1v + (size_t)b * DIM + d0);
    float4 h1b = *(const float4*)(h1v + (size_t)b * DIM + d0 + 4);
    float4 h2a = *(const float4*)(h2v + (size_t)b * DIM + d0);
    float4 h2b = *(const float4*)(h2v + (size_t)b * DIM + d0 + 4);
    float m1[8], m2[8];
    #pragma unroll
    for (int j = 0; j < 8; ++j) { m1[j] = -INFINITY; m2[j] = -INFINITY; }
    const int* sq = seq + (size_t)b * LL + s * 256;
    for (int it = 0; it < 16; ++it) {
        int tok = sq[g + 16 * it];
        const float4* r1 = (const float4*)(HS1 + (size_t)tok * DIM + d0);
        float4 va = r1[0], vb = r1[1];
        const float4* r2 = (const float4*)(HS2 + (size_t)tok * DIM + d0);
        float4 wa = r2[0], wb = r2[1];
        float p1 = h1a.x * va.x + h1a.y * va.y + h1a.z * va.z + h1a.w * va.w
                 + h1b.x * vb.x + h1b.y * vb.y + h1b.z * vb.z + h1b.w * vb.w;
        float p2 = h2a.x * wa.x + h2a.y * wa.y + h2a.z * wa.z + h2a.w * wa.w
                 + h2b.x * wb.x + h2b.y * wb.y + h2b.z * wb.z + h2b.w * wb.w;
        #pragma unroll
        for (int off = 8; off; off >>= 1) {
            p1 += __shfl_xor(p1, off);
            p2 += __shfl_xor(p2, off);
        }
        float w1 = tanhf(p1), w2 = tanhf(p2);
        m1[0] = fmaxf(m1[0], w1 * va.x); m1[1] = fmaxf(m1[1], w1 * va.y);
        m1[2] = fmaxf(m1[2], w1 * va.z); m1[3] = fmaxf(m1[3], w1 * va.w);
        m1[4] = fmaxf(m1[4], w1 * vb.x); m1[5] = fmaxf(m1[5], w1 * vb.y);
        m1[6] = fmaxf(m1[6], w1 * vb.z); m1[7] = fmaxf(m1[7], w1 * vb.w);
        m2[0] = fmaxf(m2[0], w2 * wa.x); m2[1] = fmaxf(m2[1], w2 * wa.y);
        m2[2] = fmaxf(m2[2], w2 * wa.z); m2[3] = fmaxf(m2[3], w2 * wa.w);
        m2[4] = fmaxf(m2[4], w2 * wb.x); m2[5] = fmaxf(m2[5], w2 * wb.y);
        m2[6] = fmaxf(m2[6], w2 * wb.z); m2[7] = fmaxf(m2[7], w2 * wb.w);
    }
    __shared__ float red[16][2][DIM];
    #pragma unroll
    for (int j = 0; j < 8; ++j) { red[g][0][d0 + j] = m1[j]; red[g][1][d0 + j] = m2[j]; }
    __syncthreads();
    int tb = t >> 7, d = t & 127;
    float mx = red[0][tb][d];
    #pragma unroll
    for (int gg = 1; gg < 16; ++gg) mx = fmaxf(mx, red[gg][tb][d]);
    Pc[(((size_t)s * BB + b) * 2 + tb) * DIM + d] = mx;
}

__global__ __launch_bounds__(256)
void cross_merge_kernel(const float* __restrict__ Pc,
                        float* __restrict__ IT1, float* __restrict__ IT2)
{
    int b = blockIdx.x, t = threadIdx.x;
    float m = -INFINITY;
    for (int s = 0; s < 8; ++s)
        m = fmaxf(m, Pc[((size_t)s * BB + b) * 256 + t]);
    if (t < DIM) IT1[(size_t)b * DIM + t] = m;
    else         IT2[(size_t)b * DIM + t - DIM] = m;
}

// ---------------------------------------------------------------------------
// MLP heads + outputs. grid: (B), block: 512 (branch z = t>>8)
__global__ __launch_bounds__(512)
void mlp_kernel(const float* __restrict__ FP2, const float* __restrict__ VR,
                const float* __restrict__ IT1, const float* __restrict__ IT2,
                const float* __restrict__ m1W, const float* __restrict__ m1b,
                const float* __restrict__ m2W, const float* __restrict__ m2b,
                const float* __restrict__ o1W, const float* __restrict__ o1b,
                const float* __restrict__ o2W, const float* __restrict__ o2b,
                const int* __restrict__ label,
                float* __restrict__ dout)
{
    int b = blockIdx.x, t = threadIdx.x;
    int z = t >> 8, tt = t & 255;
    __shared__ float x[2][256], y[2][256];
    __shared__ float pl[2][256];
    {
        const float* a0 = z ? VR : FP2;
        const float* a1 = z ? IT2 : IT1;
        x[z][tt] = (tt < 128) ? a0[(size_t)b * 128 + tt] : a1[(size_t)b * 128 + tt - 128];
    }
    __syncthreads();
    for (int Lr = 0; Lr < 3; ++Lr) {
        const float* W  = (z ? m2W : m1W) + (size_t)Lr * 256 * 256;
        const float* Bv = (z ? m2b : m1b) + (size_t)Lr * 256;
        float a = 0.f;
        for (int k = 0; k < 256; ++k) a += x[z][k] * W[k * 256 + tt];
        y[z][tt] = fmaxf(a + Bv[tt], 0.f);
        __syncthreads();
        x[z][tt] = y[z][tt];
        __syncthreads();
    }
    int j = t & 1, k2 = t >> 1;   // k2 in [0,256)
    pl[j][k2] = x[0][k2] * o1W[k2 * 2 + j] + x[1][k2] * o2W[k2 * 2 + j];
    __syncthreads();
    for (int s = 128; s > 0; s >>= 1) {
        if (k2 < s) pl[j][k2] += pl[j][k2 + s];
        __syncthreads();
    }
    if (t == 0) {
        float l0 = pl[0][0] + o1b[0] + o2b[0];
        float l1 = pl[1][0] + o1b[1] + o2b[1];
        dout[(size_t)b * 2 + 0] = l0;
        dout[(size_t)b * 2 + 1] = l1;
        dout[2 * BB + b] = (float)label[b];
        dout[3 * BB + b] = (float)((l1 > l0) ? 1 : 0);
        float mx = fmaxf(l0, l1);
        float e0 = expf(l0 - mx), e1 = expf(l1 - mx);
        dout[4 * BB + b] = e1 / (e0 + e1);
    }
}

// ---------------------------------------------------------------------------
extern "C" void kernel_launch(void* const* d_in, const int* in_sizes, int n_in,
                              void* d_out, int out_size, void* d_ws, size_t ws_size,
                              hipStream_t stream)
{
    const float* V    = (const float*)d_in[0];
    const float* A    = (const float*)d_in[1];
    const float* fp   = (const float*)d_in[2];
    const int*   msz  = (const int*)  d_in[3];
    const int*   seq  = (const int*)  d_in[4];
    const int*   lab  = (const int*)  d_in[5];
    const float* gcW1 = (const float*)d_in[6];  const float* gcb1 = (const float*)d_in[7];
    const float* gcW2 = (const float*)d_in[8];  const float* gcb2 = (const float*)d_in[9];
    const float* gcW3 = (const float*)d_in[10]; const float* gcb3 = (const float*)d_in[11];
    const float* fpW1 = (const float*)d_in[12]; const float* fpb1 = (const float*)d_in[13];
    const float* fpW2 = (const float*)d_in[14]; const float* fpb2 = (const float*)d_in[15];
    const float* attW = (const float*)d_in[16];
    const float* roW  = (const float*)d_in[17]; const float* rob  = (const float*)d_in[18];
    const float* emb  = (const float*)d_in[19];
    const float* mfpW = (const float*)d_in[20]; const float* mfpb = (const float*)d_in[21];
    const float* pfpW = (const float*)d_in[22]; const float* pfpb = (const float*)d_in[23];
    const float* mvW  = (const float*)d_in[24]; const float* mvb  = (const float*)d_in[25];
    const float* pvW  = (const float*)d_in[26]; const float* pvb  = (const float*)d_in[27];
    const float* m1W  = (const float*)d_in[28]; const float* m1b  = (const float*)d_in[29];
    const float* m2W  = (const float*)d_in[30]; const float* m2b  = (const float*)d_in[31];
    const float* o1W  = (const float*)d_in[32]; const float* o1b  = (const float*)d_in[33];
    const float* o2W  = (const float*)d_in[34]; const float* o2b  = (const float*)d_in[35];
    float* dout = (float*)d_out;

    // workspace layout
    char* ws = (char*)d_ws;
    size_t off = 0;
    auto alloc = [&](size_t bytes) -> char* {
        char* p = ws + off;
        off += (bytes + 255) & ~(size_t)255;
        return p;
    };
    u16*   Ah  = (u16*)  alloc((size_t)BB * AC * NN * NN * 2);   // 25.2 MB
    u16*   Vt  = (u16*)  alloc((size_t)BB * 80 * 128 * 2);       // 5.24 MB
    u16*   Wt1 = (u16*)  alloc((size_t)256 * 256 * 2);
    u16*   Wt2 = (u16*)  alloc((size_t)256 * KB * 2);
    u16*   Wt3 = (u16*)  alloc((size_t)256 * KB * 2);
    u16*   H16 = (u16*)  alloc((size_t)BB * NN * HID * 2);       // 16.8 MB (fp16, layers 1-2)
    float* H3f = (float*)alloc((size_t)BB * NN * HID * 4);       // 33.5 MB (fp32, layer 3)
    u16*   Ht  = (u16*)  alloc((size_t)BB * HID * NN * 2);       // 16.8 MB
    u16*   fph = (u16*)  alloc((size_t)BB * FPDP * 2);           // 360 KB
    u16*   W1t = (u16*)  alloc((size_t)DIM * FPDP * 2);          // 180 KB
    u16*   W2t = (u16*)  alloc((size_t)DIM * DIM * 2);
    u16*   FP1h= (u16*)  alloc((size_t)BB * DIM * 2);
    float* FP2 = (float*)alloc((size_t)BB * DIM * 4);
    float* HS1 = (float*)alloc((size_t)NWORD * DIM * 4);
    float* HS2 = (float*)alloc((size_t)NWORD * DIM * 4);
    float* PO  = (float*)alloc((size_t)BB * HID * NHEAD * 4);
    float* VR  = (float*)alloc((size_t)BB * DIM * 4);
    float* H1V = (float*)alloc((size_t)BB * DIM * 4);
    float* H2V = (float*)alloc((size_t)BB * DIM * 4);
    float* IT1 = (float*)alloc((size_t)BB * DIM * 4);
    float* IT2 = (float*)alloc((size_t)BB * DIM * 4);
    float* Pc  = (float*)alloc((size_t)8 * BB * 2 * DIM * 4);    // 2.1 MB
    float* Rp  = (float*)alloc((size_t)8 * BB * DIM * 4);        // 1.0 MB
    size_t fixedBytes = off;

    // AV tier (fp16, per-b 128*768*2 = 196608 B)
    int CB = 8;
    size_t perB = (size_t)NN * KB * 2;
    {
        const int tiers[] = {256, 128, 64, 32, 16, 8, 4, 2, 1};
        for (int i = 0; i < 9; ++i)
            if (fixedBytes + (size_t)tiers[i] * perB <= ws_size) { CB = tiers[i]; break; }
    }
    u16* AV = (u16*)(ws + fixedBytes);

    // prep + independent front-end
    prepA_kernel<<<BB * AC, 256, 0, stream>>>(A, Ah);
    prepVt_kernel<<<BB, 256, 0, stream>>>(V, Vt);
    prepW_kernel<<<dim3(256, 3), 256, 0, stream>>>(gcW1, gcW2, gcW3, Wt1, Wt2, Wt3);
    prepFp_kernel<<<BB, 256, 0, stream>>>(fp, fph);
    prepFpW_kernel<<<dim3(128, 2), 256, 0, stream>>>(fpW1, fpW2, W1t, W2t);
    fp1_mfma<<<2, 256, 0, stream>>>(fph, W1t, fpb1, FP1h);
    fp2_mfma<<<2, 256, 0, stream>>>(FP1h, W2t, fpb2, FP2);
    hs_kernel<<<dim3(NWORD / 2, 2), 256, 0, stream>>>(emb, pfpW, pfpb, pvW, pvb, HS1, HS2);

    // GConv layer 1 (F=75 padded to 80; gB K=240(+16 pad) -> kTiles 8)
    for (int b0 = 0; b0 < BB; b0 += CB) {
        gA_mfma<<<dim3(1, AC, CB), 256, 0, stream>>>(Ah, Vt, AV, b0, 80 * 128, 80, 80);
        gB_mfma<<<dim3(2, CB), 256, 0, stream>>>(AV, Wt1, gcb1, H16, H3f, b0, 8, 256, 0);
    }
    transp_kernel<<<dim3(8, 4, BB), 256, 0, stream>>>(H16, Ht);
    // layer 2
    for (int b0 = 0; b0 < BB; b0 += CB) {
        gA_mfma<<<dim3(2, AC, CB), 256, 0, stream>>>(Ah, Ht, AV, b0, HID * NN, 256, 128);
        gB_mfma<<<dim3(2, CB), 256, 0, stream>>>(AV, Wt2, gcb2, H16, H3f, b0, 24, KB, 0);
    }
    transp_kernel<<<dim3(8, 4, BB), 256, 0, stream>>>(H16, Ht);
    // layer 3 -> fp32 (fp16 tail overflow was R5's failure)
    for (int b0 = 0; b0 < BB; b0 += CB) {
        gA_mfma<<<dim3(2, AC, CB), 256, 0, stream>>>(Ah, Ht, AV, b0, HID * NN, 256, 128);
        gB_mfma<<<dim3(2, CB), 256, 0, stream>>>(AV, Wt3, gcb3, H16, H3f, b0, 24, KB, 1);
    }

    pool_kernel<<<BB, 256, 0, stream>>>(H3f, attW, msz, PO);
    readout_part<<<dim3(BB, 8), 128, 0, stream>>>(PO, roW, Rp);
    readout_merge<<<BB, 128, 0, stream>>>(Rp, rob, VR);
    atth_kernel<<<dim3(BB, 2), 128, 0, stream>>>(FP2, VR, mfpW, mfpb, mvW, mvb, H1V, H2V);
    cross_part_kernel<<<dim3(BB, 8), 256, 0, stream>>>(seq, HS1, HS2, H1V, H2V, Pc);
    cross_merge_kernel<<<BB, 256, 0, stream>>>(Pc, IT1, IT2);
    mlp_kernel<<<BB, 512, 0, stream>>>(FP2, VR, IT1, IT2, m1W, m1b, m2W, m2b,
                                       o1W, o1b, o2W, o2b, lab, dout);
}

// Round 8
// 535.900 us; speedup vs baseline: 2.6727x; 1.0438x over previous
//
#include <hip/hip_runtime.h>
#include <math.h>

// Problem constants
static constexpr int BB   = 256;   // batch
static constexpr int NN   = 128;   // nodes
static constexpr int LL   = 2048;  // protein length
static constexpr int NF   = 75;
static constexpr int AC   = 3;
static constexpr int HID  = 256;
static constexpr int DIM  = 128;
static constexpr int NHEAD= 8;
static constexpr int FPD  = 679;
static constexpr int FPDP = 704;   // FPD padded to multiple of 32
static constexpr int NWORD= 8600;
static constexpr int NWP  = 8704;  // NWORD padded to 68*128
static constexpr int KB   = 768;   // AV row stride (3*256)

typedef __attribute__((ext_vector_type(8))) _Float16 f16x8;
typedef __attribute__((ext_vector_type(4))) float f32x4;
typedef unsigned int u32;
typedef unsigned short u16;

__device__ __forceinline__ u16 f2h(float x) {
    _Float16 h = (_Float16)x;       // RNE
    return *(u16*)&h;
}
// saturating fp32->fp16 (avoid inf from rare tail values)
__device__ __forceinline__ u16 f2h_sat(float x) {
    x = fminf(fmaxf(x, -65000.f), 65000.f);
    _Float16 h = (_Float16)x;
    return *(u16*)&h;
}
__device__ __forceinline__ float h2f(u16 x) {
    return (float)(*(_Float16*)&x);
}

// fp16-carried intermediates with large range are stored scaled by 1/16.
static constexpr float SC   = 0.0625f;
static constexpr float USC  = 16.0f;

// ---------------------------------------------------------------------------
// prep: A fp32 -> fp16, same layout. grid (BB*AC), block 256.
__global__ __launch_bounds__(256)
void prepA_kernel(const float* __restrict__ A, u16* __restrict__ Ah)
{
    size_t base = (size_t)blockIdx.x * (NN * NN);
    int t = threadIdx.x;
    #pragma unroll
    for (int i = 0; i < 16; ++i) {
        int id = t + i * 256;          // 0..4095 float4s
        float4 v = *(const float4*)(A + base + (size_t)id * 4);
        u32 p0 = (u32)f2h(v.x) | ((u32)f2h(v.y) << 16);
        u32 p1 = (u32)f2h(v.z) | ((u32)f2h(v.w) << 16);
        *(uint2*)(Ah + base + (size_t)id * 4) = make_uint2(p0, p1);
    }
}

// ---------------------------------------------------------------------------
// prep: fp fp32 [256][679] -> fph fp16 [256][704] (pad 0)
__global__ __launch_bounds__(256)
void prepFp_kernel(const float* __restrict__ fp, u16* __restrict__ fph)
{
    int b = blockIdx.x, t = threadIdx.x;
    for (int i = t; i < FPDP; i += 256) {
        float v = (i < FPD) ? fp[(size_t)b * FPD + i] : 0.f;
        fph[(size_t)b * FPDP + i] = f2h(v);
    }
}

// prep: W1t fp16 [128][704], W2t fp16 [128][128] (transposed from fpW1/fpW2)
__global__ __launch_bounds__(256)
void prepFpW_kernel(const float* __restrict__ fpW1, const float* __restrict__ fpW2,
                    u16* __restrict__ W1t, u16* __restrict__ W2t)
{
    int o = blockIdx.x, z = blockIdx.y, t = threadIdx.x;
    if (z == 0) {
        for (int k = t; k < FPDP; k += 256) {
            float v = (k < FPD) ? fpW1[(size_t)k * DIM + o] : 0.f;
            W1t[(size_t)o * FPDP + k] = f2h(v);
        }
    } else {
        if (t < 128) W2t[(size_t)o * 128 + t] = f2h(fpW2[(size_t)t * DIM + o]);
    }
}

// prep: 4x [128][128] transposes fp32->fp16 (pfpW, pvW, mfpW, mvW)
__global__ __launch_bounds__(128)
void prepCrossW_kernel(const float* __restrict__ pfpW, const float* __restrict__ pvW,
                       const float* __restrict__ mfpW, const float* __restrict__ mvW,
                       u16* __restrict__ pWt12, u16* __restrict__ mWt12)
{
    int o = blockIdx.x, z = blockIdx.y, t = threadIdx.x;
    const float* W = (z == 0) ? pfpW : (z == 1) ? pvW : (z == 2) ? mfpW : mvW;
    u16* Wt = (z < 2) ? (pWt12 + (size_t)z * 128 * 128)
                      : (mWt12 + (size_t)(z - 2) * 128 * 128);
    Wt[(size_t)o * 128 + t] = f2h(W[(size_t)t * 128 + o]);
}

// prep: MLP weights transposed fp16: Wmlp[br][Lr][o][k]
__global__ __launch_bounds__(256)
void prepMlpW_kernel(const float* __restrict__ m1W, const float* __restrict__ m2W,
                     u16* __restrict__ Wmlp)
{
    int o = blockIdx.x, Lr = blockIdx.y, br = blockIdx.z, t = threadIdx.x;
    const float* W = (br ? m2W : m1W) + (size_t)Lr * 256 * 256;
    Wmlp[(((size_t)(br * 3 + Lr)) * 256 + o) * 256 + t] = f2h(W[(size_t)t * 256 + o]);
}

// ---------------------------------------------------------------------------
// fp chain layer 1 (MFMA): FP1h[m][d] = fp16(relu(sum_k fph[m][k]*W1t[d][k] + b1[d]))
__global__ __launch_bounds__(256)
void fp1_mfma(const u16* __restrict__ fph, const u16* __restrict__ W1t,
              const float* __restrict__ b1, u16* __restrict__ FP1h)
{
    __shared__ u16 As[128 * 40];
    __shared__ u16 Bs[128 * 40];
    int mt = blockIdx.x;
    const u16* Ap = fph + (size_t)(mt * 128) * FPDP;

    int t = threadIdx.x;
    int l = t & 63, wid = t >> 6;
    int rb = (wid >> 1) * 64, cb = (wid & 1) * 64;
    int ln = l & 15, q = l >> 4;

    f32x4 acc[4][4] = {};

    for (int kt = 0; kt < FPDP / 32; ++kt) {
        #pragma unroll
        for (int i = 0; i < 2; ++i) {
            int id = t + i * 256;
            int row = id >> 2, qh = id & 3;
            *(uint4*)&As[row * 40 + qh * 8] =
                *(const uint4*)(Ap + (size_t)row * FPDP + kt * 32 + qh * 8);
            *(uint4*)&Bs[row * 40 + qh * 8] =
                *(const uint4*)(W1t + (size_t)row * FPDP + kt * 32 + qh * 8);
        }
        __syncthreads();
        f16x8 af[4], bfr[4];
        #pragma unroll
        for (int fr = 0; fr < 4; ++fr)
            af[fr] = *(const f16x8*)&As[(rb + fr * 16 + ln) * 40 + q * 8];
        #pragma unroll
        for (int fc = 0; fc < 4; ++fc)
            bfr[fc] = *(const f16x8*)&Bs[(cb + fc * 16 + ln) * 40 + q * 8];
        #pragma unroll
        for (int fr = 0; fr < 4; ++fr)
            #pragma unroll
            for (int fc = 0; fc < 4; ++fc)
                acc[fr][fc] = __builtin_amdgcn_mfma_f32_16x16x32_f16(
                    af[fr], bfr[fc], acc[fr][fc], 0, 0, 0);
        __syncthreads();
    }
    #pragma unroll
    for (int fr = 0; fr < 4; ++fr)
        #pragma unroll
        for (int fc = 0; fc < 4; ++fc) {
            int d = cb + fc * 16 + ln;
            float bv = b1[d];
            #pragma unroll
            for (int r = 0; r < 4; ++r) {
                int m = rb + fr * 16 + q * 4 + r;
                FP1h[(size_t)(mt * 128 + m) * 128 + d] = f2h(fmaxf(acc[fr][fc][r] + bv, 0.f));
            }
        }
}

// fp chain layer 2 (MFMA): FP2 fp32 + FP2h fp16
__global__ __launch_bounds__(256)
void fp2_mfma(const u16* __restrict__ FP1h, const u16* __restrict__ W2t,
              const float* __restrict__ b2, float* __restrict__ FP2,
              u16* __restrict__ FP2h)
{
    __shared__ u16 As[128 * 40];
    __shared__ u16 Bs[128 * 40];
    int mt = blockIdx.x;
    const u16* Ap = FP1h + (size_t)(mt * 128) * 128;

    int t = threadIdx.x;
    int l = t & 63, wid = t >> 6;
    int rb = (wid >> 1) * 64, cb = (wid & 1) * 64;
    int ln = l & 15, q = l >> 4;

    f32x4 acc[4][4] = {};

    for (int kt = 0; kt < 4; ++kt) {
        #pragma unroll
        for (int i = 0; i < 2; ++i) {
            int id = t + i * 256;
            int row = id >> 2, qh = id & 3;
            *(uint4*)&As[row * 40 + qh * 8] =
                *(const uint4*)(Ap + (size_t)row * 128 + kt * 32 + qh * 8);
            *(uint4*)&Bs[row * 40 + qh * 8] =
                *(const uint4*)(W2t + (size_t)row * 128 + kt * 32 + qh * 8);
        }
        __syncthreads();
        f16x8 af[4], bfr[4];
        #pragma unroll
        for (int fr = 0; fr < 4; ++fr)
            af[fr] = *(const f16x8*)&As[(rb + fr * 16 + ln) * 40 + q * 8];
        #pragma unroll
        for (int fc = 0; fc < 4; ++fc)
            bfr[fc] = *(const f16x8*)&Bs[(cb + fc * 16 + ln) * 40 + q * 8];
        #pragma unroll
        for (int fr = 0; fr < 4; ++fr)
            #pragma unroll
            for (int fc = 0; fc < 4; ++fc)
                acc[fr][fc] = __builtin_amdgcn_mfma_f32_16x16x32_f16(
                    af[fr], bfr[fc], acc[fr][fc], 0, 0, 0);
        __syncthreads();
    }
    #pragma unroll
    for (int fr = 0; fr < 4; ++fr)
        #pragma unroll
        for (int fc = 0; fc < 4; ++fc) {
            int d = cb + fc * 16 + ln;
            float bv = b2[d];
            #pragma unroll
            for (int r = 0; r < 4; ++r) {
                int m = rb + fr * 16 + q * 4 + r;
                float val = fmaxf(acc[fr][fc][r] + bv, 0.f);
                FP2 [(size_t)(mt * 128 + m) * 128 + d] = val;
                FP2h[(size_t)(mt * 128 + m) * 128 + d] = f2h(val);
            }
        }
}

// ---------------------------------------------------------------------------
// HS12 tables (MFMA): HS12[r][br*128+d] = fp16(relu(emb[r]@pW_br + b_br[d]))
// grid (NWP/128, 2), block 256.
__global__ __launch_bounds__(256)
void hs12_mfma(const float* __restrict__ emb, const u16* __restrict__ pWt12,
               const float* __restrict__ ba, const float* __restrict__ bb_,
               u16* __restrict__ HS12)
{
    __shared__ u16 As[128 * 40];
    __shared__ u16 Bs[128 * 40];
    int ft = blockIdx.x, br = blockIdx.y;
    const u16* Bp = pWt12 + (size_t)br * 128 * 128;
    const float* bias = br ? bb_ : ba;
    int r0 = ft * 128;

    int t = threadIdx.x;
    int l = t & 63, wid = t >> 6;
    int rb = (wid >> 1) * 64, cb = (wid & 1) * 64;
    int ln = l & 15, q = l >> 4;

    f32x4 acc[4][4] = {};

    for (int kt = 0; kt < 4; ++kt) {
        // stage A tile 128x32 fp32 -> fp16 (rows >= NWORD -> 0)
        #pragma unroll
        for (int i = 0; i < 4; ++i) {
            int id = t + i * 256;            // 0..1023
            int row = id >> 3, qf = id & 7;
            int r = r0 + row;
            float4 v = make_float4(0.f, 0.f, 0.f, 0.f);
            if (r < NWORD) v = *(const float4*)(emb + (size_t)r * 128 + kt * 32 + qf * 4);
            u32 p0 = (u32)f2h(v.x) | ((u32)f2h(v.y) << 16);
            u32 p1 = (u32)f2h(v.z) | ((u32)f2h(v.w) << 16);
            u32* dst = (u32*)&As[row * 40 + qf * 4];
            dst[0] = p0; dst[1] = p1;
        }
        #pragma unroll
        for (int i = 0; i < 2; ++i) {
            int id = t + i * 256;
            int row = id >> 2, qh = id & 3;
            *(uint4*)&Bs[row * 40 + qh * 8] =
                *(const uint4*)(Bp + (size_t)row * 128 + kt * 32 + qh * 8);
        }
        __syncthreads();
        f16x8 af[4], bfr[4];
        #pragma unroll
        for (int fr = 0; fr < 4; ++fr)
            af[fr] = *(const f16x8*)&As[(rb + fr * 16 + ln) * 40 + q * 8];
        #pragma unroll
        for (int fc = 0; fc < 4; ++fc)
            bfr[fc] = *(const f16x8*)&Bs[(cb + fc * 16 + ln) * 40 + q * 8];
        #pragma unroll
        for (int fr = 0; fr < 4; ++fr)
            #pragma unroll
            for (int fc = 0; fc < 4; ++fc)
                acc[fr][fc] = __builtin_amdgcn_mfma_f32_16x16x32_f16(
                    af[fr], bfr[fc], acc[fr][fc], 0, 0, 0);
        __syncthreads();
    }
    #pragma unroll
    for (int fr = 0; fr < 4; ++fr)
        #pragma unroll
        for (int fc = 0; fc < 4; ++fc) {
            int d = cb + fc * 16 + ln;
            float bv = bias[d];
            #pragma unroll
            for (int r = 0; r < 4; ++r) {
                int m = rb + fr * 16 + q * 4 + r;
                int rr = r0 + m;
                if (rr < NWORD)
                    HS12[(size_t)rr * 256 + br * 128 + d] = f2h(fmaxf(acc[fr][fc][r] + bv, 0.f));
            }
        }
}

// ---------------------------------------------------------------------------
// prep: V fp32 [b][128][75] -> Vt fp16 [b][80][128] (transposed, rows 75..79 = 0)
__global__ __launch_bounds__(256)
void prepVt_kernel(const float* __restrict__ V, u16* __restrict__ Vt)
{
    int b = blockIdx.x, t = threadIdx.x;
    __shared__ float sV[NN * NF];
    for (int i = t; i < NN * NF; i += 256) sV[i] = V[(size_t)b * (NN * NF) + i];
    __syncthreads();
    for (int i = t; i < 80 * 128; i += 256) {
        int f = i >> 7, n = i & 127;
        float v = (f < NF) ? sV[n * NF + f] : 0.f;
        Vt[(size_t)b * (80 * 128) + i] = f2h(v);
    }
}

// ---------------------------------------------------------------------------
// prep weights transposed fp16: Wt[o][k].
__global__ __launch_bounds__(256)
void prepW_kernel(const float* __restrict__ W1, const float* __restrict__ W2,
                  const float* __restrict__ W3, u16* __restrict__ Wt1,
                  u16* __restrict__ Wt2, u16* __restrict__ Wt3)
{
    int o = blockIdx.x, z = blockIdx.y, t = threadIdx.x;
    if (z == 0) {
        int k = t;   // 0..255
        int c = k / 80, f = k - c * 80;
        float v = (c < 3 && f < NF) ? W1[((size_t)c * NF + f) * HID + o] : 0.f;
        Wt1[(size_t)o * 256 + k] = f2h(v);
    } else {
        const float* W = (z == 1) ? W2 : W3;
        u16* Wt = (z == 1) ? Wt2 : Wt3;
        for (int k = t; k < KB; k += 256) {
            int c = k >> 8, f = k & 255;
            Wt[(size_t)o * KB + k] = f2h(W[((size_t)c * HID + f) * HID + o]);
        }
    }
}

// ---------------------------------------------------------------------------
// transpose: H fp16 [b][128][256] -> Ht fp16 [b][256][128]
__global__ __launch_bounds__(256)
void transp_kernel(const u16* __restrict__ H, u16* __restrict__ Ht)
{
    __shared__ u16 s[32][34];
    int o0 = blockIdx.x * 32, n0 = blockIdx.y * 32, b = blockIdx.z;
    int tx = threadIdx.x & 31, ty = threadIdx.x >> 5;
    const u16* Hp = H + (size_t)b * (NN * HID);
    #pragma unroll
    for (int j = 0; j < 4; ++j)
        s[ty + 8 * j][tx] = Hp[(size_t)(n0 + ty + 8 * j) * HID + o0 + tx];
    __syncthreads();
    u16* Hto = Ht + (size_t)b * (HID * NN);
    #pragma unroll
    for (int j = 0; j < 4; ++j)
        Hto[(size_t)(o0 + ty + 8 * j) * NN + n0 + tx] = s[tx][ty + 8 * j];
}

// ---------------------------------------------------------------------------
// gA (MFMA): AV[bl][n][c*fpMul + ft*128 + f] = (1/16) * sum_m Ah[b][c][n][m] * Htr[b][f'][m]
__global__ __launch_bounds__(256)
void gA_mfma(const u16* __restrict__ Agr, const u16* __restrict__ Htr,
             u16* __restrict__ AV, int b0, int htStride, int fpMul, int Fvalid)
{
    __shared__ u16 As[128 * 40];
    __shared__ u16 Bs[128 * 40];
    int ft = blockIdx.x, c = blockIdx.y, bl = blockIdx.z;
    int b = b0 + bl;
    const u16* Ap = Agr + ((size_t)b * AC + c) * (NN * NN);
    const u16* Bp = Htr + (size_t)b * htStride + ft * (128 * 128);
    u16* Cp = AV + (size_t)bl * (NN * KB) + c * fpMul + ft * 128;

    int t = threadIdx.x;
    int l = t & 63, wid = t >> 6;
    int rb = (wid >> 1) * 64, cb = (wid & 1) * 64;
    int ln = l & 15, q = l >> 4;

    f32x4 acc[4][4] = {};

    for (int kt = 0; kt < 4; ++kt) {
        #pragma unroll
        for (int i = 0; i < 2; ++i) {
            int id = t + i * 256;
            int row = id >> 2, qh = id & 3;
            *(uint4*)&As[row * 40 + qh * 8] =
                *(const uint4*)(Ap + (size_t)row * NN + kt * 32 + qh * 8);
        }
        #pragma unroll
        for (int i = 0; i < 2; ++i) {
            int id = t + i * 256;
            int row = id >> 2, qh = id & 3;
            uint4 v = make_uint4(0, 0, 0, 0);
            if (row < Fvalid) v = *(const uint4*)(Bp + (size_t)row * 128 + kt * 32 + qh * 8);
            *(uint4*)&Bs[row * 40 + qh * 8] = v;
        }
        __syncthreads();
        f16x8 af[4], bfr[4];
        #pragma unroll
        for (int fr = 0; fr < 4; ++fr)
            af[fr] = *(const f16x8*)&As[(rb + fr * 16 + ln) * 40 + q * 8];
        #pragma unroll
        for (int fc = 0; fc < 4; ++fc)
            bfr[fc] = *(const f16x8*)&Bs[(cb + fc * 16 + ln) * 40 + q * 8];
        #pragma unroll
        for (int fr = 0; fr < 4; ++fr)
            #pragma unroll
            for (int fc = 0; fc < 4; ++fc)
                acc[fr][fc] = __builtin_amdgcn_mfma_f32_16x16x32_f16(
                    af[fr], bfr[fc], acc[fr][fc], 0, 0, 0);
        __syncthreads();
    }
    #pragma unroll
    for (int fr = 0; fr < 4; ++fr) {
        #pragma unroll
        for (int fc = 0; fc < 4; ++fc) {
            int fcol = cb + fc * 16 + ln;
            if (fcol < Fvalid) {
                #pragma unroll
                for (int r = 0; r < 4; ++r) {
                    int n = rb + fr * 16 + q * 4 + r;
                    Cp[(size_t)n * KB + fcol] = f2h_sat(acc[fr][fc][r] * SC);
                }
            }
        }
    }
}

// ---------------------------------------------------------------------------
// gB (MFMA): out[b][n][o] = relu( 16 * sum_k AVs[bl][n][k] * Wt[o][k] + bias[o] )
__global__ __launch_bounds__(256)
void gB_mfma(const u16* __restrict__ AV, const u16* __restrict__ Wt,
             const float* __restrict__ bias, u16* __restrict__ H16,
             float* __restrict__ H32,
             int b0, int kTiles, int Ks, int outF32)
{
    __shared__ u16 As[128 * 40];
    __shared__ u16 Bs[128 * 40];
    int ot = blockIdx.x, bl = blockIdx.y;
    int b = b0 + bl;
    const u16* Ap = AV + (size_t)bl * (NN * KB);
    const u16* Bp = Wt + (size_t)ot * 128 * Ks;

    int t = threadIdx.x;
    int l = t & 63, wid = t >> 6;
    int rb = (wid >> 1) * 64, cb = (wid & 1) * 64;
    int ln = l & 15, q = l >> 4;

    f32x4 acc[4][4] = {};

    for (int kt = 0; kt < kTiles; ++kt) {
        #pragma unroll
        for (int i = 0; i < 2; ++i) {
            int id = t + i * 256;
            int row = id >> 2, qh = id & 3;
            *(uint4*)&As[row * 40 + qh * 8] =
                *(const uint4*)(Ap + (size_t)row * KB + kt * 32 + qh * 8);
            *(uint4*)&Bs[row * 40 + qh * 8] =
                *(const uint4*)(Bp + (size_t)row * Ks + kt * 32 + qh * 8);
        }
        __syncthreads();
        f16x8 af[4], bfr[4];
        #pragma unroll
        for (int fr = 0; fr < 4; ++fr)
            af[fr] = *(const f16x8*)&As[(rb + fr * 16 + ln) * 40 + q * 8];
        #pragma unroll
        for (int fc = 0; fc < 4; ++fc)
            bfr[fc] = *(const f16x8*)&Bs[(cb + fc * 16 + ln) * 40 + q * 8];
        #pragma unroll
        for (int fr = 0; fr < 4; ++fr)
            #pragma unroll
            for (int fc = 0; fc < 4; ++fc)
                acc[fr][fc] = __builtin_amdgcn_mfma_f32_16x16x32_f16(
                    af[fr], bfr[fc], acc[fr][fc], 0, 0, 0);
        __syncthreads();
    }
    #pragma unroll
    for (int fr = 0; fr < 4; ++fr) {
        #pragma unroll
        for (int fc = 0; fc < 4; ++fc) {
            int oc = cb + fc * 16 + ln;
            float bv = bias[ot * 128 + oc];
            #pragma unroll
            for (int r = 0; r < 4; ++r) {
                int n = rb + fr * 16 + q * 4 + r;
                float val = fmaxf(acc[fr][fc][r] * USC + bv, 0.f);
                if (outF32)
                    H32[((size_t)b * NN + n) * HID + ot * 128 + oc] = val;
                else
                    H16[((size_t)b * NN + n) * HID + ot * 128 + oc] = f2h_sat(val);
            }
        }
    }
}

// ---------------------------------------------------------------------------
// Masked multi-head attention pooling (H3 fp32). grid: (B), block: 256
__global__ __launch_bounds__(256)
void pool_kernel(const float* __restrict__ H3,
                 const float* __restrict__ attW,
                 const int* __restrict__ msz,
                 float* __restrict__ pooled)
{
    int b = blockIdx.x, t = threadIdx.x;
    __shared__ float sW[HID * NHEAD];
    __shared__ float sS[NN * NHEAD];
    __shared__ float sT[16][264];
    __shared__ float sP[16][NHEAD][2];
    for (int i = t; i < HID * NHEAD; i += 256) sW[i] = attW[i];
    __syncthreads();
    const float* Hb = H3 + (size_t)b * NN * HID;

    for (int n0 = 0; n0 < NN; n0 += 16) {
        for (int i = t; i < 16 * 64; i += 256) {
            int row = i >> 6, fq = (i & 63) * 4;
            float4 v = *(const float4*)(Hb + (size_t)(n0 + row) * HID + fq);
            *(float4*)&sT[row][fq] = v;
        }
        __syncthreads();
        {
            int nl = t >> 4, h = (t >> 1) & 7, fh = t & 1;
            float s = 0.f;
            for (int f = fh * 128; f < fh * 128 + 128; ++f)
                s += sT[nl][f] * sW[f * NHEAD + h];
            sP[nl][h][fh] = s;
        }
        __syncthreads();
        if (t < 128) {
            int n2 = t >> 3, h2 = t & 7;
            sS[(n0 + n2) * NHEAD + h2] = sP[n2][h2][0] + sP[n2][h2][1];
        }
        __syncthreads();
    }
    int ms = msz[b];
    int h = t >> 5, ln = t & 31;
    float mx = -1e9f;
    for (int n = ln; n < NN; n += 32) {
        float s = (n < ms) ? sS[n * NHEAD + h] : -1e9f;
        mx = fmaxf(mx, s);
    }
    #pragma unroll
    for (int off = 16; off; off >>= 1) mx = fmaxf(mx, __shfl_xor(mx, off, 32));
    float sum = 0.f;
    for (int n = ln; n < NN; n += 32) {
        float s = (n < ms) ? sS[n * NHEAD + h] : -1e9f;
        sum += expf(s - mx);
    }
    #pragma unroll
    for (int off = 16; off; off >>= 1) sum += __shfl_xor(sum, off, 32);
    float inv = 1.f / sum;
    for (int n = ln; n < NN; n += 32) {
        float s = (n < ms) ? sS[n * NHEAD + h] : -1e9f;
        sS[n * NHEAD + h] = expf(s - mx) * inv;
    }
    __syncthreads();
    float accp[NHEAD] = {};
    for (int n = 0; n < NN; ++n) {
        float hv = Hb[(size_t)n * HID + t];
        #pragma unroll
        for (int hh = 0; hh < NHEAD; ++hh) accp[hh] += sS[n * NHEAD + hh] * hv;
    }
    #pragma unroll
    for (int hh = 0; hh < NHEAD; ++hh)
        pooled[(size_t)b * (HID * NHEAD) + hh * HID + t] = accp[hh];
}

// ---------------------------------------------------------------------------
// Readout, k-split
__global__ __launch_bounds__(128)
void readout_part(const float* __restrict__ pooled,
                  const float* __restrict__ roW,
                  float* __restrict__ Rp)
{
    int b = blockIdx.x, s = blockIdx.y, t = threadIdx.x;
    __shared__ float sx[256];
    const float* sp = pooled + (size_t)b * (HID * NHEAD) + s * 256;
    sx[t] = sp[t];
    sx[t + 128] = sp[t + 128];
    __syncthreads();
    float acc = 0.f;
    const float* W = roW + (size_t)(s * 256) * DIM + t;
    for (int k = 0; k < 256; ++k) acc += sx[k] * W[(size_t)k * DIM];
    Rp[((size_t)s * BB + b) * DIM + t] = acc;
}

__global__ __launch_bounds__(128)
void readout_merge(const float* __restrict__ Rp,
                   const float* __restrict__ rob,
                   float* __restrict__ Vr, u16* __restrict__ Vrh)
{
    int b = blockIdx.x, t = threadIdx.x;
    float a = rob[t];
    #pragma unroll
    for (int s = 0; s < 8; ++s) a += Rp[((size_t)s * BB + b) * DIM + t];
    float v = fmaxf(a, 0.f);
    Vr [(size_t)b * DIM + t] = v;
    Vrh[(size_t)b * DIM + t] = f2h_sat(v * SC);   // scaled 1/16
}

// ---------------------------------------------------------------------------
// atth (MFMA): h_br = relu(X_br @ W_br + b_br). br=0: X=FP2h (unscaled);
// br=1: X=VRh (scaled 1/16 -> unscale 16 in epilogue). grid (2 mt, 2 br).
__global__ __launch_bounds__(256)
void atth_mfma(const u16* __restrict__ FP2h, const u16* __restrict__ VRh,
               const u16* __restrict__ mWt12,
               const float* __restrict__ mfpb, const float* __restrict__ mvb,
               float* __restrict__ h1v, float* __restrict__ h2v)
{
    __shared__ u16 As[128 * 40];
    __shared__ u16 Bs[128 * 40];
    int mt = blockIdx.x, br = blockIdx.y;
    const u16* Ap = (br ? VRh : FP2h) + (size_t)(mt * 128) * 128;
    const u16* Bp = mWt12 + (size_t)br * 128 * 128;
    const float* bias = br ? mvb : mfpb;
    float unsc = br ? USC : 1.f;
    float* out = br ? h2v : h1v;

    int t = threadIdx.x;
    int l = t & 63, wid = t >> 6;
    int rb = (wid >> 1) * 64, cb = (wid & 1) * 64;
    int ln = l & 15, q = l >> 4;

    f32x4 acc[4][4] = {};

    for (int kt = 0; kt < 4; ++kt) {
        #pragma unroll
        for (int i = 0; i < 2; ++i) {
            int id = t + i * 256;
            int row = id >> 2, qh = id & 3;
            *(uint4*)&As[row * 40 + qh * 8] =
                *(const uint4*)(Ap + (size_t)row * 128 + kt * 32 + qh * 8);
            *(uint4*)&Bs[row * 40 + qh * 8] =
                *(const uint4*)(Bp + (size_t)row * 128 + kt * 32 + qh * 8);
        }
        __syncthreads();
        f16x8 af[4], bfr[4];
        #pragma unroll
        for (int fr = 0; fr < 4; ++fr)
            af[fr] = *(const f16x8*)&As[(rb + fr * 16 + ln) * 40 + q * 8];
        #pragma unroll
        for (int fc = 0; fc < 4; ++fc)
            bfr[fc] = *(const f16x8*)&Bs[(cb + fc * 16 + ln) * 40 + q * 8];
        #pragma unroll
        for (int fr = 0; fr < 4; ++fr)
            #pragma unroll
            for (int fc = 0; fc < 4; ++fc)
                acc[fr][fc] = __builtin_amdgcn_mfma_f32_16x16x32_f16(
                    af[fr], bfr[fc], acc[fr][fc], 0, 0, 0);
        __syncthreads();
    }
    #pragma unroll
    for (int fr = 0; fr < 4; ++fr)
        #pragma unroll
        for (int fc = 0; fc < 4; ++fc) {
            int d = cb + fc * 16 + ln;
            float bv = bias[d];
            #pragma unroll
            for (int r = 0; r < 4; ++r) {
                int m = rb + fr * 16 + q * 4 + r;
                out[(size_t)(mt * 128 + m) * 128 + d] = fmaxf(acc[fr][fc][r] * unsc + bv, 0.f);
            }
        }
}

// ---------------------------------------------------------------------------
// Cross-attn partial scan over fp16 interleaved tables. grid (B, 8).
__global__ __launch_bounds__(256)
void cross_part_kernel(const int* __restrict__ seq,
                       const u16* __restrict__ HS12,
                       const float* __restrict__ h1v, const float* __restrict__ h2v,
                       float* __restrict__ Pc)   // [8][B][2][128]
{
    int b = blockIdx.x, s = blockIdx.y, t = threadIdx.x;
    int g = t >> 4, gl = t & 15;
    int d0 = gl * 8;
    float h1[8], h2[8];
    #pragma unroll
    for (int j = 0; j < 8; ++j) {
        h1[j] = h1v[(size_t)b * DIM + d0 + j];
        h2[j] = h2v[(size_t)b * DIM + d0 + j];
    }
    float m1[8], m2[8];
    #pragma unroll
    for (int j = 0; j < 8; ++j) { m1[j] = -INFINITY; m2[j] = -INFINITY; }
    const int* sq = seq + (size_t)b * LL + s * 256;
    for (int it = 0; it < 16; ++it) {
        int tok = sq[g + 16 * it];
        const u16* r12 = HS12 + (size_t)tok * 256 + d0;
        f16x8 va16 = *(const f16x8*)(r12);         // branch 0
        f16x8 vb16 = *(const f16x8*)(r12 + 128);   // branch 1
        float va[8], vb[8];
        float p1 = 0.f, p2 = 0.f;
        #pragma unroll
        for (int j = 0; j < 8; ++j) {
            va[j] = (float)va16[j];
            vb[j] = (float)vb16[j];
            p1 += h1[j] * va[j];
            p2 += h2[j] * vb[j];
        }
        #pragma unroll
        for (int off = 8; off; off >>= 1) {
            p1 += __shfl_xor(p1, off);
            p2 += __shfl_xor(p2, off);
        }
        float w1 = tanhf(p1), w2 = tanhf(p2);
        #pragma unroll
        for (int j = 0; j < 8; ++j) {
            m1[j] = fmaxf(m1[j], w1 * va[j]);
            m2[j] = fmaxf(m2[j], w2 * vb[j]);
        }
    }
    __shared__ float red[16][2][DIM];
    #pragma unroll
    for (int j = 0; j < 8; ++j) { red[g][0][d0 + j] = m1[j]; red[g][1][d0 + j] = m2[j]; }
    __syncthreads();
    int tb = t >> 7, d = t & 127;
    float mx = red[0][tb][d];
    #pragma unroll
    for (int gg = 1; gg < 16; ++gg) mx = fmaxf(mx, red[gg][tb][d]);
    Pc[(((size_t)s * BB + b) * 2 + tb) * DIM + d] = mx;
}

__global__ __launch_bounds__(256)
void cross_merge_kernel(const float* __restrict__ Pc,
                        float* __restrict__ IT1, float* __restrict__ IT2)
{
    int b = blockIdx.x, t = threadIdx.x;
    float m = -INFINITY;
    for (int s = 0; s < 8; ++s)
        m = fmaxf(m, Pc[((size_t)s * BB + b) * 256 + t]);
    if (t < DIM) IT1[(size_t)b * DIM + t] = m;
    else         IT2[(size_t)b * DIM + t - DIM] = m;
}

// ---------------------------------------------------------------------------
// MLP as batch GEMMs. Xh layout: [br][256 batch][256], values scaled 1/16.
__global__ __launch_bounds__(256)
void prepX_kernel(const float* __restrict__ FP2, const float* __restrict__ VR,
                  const float* __restrict__ IT1, const float* __restrict__ IT2,
                  u16* __restrict__ Xh)
{
    int b = blockIdx.x, br = blockIdx.y, t = threadIdx.x;
    const float* a0 = br ? VR : FP2;
    const float* a1 = br ? IT2 : IT1;
    float v = (t < 128) ? a0[(size_t)b * 128 + t] : a1[(size_t)b * 128 + t - 128];
    Xh[((size_t)br * BB + b) * 256 + t] = f2h_sat(v * SC);
}

// one MLP layer: Y = relu(X@W+b), in/out scaled 1/16. grid (2 mt, 2 ot, 2 br).
__global__ __launch_bounds__(256)
void mlpL_mfma(const u16* __restrict__ X, const u16* __restrict__ Wmlp,
               const float* __restrict__ m1b, const float* __restrict__ m2b,
               int Lr, u16* __restrict__ Y)
{
    __shared__ u16 As[128 * 40];
    __shared__ u16 Bs[128 * 40];
    int mt = blockIdx.x, ot = blockIdx.y, br = blockIdx.z;
    const u16* Ap = X + ((size_t)br * BB + mt * 128) * 256;
    const u16* Bp = Wmlp + (((size_t)(br * 3 + Lr)) * 256 + ot * 128) * 256;
    const float* bias = (br ? m2b : m1b) + (size_t)Lr * 256 + ot * 128;

    int t = threadIdx.x;
    int l = t & 63, wid = t >> 6;
    int rb = (wid >> 1) * 64, cb = (wid & 1) * 64;
    int ln = l & 15, q = l >> 4;

    f32x4 acc[4][4] = {};

    for (int kt = 0; kt < 8; ++kt) {
        #pragma unroll
        for (int i = 0; i < 2; ++i) {
            int id = t + i * 256;
            int row = id >> 2, qh = id & 3;
            *(uint4*)&As[row * 40 + qh * 8] =
                *(const uint4*)(Ap + (size_t)row * 256 + kt * 32 + qh * 8);
            *(uint4*)&Bs[row * 40 + qh * 8] =
                *(const uint4*)(Bp + (size_t)row * 256 + kt * 32 + qh * 8);
        }
        __syncthreads();
        f16x8 af[4], bfr[4];
        #pragma unroll
        for (int fr = 0; fr < 4; ++fr)
            af[fr] = *(const f16x8*)&As[(rb + fr * 16 + ln) * 40 + q * 8];
        #pragma unroll
        for (int fc = 0; fc < 4; ++fc)
            bfr[fc] = *(const f16x8*)&Bs[(cb + fc * 16 + ln) * 40 + q * 8];
        #pragma unroll
        for (int fr = 0; fr < 4; ++fr)
            #pragma unroll
            for (int fc = 0; fc < 4; ++fc)
                acc[fr][fc] = __builtin_amdgcn_mfma_f32_16x16x32_f16(
                    af[fr], bfr[fc], acc[fr][fc], 0, 0, 0);
        __syncthreads();
    }
    // stored y = relu(16*acc + b)/16 = relu(acc + b/16)
    #pragma unroll
    for (int fr = 0; fr < 4; ++fr)
        #pragma unroll
        for (int fc = 0; fc < 4; ++fc) {
            int oc = cb + fc * 16 + ln;
            float bv = bias[oc] * SC;
            #pragma unroll
            for (int r = 0; r < 4; ++r) {
                int m = rb + fr * 16 + q * 4 + r;
                Y[((size_t)br * BB + (mt * 128 + m)) * 256 + ot * 128 + oc] =
                    f2h_sat(fmaxf(acc[fr][fc][r] + bv, 0.f));
            }
        }
}

// head + outputs. grid (BB), block 256.
__global__ __launch_bounds__(256)
void mlp_out_kernel(const u16* __restrict__ Y,
                    const float* __restrict__ o1W, const float* __restrict__ o1b,
                    const float* __restrict__ o2W, const float* __restrict__ o2b,
                    const int* __restrict__ label,
                    float* __restrict__ dout)
{
    int b = blockIdx.x, t = threadIdx.x;
    __shared__ float pl[2][128];
    const u16* y1 = Y + (size_t)b * 256;
    const u16* y2 = Y + ((size_t)BB + b) * 256;
    int j = t & 1, k2 = t >> 1;   // k2 in [0,128)
    float p = USC * (h2f(y1[k2])       * o1W[k2 * 2 + j]
                   + h2f(y1[k2 + 128]) * o1W[(k2 + 128) * 2 + j]
                   + h2f(y2[k2])       * o2W[k2 * 2 + j]
                   + h2f(y2[k2 + 128]) * o2W[(k2 + 128) * 2 + j]);
    pl[j][k2] = p;
    __syncthreads();
    for (int s = 64; s > 0; s >>= 1) {
        if (k2 < s) pl[j][k2] += pl[j][k2 + s];
        __syncthreads();
    }
    if (t == 0) {
        float l0 = pl[0][0] + o1b[0] + o2b[0];
        float l1 = pl[1][0] + o1b[1] + o2b[1];
        dout[(size_t)b * 2 + 0] = l0;
        dout[(size_t)b * 2 + 1] = l1;
        dout[2 * BB + b] = (float)label[b];
        dout[3 * BB + b] = (float)((l1 > l0) ? 1 : 0);
        float mx = fmaxf(l0, l1);
        float e0 = expf(l0 - mx), e1 = expf(l1 - mx);
        dout[4 * BB + b] = e1 / (e0 + e1);
    }
}

// ---------------------------------------------------------------------------
extern "C" void kernel_launch(void* const* d_in, const int* in_sizes, int n_in,
                              void* d_out, int out_size, void* d_ws, size_t ws_size,
                              hipStream_t stream)
{
    const float* V    = (const float*)d_in[0];
    const float* A    = (const float*)d_in[1];
    const float* fp   = (const float*)d_in[2];
    const int*   msz  = (const int*)  d_in[3];
    const int*   seq  = (const int*)  d_in[4];
    const int*   lab  = (const int*)  d_in[5];
    const float* gcW1 = (const float*)d_in[6];  const float* gcb1 = (const float*)d_in[7];
    const float* gcW2 = (const float*)d_in[8];  const float* gcb2 = (const float*)d_in[9];
    const float* gcW3 = (const float*)d_in[10]; const float* gcb3 = (const float*)d_in[11];
    const float* fpW1 = (const float*)d_in[12]; const float* fpb1 = (const float*)d_in[13];
    const float* fpW2 = (const float*)d_in[14]; const float* fpb2 = (const float*)d_in[15];
    const float* attW = (const float*)d_in[16];
    const float* roW  = (const float*)d_in[17]; const float* rob  = (const float*)d_in[18];
    const float* emb  = (const float*)d_in[19];
    const float* mfpW = (const float*)d_in[20]; const float* mfpb = (const float*)d_in[21];
    const float* pfpW = (const float*)d_in[22]; const float* pfpb = (const float*)d_in[23];
    const float* mvW  = (const float*)d_in[24]; const float* mvb  = (const float*)d_in[25];
    const float* pvW  = (const float*)d_in[26]; const float* pvb  = (const float*)d_in[27];
    const float* m1W  = (const float*)d_in[28]; const float* m1b  = (const float*)d_in[29];
    const float* m2W  = (const float*)d_in[30]; const float* m2b  = (const float*)d_in[31];
    const float* o1W  = (const float*)d_in[32]; const float* o1b  = (const float*)d_in[33];
    const float* o2W  = (const float*)d_in[34]; const float* o2b  = (const float*)d_in[35];
    float* dout = (float*)d_out;

    // workspace layout
    char* ws = (char*)d_ws;
    size_t off = 0;
    auto alloc = [&](size_t bytes) -> char* {
        char* p = ws + off;
        off += (bytes + 255) & ~(size_t)255;
        return p;
    };
    u16*   Ah    = (u16*)  alloc((size_t)BB * AC * NN * NN * 2);   // 25.2 MB
    u16*   Vt    = (u16*)  alloc((size_t)BB * 80 * 128 * 2);       // 5.24 MB
    u16*   Wt1   = (u16*)  alloc((size_t)256 * 256 * 2);
    u16*   Wt2   = (u16*)  alloc((size_t)256 * KB * 2);
    u16*   Wt3   = (u16*)  alloc((size_t)256 * KB * 2);
    u16*   H16   = (u16*)  alloc((size_t)BB * NN * HID * 2);       // 16.8 MB
    float* H3f   = (float*)alloc((size_t)BB * NN * HID * 4);       // 33.5 MB
    u16*   Ht    = (u16*)  alloc((size_t)BB * HID * NN * 2);       // 16.8 MB
    u16*   fph   = (u16*)  alloc((size_t)BB * FPDP * 2);
    u16*   W1t   = (u16*)  alloc((size_t)DIM * FPDP * 2);
    u16*   W2t   = (u16*)  alloc((size_t)DIM * DIM * 2);
    u16*   FP1h  = (u16*)  alloc((size_t)BB * DIM * 2);
    float* FP2   = (float*)alloc((size_t)BB * DIM * 4);
    u16*   FP2h  = (u16*)  alloc((size_t)BB * DIM * 2);
    u16*   pWt12 = (u16*)  alloc((size_t)2 * 128 * 128 * 2);
    u16*   mWt12 = (u16*)  alloc((size_t)2 * 128 * 128 * 2);
    u16*   HS12  = (u16*)  alloc((size_t)NWP * 256 * 2);           // 4.45 MB
    float* PO    = (float*)alloc((size_t)BB * HID * NHEAD * 4);
    float* VR    = (float*)alloc((size_t)BB * DIM * 4);
    u16*   VRh   = (u16*)  alloc((size_t)BB * DIM * 2);
    float* H1V   = (float*)alloc((size_t)BB * DIM * 4);
    float* H2V   = (float*)alloc((size_t)BB * DIM * 4);
    float* IT1   = (float*)alloc((size_t)BB * DIM * 4);
    float* IT2   = (float*)alloc((size_t)BB * DIM * 4);
    float* Pc    = (float*)alloc((size_t)8 * BB * 2 * DIM * 4);
    float* Rp    = (float*)alloc((size_t)8 * BB * DIM * 4);
    u16*   Wmlp  = (u16*)  alloc((size_t)2 * 3 * 256 * 256 * 2);   // 786 KB
    u16*   Xa    = (u16*)  alloc((size_t)2 * BB * 256 * 2);        // 256 KB
    u16*   Xb    = (u16*)  alloc((size_t)2 * BB * 256 * 2);
    size_t fixedBytes = off;

    // AV tier (fp16, per-b 128*768*2 = 196608 B)
    int CB = 8;
    size_t perB = (size_t)NN * KB * 2;
    {
        const int tiers[] = {256, 128, 64, 32, 16, 8, 4, 2, 1};
        for (int i = 0; i < 9; ++i)
            if (fixedBytes + (size_t)tiers[i] * perB <= ws_size) { CB = tiers[i]; break; }
    }
    u16* AV = (u16*)(ws + fixedBytes);

    // prep + independent front-end
    prepA_kernel<<<BB * AC, 256, 0, stream>>>(A, Ah);
    prepVt_kernel<<<BB, 256, 0, stream>>>(V, Vt);
    prepW_kernel<<<dim3(256, 3), 256, 0, stream>>>(gcW1, gcW2, gcW3, Wt1, Wt2, Wt3);
    prepFp_kernel<<<BB, 256, 0, stream>>>(fp, fph);
    prepFpW_kernel<<<dim3(128, 2), 256, 0, stream>>>(fpW1, fpW2, W1t, W2t);
    prepCrossW_kernel<<<dim3(128, 4), 128, 0, stream>>>(pfpW, pvW, mfpW, mvW, pWt12, mWt12);
    prepMlpW_kernel<<<dim3(256, 3, 2), 256, 0, stream>>>(m1W, m2W, Wmlp);
    fp1_mfma<<<2, 256, 0, stream>>>(fph, W1t, fpb1, FP1h);
    fp2_mfma<<<2, 256, 0, stream>>>(FP1h, W2t, fpb2, FP2, FP2h);
    hs12_mfma<<<dim3(NWP / 128, 2), 256, 0, stream>>>(emb, pWt12, pfpb, pvb, HS12);

    // GConv layer 1 (F=75 padded to 80; gB K=240(+16 pad) -> kTiles 8)
    for (int b0 = 0; b0 < BB; b0 += CB) {
        gA_mfma<<<dim3(1, AC, CB), 256, 0, stream>>>(Ah, Vt, AV, b0, 80 * 128, 80, 80);
        gB_mfma<<<dim3(2, CB), 256, 0, stream>>>(AV, Wt1, gcb1, H16, H3f, b0, 8, 256, 0);
    }
    transp_kernel<<<dim3(8, 4, BB), 256, 0, stream>>>(H16, Ht);
    // layer 2
    for (int b0 = 0; b0 < BB; b0 += CB) {
        gA_mfma<<<dim3(2, AC, CB), 256, 0, stream>>>(Ah, Ht, AV, b0, HID * NN, 256, 128);
        gB_mfma<<<dim3(2, CB), 256, 0, stream>>>(AV, Wt2, gcb2, H16, H3f, b0, 24, KB, 0);
    }
    transp_kernel<<<dim3(8, 4, BB), 256, 0, stream>>>(H16, Ht);
    // layer 3 -> fp32 (fp16 tail overflow was R5's failure)
    for (int b0 = 0; b0 < BB; b0 += CB) {
        gA_mfma<<<dim3(2, AC, CB), 256, 0, stream>>>(Ah, Ht, AV, b0, HID * NN, 256, 128);
        gB_mfma<<<dim3(2, CB), 256, 0, stream>>>(AV, Wt3, gcb3, H16, H3f, b0, 24, KB, 1);
    }

    pool_kernel<<<BB, 256, 0, stream>>>(H3f, attW, msz, PO);
    readout_part<<<dim3(BB, 8), 128, 0, stream>>>(PO, roW, Rp);
    readout_merge<<<BB, 128, 0, stream>>>(Rp, rob, VR, VRh);
    atth_mfma<<<dim3(2, 2), 256, 0, stream>>>(FP2h, VRh, mWt12, mfpb, mvb, H1V, H2V);
    cross_part_kernel<<<dim3(BB, 8), 256, 0, stream>>>(seq, HS12, H1V, H2V, Pc);
    cross_merge_kernel<<<BB, 256, 0, stream>>>(Pc, IT1, IT2);
    prepX_kernel<<<dim3(BB, 2), 256, 0, stream>>>(FP2, VR, IT1, IT2, Xa);
    mlpL_mfma<<<dim3(2, 2, 2), 256, 0, stream>>>(Xa, Wmlp, m1b, m2b, 0, Xb);
    mlpL_mfma<<<dim3(2, 2, 2), 256, 0, stream>>>(Xb, Wmlp, m1b, m2b, 1, Xa);
    mlpL_mfma<<<dim3(2, 2, 2), 256, 0, stream>>>(Xa, Wmlp, m1b, m2b, 2, Xb);
    mlp_out_kernel<<<BB, 256, 0, stream>>>(Xb, o1W, o1b, o2W, o2b, lab, dout);
}

// Round 9
// 507.601 us; speedup vs baseline: 2.8217x; 1.0557x over previous
//
#include <hip/hip_runtime.h>
#include <math.h>

// Problem constants
static constexpr int BB   = 256;   // batch
static constexpr int NN   = 128;   // nodes
static constexpr int LL   = 2048;  // protein length
static constexpr int NF   = 75;
static constexpr int AC   = 3;
static constexpr int HID  = 256;
static constexpr int DIM  = 128;
static constexpr int NHEAD= 8;
static constexpr int FPD  = 679;
static constexpr int FPDP = 704;   // FPD padded to multiple of 32
static constexpr int NWORD= 8600;
static constexpr int NWP  = 8704;  // NWORD padded to 68*128
static constexpr int KB   = 768;   // AV row stride (3*256)

typedef __attribute__((ext_vector_type(8))) _Float16 f16x8;
typedef __attribute__((ext_vector_type(4))) float f32x4;
typedef unsigned int u32;
typedef unsigned short u16;

__device__ __forceinline__ u16 f2h(float x) {
    _Float16 h = (_Float16)x;       // RNE
    return *(u16*)&h;
}
// saturating fp32->fp16 (avoid inf from rare tail values)
__device__ __forceinline__ u16 f2h_sat(float x) {
    x = fminf(fmaxf(x, -65000.f), 65000.f);
    _Float16 h = (_Float16)x;
    return *(u16*)&h;
}
__device__ __forceinline__ float h2f(u16 x) {
    return (float)(*(_Float16*)&x);
}

// fp16-carried intermediates with large range are stored scaled by 1/16.
static constexpr float SC   = 0.0625f;
static constexpr float USC  = 16.0f;

// ---------------------------------------------------------------------------
// prep: A fp32 -> fp16, same layout. grid (BB*AC), block 256.
__global__ __launch_bounds__(256)
void prepA_kernel(const float* __restrict__ A, u16* __restrict__ Ah)
{
    size_t base = (size_t)blockIdx.x * (NN * NN);
    int t = threadIdx.x;
    #pragma unroll
    for (int i = 0; i < 16; ++i) {
        int id = t + i * 256;          // 0..4095 float4s
        float4 v = *(const float4*)(A + base + (size_t)id * 4);
        u32 p0 = (u32)f2h(v.x) | ((u32)f2h(v.y) << 16);
        u32 p1 = (u32)f2h(v.z) | ((u32)f2h(v.w) << 16);
        *(uint2*)(Ah + base + (size_t)id * 4) = make_uint2(p0, p1);
    }
}

// ---------------------------------------------------------------------------
// prep: fp fp32 [256][679] -> fph fp16 [256][704] (pad 0)
__global__ __launch_bounds__(256)
void prepFp_kernel(const float* __restrict__ fp, u16* __restrict__ fph)
{
    int b = blockIdx.x, t = threadIdx.x;
    for (int i = t; i < FPDP; i += 256) {
        float v = (i < FPD) ? fp[(size_t)b * FPD + i] : 0.f;
        fph[(size_t)b * FPDP + i] = f2h(v);
    }
}

// prep: W1t fp16 [128][704], W2t fp16 [128][128] (transposed from fpW1/fpW2)
__global__ __launch_bounds__(256)
void prepFpW_kernel(const float* __restrict__ fpW1, const float* __restrict__ fpW2,
                    u16* __restrict__ W1t, u16* __restrict__ W2t)
{
    int o = blockIdx.x, z = blockIdx.y, t = threadIdx.x;
    if (z == 0) {
        for (int k = t; k < FPDP; k += 256) {
            float v = (k < FPD) ? fpW1[(size_t)k * DIM + o] : 0.f;
            W1t[(size_t)o * FPDP + k] = f2h(v);
        }
    } else {
        if (t < 128) W2t[(size_t)o * 128 + t] = f2h(fpW2[(size_t)t * DIM + o]);
    }
}

// prep: 4x [128][128] transposes fp32->fp16 (pfpW, pvW, mfpW, mvW)
__global__ __launch_bounds__(128)
void prepCrossW_kernel(const float* __restrict__ pfpW, const float* __restrict__ pvW,
                       const float* __restrict__ mfpW, const float* __restrict__ mvW,
                       u16* __restrict__ pWt12, u16* __restrict__ mWt12)
{
    int o = blockIdx.x, z = blockIdx.y, t = threadIdx.x;
    const float* W = (z == 0) ? pfpW : (z == 1) ? pvW : (z == 2) ? mfpW : mvW;
    u16* Wt = (z < 2) ? (pWt12 + (size_t)z * 128 * 128)
                      : (mWt12 + (size_t)(z - 2) * 128 * 128);
    Wt[(size_t)o * 128 + t] = f2h(W[(size_t)t * 128 + o]);
}

// prep: MLP weights transposed fp16: Wmlp[br][Lr][o][k]
__global__ __launch_bounds__(256)
void prepMlpW_kernel(const float* __restrict__ m1W, const float* __restrict__ m2W,
                     u16* __restrict__ Wmlp)
{
    int o = blockIdx.x, Lr = blockIdx.y, br = blockIdx.z, t = threadIdx.x;
    const float* W = (br ? m2W : m1W) + (size_t)Lr * 256 * 256;
    Wmlp[(((size_t)(br * 3 + Lr)) * 256 + o) * 256 + t] = f2h(W[(size_t)t * 256 + o]);
}

// ---------------------------------------------------------------------------
// fp chain layer 1 (MFMA)
__global__ __launch_bounds__(256)
void fp1_mfma(const u16* __restrict__ fph, const u16* __restrict__ W1t,
              const float* __restrict__ b1, u16* __restrict__ FP1h)
{
    __shared__ u16 As[128 * 40];
    __shared__ u16 Bs[128 * 40];
    int mt = blockIdx.x;
    const u16* Ap = fph + (size_t)(mt * 128) * FPDP;

    int t = threadIdx.x;
    int l = t & 63, wid = t >> 6;
    int rb = (wid >> 1) * 64, cb = (wid & 1) * 64;
    int ln = l & 15, q = l >> 4;

    f32x4 acc[4][4] = {};

    for (int kt = 0; kt < FPDP / 32; ++kt) {
        #pragma unroll
        for (int i = 0; i < 2; ++i) {
            int id = t + i * 256;
            int row = id >> 2, qh = id & 3;
            *(uint4*)&As[row * 40 + qh * 8] =
                *(const uint4*)(Ap + (size_t)row * FPDP + kt * 32 + qh * 8);
            *(uint4*)&Bs[row * 40 + qh * 8] =
                *(const uint4*)(W1t + (size_t)row * FPDP + kt * 32 + qh * 8);
        }
        __syncthreads();
        f16x8 af[4], bfr[4];
        #pragma unroll
        for (int fr = 0; fr < 4; ++fr)
            af[fr] = *(const f16x8*)&As[(rb + fr * 16 + ln) * 40 + q * 8];
        #pragma unroll
        for (int fc = 0; fc < 4; ++fc)
            bfr[fc] = *(const f16x8*)&Bs[(cb + fc * 16 + ln) * 40 + q * 8];
        #pragma unroll
        for (int fr = 0; fr < 4; ++fr)
            #pragma unroll
            for (int fc = 0; fc < 4; ++fc)
                acc[fr][fc] = __builtin_amdgcn_mfma_f32_16x16x32_f16(
                    af[fr], bfr[fc], acc[fr][fc], 0, 0, 0);
        __syncthreads();
    }
    #pragma unroll
    for (int fr = 0; fr < 4; ++fr)
        #pragma unroll
        for (int fc = 0; fc < 4; ++fc) {
            int d = cb + fc * 16 + ln;
            float bv = b1[d];
            #pragma unroll
            for (int r = 0; r < 4; ++r) {
                int m = rb + fr * 16 + q * 4 + r;
                FP1h[(size_t)(mt * 128 + m) * 128 + d] = f2h(fmaxf(acc[fr][fc][r] + bv, 0.f));
            }
        }
}

// fp chain layer 2 (MFMA): FP2 fp32 + FP2h fp16
__global__ __launch_bounds__(256)
void fp2_mfma(const u16* __restrict__ FP1h, const u16* __restrict__ W2t,
              const float* __restrict__ b2, float* __restrict__ FP2,
              u16* __restrict__ FP2h)
{
    __shared__ u16 As[128 * 40];
    __shared__ u16 Bs[128 * 40];
    int mt = blockIdx.x;
    const u16* Ap = FP1h + (size_t)(mt * 128) * 128;

    int t = threadIdx.x;
    int l = t & 63, wid = t >> 6;
    int rb = (wid >> 1) * 64, cb = (wid & 1) * 64;
    int ln = l & 15, q = l >> 4;

    f32x4 acc[4][4] = {};

    for (int kt = 0; kt < 4; ++kt) {
        #pragma unroll
        for (int i = 0; i < 2; ++i) {
            int id = t + i * 256;
            int row = id >> 2, qh = id & 3;
            *(uint4*)&As[row * 40 + qh * 8] =
                *(const uint4*)(Ap + (size_t)row * 128 + kt * 32 + qh * 8);
            *(uint4*)&Bs[row * 40 + qh * 8] =
                *(const uint4*)(W2t + (size_t)row * 128 + kt * 32 + qh * 8);
        }
        __syncthreads();
        f16x8 af[4], bfr[4];
        #pragma unroll
        for (int fr = 0; fr < 4; ++fr)
            af[fr] = *(const f16x8*)&As[(rb + fr * 16 + ln) * 40 + q * 8];
        #pragma unroll
        for (int fc = 0; fc < 4; ++fc)
            bfr[fc] = *(const f16x8*)&Bs[(cb + fc * 16 + ln) * 40 + q * 8];
        #pragma unroll
        for (int fr = 0; fr < 4; ++fr)
            #pragma unroll
            for (int fc = 0; fc < 4; ++fc)
                acc[fr][fc] = __builtin_amdgcn_mfma_f32_16x16x32_f16(
                    af[fr], bfr[fc], acc[fr][fc], 0, 0, 0);
        __syncthreads();
    }
    #pragma unroll
    for (int fr = 0; fr < 4; ++fr)
        #pragma unroll
        for (int fc = 0; fc < 4; ++fc) {
            int d = cb + fc * 16 + ln;
            float bv = b2[d];
            #pragma unroll
            for (int r = 0; r < 4; ++r) {
                int m = rb + fr * 16 + q * 4 + r;
                float val = fmaxf(acc[fr][fc][r] + bv, 0.f);
                FP2 [(size_t)(mt * 128 + m) * 128 + d] = val;
                FP2h[(size_t)(mt * 128 + m) * 128 + d] = f2h(val);
            }
        }
}

// ---------------------------------------------------------------------------
// HS12 tables (MFMA): HS12[r][br*128+d] = fp16(relu(emb[r]@pW_br + b_br[d]))
__global__ __launch_bounds__(256)
void hs12_mfma(const float* __restrict__ emb, const u16* __restrict__ pWt12,
               const float* __restrict__ ba, const float* __restrict__ bb_,
               u16* __restrict__ HS12)
{
    __shared__ u16 As[128 * 40];
    __shared__ u16 Bs[128 * 40];
    int ft = blockIdx.x, br = blockIdx.y;
    const u16* Bp = pWt12 + (size_t)br * 128 * 128;
    const float* bias = br ? bb_ : ba;
    int r0 = ft * 128;

    int t = threadIdx.x;
    int l = t & 63, wid = t >> 6;
    int rb = (wid >> 1) * 64, cb = (wid & 1) * 64;
    int ln = l & 15, q = l >> 4;

    f32x4 acc[4][4] = {};

    for (int kt = 0; kt < 4; ++kt) {
        #pragma unroll
        for (int i = 0; i < 4; ++i) {
            int id = t + i * 256;
            int row = id >> 3, qf = id & 7;
            int r = r0 + row;
            float4 v = make_float4(0.f, 0.f, 0.f, 0.f);
            if (r < NWORD) v = *(const float4*)(emb + (size_t)r * 128 + kt * 32 + qf * 4);
            u32 p0 = (u32)f2h(v.x) | ((u32)f2h(v.y) << 16);
            u32 p1 = (u32)f2h(v.z) | ((u32)f2h(v.w) << 16);
            u32* dst = (u32*)&As[row * 40 + qf * 4];
            dst[0] = p0; dst[1] = p1;
        }
        #pragma unroll
        for (int i = 0; i < 2; ++i) {
            int id = t + i * 256;
            int row = id >> 2, qh = id & 3;
            *(uint4*)&Bs[row * 40 + qh * 8] =
                *(const uint4*)(Bp + (size_t)row * 128 + kt * 32 + qh * 8);
        }
        __syncthreads();
        f16x8 af[4], bfr[4];
        #pragma unroll
        for (int fr = 0; fr < 4; ++fr)
            af[fr] = *(const f16x8*)&As[(rb + fr * 16 + ln) * 40 + q * 8];
        #pragma unroll
        for (int fc = 0; fc < 4; ++fc)
            bfr[fc] = *(const f16x8*)&Bs[(cb + fc * 16 + ln) * 40 + q * 8];
        #pragma unroll
        for (int fr = 0; fr < 4; ++fr)
            #pragma unroll
            for (int fc = 0; fc < 4; ++fc)
                acc[fr][fc] = __builtin_amdgcn_mfma_f32_16x16x32_f16(
                    af[fr], bfr[fc], acc[fr][fc], 0, 0, 0);
        __syncthreads();
    }
    #pragma unroll
    for (int fr = 0; fr < 4; ++fr)
        #pragma unroll
        for (int fc = 0; fc < 4; ++fc) {
            int d = cb + fc * 16 + ln;
            float bv = bias[d];
            #pragma unroll
            for (int r = 0; r < 4; ++r) {
                int m = rb + fr * 16 + q * 4 + r;
                int rr = r0 + m;
                if (rr < NWORD)
                    HS12[(size_t)rr * 256 + br * 128 + d] = f2h(fmaxf(acc[fr][fc][r] + bv, 0.f));
            }
        }
}

// ---------------------------------------------------------------------------
// prep: V fp32 [b][128][75] -> Vt fp16 [b][80][128] (transposed, rows 75..79 = 0)
__global__ __launch_bounds__(256)
void prepVt_kernel(const float* __restrict__ V, u16* __restrict__ Vt)
{
    int b = blockIdx.x, t = threadIdx.x;
    __shared__ float sV[NN * NF];
    for (int i = t; i < NN * NF; i += 256) sV[i] = V[(size_t)b * (NN * NF) + i];
    __syncthreads();
    for (int i = t; i < 80 * 128; i += 256) {
        int f = i >> 7, n = i & 127;
        float v = (f < NF) ? sV[n * NF + f] : 0.f;
        Vt[(size_t)b * (80 * 128) + i] = f2h(v);
    }
}

// ---------------------------------------------------------------------------
// prep weights transposed fp16: Wt[o][k].
__global__ __launch_bounds__(256)
void prepW_kernel(const float* __restrict__ W1, const float* __restrict__ W2,
                  const float* __restrict__ W3, u16* __restrict__ Wt1,
                  u16* __restrict__ Wt2, u16* __restrict__ Wt3)
{
    int o = blockIdx.x, z = blockIdx.y, t = threadIdx.x;
    if (z == 0) {
        int k = t;   // 0..255
        int c = k / 80, f = k - c * 80;
        float v = (c < 3 && f < NF) ? W1[((size_t)c * NF + f) * HID + o] : 0.f;
        Wt1[(size_t)o * 256 + k] = f2h(v);
    } else {
        const float* W = (z == 1) ? W2 : W3;
        u16* Wt = (z == 1) ? Wt2 : Wt3;
        for (int k = t; k < KB; k += 256) {
            int c = k >> 8, f = k & 255;
            Wt[(size_t)o * KB + k] = f2h(W[((size_t)c * HID + f) * HID + o]);
        }
    }
}

// ---------------------------------------------------------------------------
// gA (MFMA): AV[bl][n][c*fpMul + ft*128 + f] = (1/16) * sum_m Ah[b][c][n][m] * Htr[b][f'][m]
__global__ __launch_bounds__(256)
void gA_mfma(const u16* __restrict__ Agr, const u16* __restrict__ Htr,
             u16* __restrict__ AV, int b0, int htStride, int fpMul, int Fvalid)
{
    __shared__ u16 As[128 * 40];
    __shared__ u16 Bs[128 * 40];
    int ft = blockIdx.x, c = blockIdx.y, bl = blockIdx.z;
    int b = b0 + bl;
    const u16* Ap = Agr + ((size_t)b * AC + c) * (NN * NN);
    const u16* Bp = Htr + (size_t)b * htStride + ft * (128 * 128);
    u16* Cp = AV + (size_t)bl * (NN * KB) + c * fpMul + ft * 128;

    int t = threadIdx.x;
    int l = t & 63, wid = t >> 6;
    int rb = (wid >> 1) * 64, cb = (wid & 1) * 64;
    int ln = l & 15, q = l >> 4;

    f32x4 acc[4][4] = {};

    for (int kt = 0; kt < 4; ++kt) {
        #pragma unroll
        for (int i = 0; i < 2; ++i) {
            int id = t + i * 256;
            int row = id >> 2, qh = id & 3;
            *(uint4*)&As[row * 40 + qh * 8] =
                *(const uint4*)(Ap + (size_t)row * NN + kt * 32 + qh * 8);
        }
        #pragma unroll
        for (int i = 0; i < 2; ++i) {
            int id = t + i * 256;
            int row = id >> 2, qh = id & 3;
            uint4 v = make_uint4(0, 0, 0, 0);
            if (row < Fvalid) v = *(const uint4*)(Bp + (size_t)row * 128 + kt * 32 + qh * 8);
            *(uint4*)&Bs[row * 40 + qh * 8] = v;
        }
        __syncthreads();
        f16x8 af[4], bfr[4];
        #pragma unroll
        for (int fr = 0; fr < 4; ++fr)
            af[fr] = *(const f16x8*)&As[(rb + fr * 16 + ln) * 40 + q * 8];
        #pragma unroll
        for (int fc = 0; fc < 4; ++fc)
            bfr[fc] = *(const f16x8*)&Bs[(cb + fc * 16 + ln) * 40 + q * 8];
        #pragma unroll
        for (int fr = 0; fr < 4; ++fr)
            #pragma unroll
            for (int fc = 0; fc < 4; ++fc)
                acc[fr][fc] = __builtin_amdgcn_mfma_f32_16x16x32_f16(
                    af[fr], bfr[fc], acc[fr][fc], 0, 0, 0);
        __syncthreads();
    }
    #pragma unroll
    for (int fr = 0; fr < 4; ++fr) {
        #pragma unroll
        for (int fc = 0; fc < 4; ++fc) {
            int fcol = cb + fc * 16 + ln;
            if (fcol < Fvalid) {
                #pragma unroll
                for (int r = 0; r < 4; ++r) {
                    int n = rb + fr * 16 + q * 4 + r;
                    Cp[(size_t)n * KB + fcol] = f2h_sat(acc[fr][fc][r] * SC);
                }
            }
        }
    }
}

// ---------------------------------------------------------------------------
// gB (MFMA): val[n][o] = relu( 16 * sum_k AVs[bl][n][k] * Wt[o][k] + bias[o] )
// mode 0 (layers 1-2): write TRANSPOSED fp16 to Ht [b][256][128] (LDS transpose
//   in epilogue — replaces the separate transp kernel).
// mode 1 (layer 3): write fp16 scaled 1/16 to H3h [b][n][256].
__global__ __launch_bounds__(256)
void gB_mfma(const u16* __restrict__ AV, const u16* __restrict__ Wt,
             const float* __restrict__ bias, u16* __restrict__ Hout,
             int b0, int kTiles, int Ks, int mode)
{
    __shared__ u16 As[128 * 40];
    __shared__ u16 Bs[128 * 40];
    __shared__ u16 sLT[128][136];   // transpose tile (mode 0); 16B-aligned rows
    int ot = blockIdx.x, bl = blockIdx.y;
    int b = b0 + bl;
    const u16* Ap = AV + (size_t)bl * (NN * KB);
    const u16* Bp = Wt + (size_t)ot * 128 * Ks;

    int t = threadIdx.x;
    int l = t & 63, wid = t >> 6;
    int rb = (wid >> 1) * 64, cb = (wid & 1) * 64;
    int ln = l & 15, q = l >> 4;

    f32x4 acc[4][4] = {};

    for (int kt = 0; kt < kTiles; ++kt) {
        #pragma unroll
        for (int i = 0; i < 2; ++i) {
            int id = t + i * 256;
            int row = id >> 2, qh = id & 3;
            *(uint4*)&As[row * 40 + qh * 8] =
                *(const uint4*)(Ap + (size_t)row * KB + kt * 32 + qh * 8);
            *(uint4*)&Bs[row * 40 + qh * 8] =
                *(const uint4*)(Bp + (size_t)row * Ks + kt * 32 + qh * 8);
        }
        __syncthreads();
        f16x8 af[4], bfr[4];
        #pragma unroll
        for (int fr = 0; fr < 4; ++fr)
            af[fr] = *(const f16x8*)&As[(rb + fr * 16 + ln) * 40 + q * 8];
        #pragma unroll
        for (int fc = 0; fc < 4; ++fc)
            bfr[fc] = *(const f16x8*)&Bs[(cb + fc * 16 + ln) * 40 + q * 8];
        #pragma unroll
        for (int fr = 0; fr < 4; ++fr)
            #pragma unroll
            for (int fc = 0; fc < 4; ++fc)
                acc[fr][fc] = __builtin_amdgcn_mfma_f32_16x16x32_f16(
                    af[fr], bfr[fc], acc[fr][fc], 0, 0, 0);
        __syncthreads();
    }
    if (mode == 0) {
        // scatter transposed into LDS, then coalesced row writes to Ht[b][o][n]
        #pragma unroll
        for (int fr = 0; fr < 4; ++fr)
            #pragma unroll
            for (int fc = 0; fc < 4; ++fc) {
                int oc = cb + fc * 16 + ln;
                float bv = bias[ot * 128 + oc];
                #pragma unroll
                for (int r = 0; r < 4; ++r) {
                    int n = rb + fr * 16 + q * 4 + r;
                    sLT[oc][n] = f2h_sat(fmaxf(acc[fr][fc][r] * USC + bv, 0.f));
                }
            }
        __syncthreads();
        int row = t >> 1, half = t & 1;
        u16* dst = Hout + ((size_t)b * HID + ot * 128 + row) * NN + half * 64;
        #pragma unroll
        for (int j = 0; j < 8; ++j)
            *(uint4*)(dst + j * 8) = *(const uint4*)&sLT[row][half * 64 + j * 8];
    } else {
        #pragma unroll
        for (int fr = 0; fr < 4; ++fr)
            #pragma unroll
            for (int fc = 0; fc < 4; ++fc) {
                int oc = cb + fc * 16 + ln;
                float bv = bias[ot * 128 + oc];
                #pragma unroll
                for (int r = 0; r < 4; ++r) {
                    int n = rb + fr * 16 + q * 4 + r;
                    float val = fmaxf(acc[fr][fc][r] * USC + bv, 0.f);
                    Hout[((size_t)b * NN + n) * HID + ot * 128 + oc] = f2h_sat(val * SC);
                }
            }
    }
}

// ---------------------------------------------------------------------------
// Masked multi-head attention pooling. H3h fp16 scaled 1/16; single-pass
// from a full 128x256 LDS stage. grid: (B), block: 256
__global__ __launch_bounds__(256)
void pool_kernel(const u16* __restrict__ H3h,
                 const float* __restrict__ attW,
                 const int* __restrict__ msz,
                 float* __restrict__ pooled)
{
    int b = blockIdx.x, t = threadIdx.x;
    __shared__ u16  sTh[128][264];      // 67.6 KB, rows 16B-aligned
    __shared__ float sW[HID * NHEAD];   // 8 KB
    __shared__ float sS[NN * NHEAD];    // 4 KB
    __shared__ float sP[16][NHEAD][2];
    for (int i = t; i < HID * NHEAD; i += 256) sW[i] = attW[i];
    const u16* Hb = H3h + (size_t)b * NN * HID;
    for (int i = t; i < 128 * 32; i += 256) {      // 4096 uint4 = 32768 u16
        int row = i >> 5, fq = (i & 31) * 8;
        *(uint4*)&sTh[row][fq] = *(const uint4*)(Hb + (size_t)row * HID + fq);
    }
    __syncthreads();
    // scores (x16 unscale: real H3 = 16 * stored)
    for (int n0 = 0; n0 < NN; n0 += 16) {
        int nl = t >> 4, h = (t >> 1) & 7, fh = t & 1;
        float s = 0.f;
        for (int f = fh * 128; f < fh * 128 + 128; ++f)
            s += h2f(sTh[n0 + nl][f]) * sW[f * NHEAD + h];
        sP[nl][h][fh] = s;
        __syncthreads();
        if (t < 128) {
            int n2 = t >> 3, h2 = t & 7;
            sS[(n0 + n2) * NHEAD + h2] = USC * (sP[n2][h2][0] + sP[n2][h2][1]);
        }
        __syncthreads();
    }
    int ms = msz[b];
    int h = t >> 5, ln = t & 31;
    float mx = -1e9f;
    for (int n = ln; n < NN; n += 32) {
        float s = (n < ms) ? sS[n * NHEAD + h] : -1e9f;
        mx = fmaxf(mx, s);
    }
    #pragma unroll
    for (int off = 16; off; off >>= 1) mx = fmaxf(mx, __shfl_xor(mx, off, 32));
    float sum = 0.f;
    for (int n = ln; n < NN; n += 32) {
        float s = (n < ms) ? sS[n * NHEAD + h] : -1e9f;
        sum += expf(s - mx);
    }
    #pragma unroll
    for (int off = 16; off; off >>= 1) sum += __shfl_xor(sum, off, 32);
    float inv = 1.f / sum;
    for (int n = ln; n < NN; n += 32) {
        float s = (n < ms) ? sS[n * NHEAD + h] : -1e9f;
        sS[n * NHEAD + h] = expf(s - mx) * inv;
    }
    __syncthreads();
    float accp[NHEAD] = {};
    for (int n = 0; n < NN; ++n) {
        float hv = h2f(sTh[n][t]);
        #pragma unroll
        for (int hh = 0; hh < NHEAD; ++hh) accp[hh] += sS[n * NHEAD + hh] * hv;
    }
    #pragma unroll
    for (int hh = 0; hh < NHEAD; ++hh)
        pooled[(size_t)b * (HID * NHEAD) + hh * HID + t] = USC * accp[hh];
}

// ---------------------------------------------------------------------------
// Readout, k-split
__global__ __launch_bounds__(128)
void readout_part(const float* __restrict__ pooled,
                  const float* __restrict__ roW,
                  float* __restrict__ Rp)
{
    int b = blockIdx.x, s = blockIdx.y, t = threadIdx.x;
    __shared__ float sx[256];
    const float* sp = pooled + (size_t)b * (HID * NHEAD) + s * 256;
    sx[t] = sp[t];
    sx[t + 128] = sp[t + 128];
    __syncthreads();
    float acc = 0.f;
    const float* W = roW + (size_t)(s * 256) * DIM + t;
    for (int k = 0; k < 256; ++k) acc += sx[k] * W[(size_t)k * DIM];
    Rp[((size_t)s * BB + b) * DIM + t] = acc;
}

__global__ __launch_bounds__(128)
void readout_merge(const float* __restrict__ Rp,
                   const float* __restrict__ rob,
                   float* __restrict__ Vr, u16* __restrict__ Vrh)
{
    int b = blockIdx.x, t = threadIdx.x;
    float a = rob[t];
    #pragma unroll
    for (int s = 0; s < 8; ++s) a += Rp[((size_t)s * BB + b) * DIM + t];
    float v = fmaxf(a, 0.f);
    Vr [(size_t)b * DIM + t] = v;
    Vrh[(size_t)b * DIM + t] = f2h_sat(v * SC);   // scaled 1/16
}

// ---------------------------------------------------------------------------
// atth (MFMA): h_br = relu(X_br @ W_br + b_br). grid (2 mt, 2 br).
__global__ __launch_bounds__(256)
void atth_mfma(const u16* __restrict__ FP2h, const u16* __restrict__ VRh,
               const u16* __restrict__ mWt12,
               const float* __restrict__ mfpb, const float* __restrict__ mvb,
               float* __restrict__ h1v, float* __restrict__ h2v)
{
    __shared__ u16 As[128 * 40];
    __shared__ u16 Bs[128 * 40];
    int mt = blockIdx.x, br = blockIdx.y;
    const u16* Ap = (br ? VRh : FP2h) + (size_t)(mt * 128) * 128;
    const u16* Bp = mWt12 + (size_t)br * 128 * 128;
    const float* bias = br ? mvb : mfpb;
    float unsc = br ? USC : 1.f;
    float* out = br ? h2v : h1v;

    int t = threadIdx.x;
    int l = t & 63, wid = t >> 6;
    int rb = (wid >> 1) * 64, cb = (wid & 1) * 64;
    int ln = l & 15, q = l >> 4;

    f32x4 acc[4][4] = {};

    for (int kt = 0; kt < 4; ++kt) {
        #pragma unroll
        for (int i = 0; i < 2; ++i) {
            int id = t + i * 256;
            int row = id >> 2, qh = id & 3;
            *(uint4*)&As[row * 40 + qh * 8] =
                *(const uint4*)(Ap + (size_t)row * 128 + kt * 32 + qh * 8);
            *(uint4*)&Bs[row * 40 + qh * 8] =
                *(const uint4*)(Bp + (size_t)row * 128 + kt * 32 + qh * 8);
        }
        __syncthreads();
        f16x8 af[4], bfr[4];
        #pragma unroll
        for (int fr = 0; fr < 4; ++fr)
            af[fr] = *(const f16x8*)&As[(rb + fr * 16 + ln) * 40 + q * 8];
        #pragma unroll
        for (int fc = 0; fc < 4; ++fc)
            bfr[fc] = *(const f16x8*)&Bs[(cb + fc * 16 + ln) * 40 + q * 8];
        #pragma unroll
        for (int fr = 0; fr < 4; ++fr)
            #pragma unroll
            for (int fc = 0; fc < 4; ++fc)
                acc[fr][fc] = __builtin_amdgcn_mfma_f32_16x16x32_f16(
                    af[fr], bfr[fc], acc[fr][fc], 0, 0, 0);
        __syncthreads();
    }
    #pragma unroll
    for (int fr = 0; fr < 4; ++fr)
        #pragma unroll
        for (int fc = 0; fc < 4; ++fc) {
            int d = cb + fc * 16 + ln;
            float bv = bias[d];
            #pragma unroll
            for (int r = 0; r < 4; ++r) {
                int m = rb + fr * 16 + q * 4 + r;
                out[(size_t)(mt * 128 + m) * 128 + d] = fmaxf(acc[fr][fc][r] * unsc + bv, 0.f);
            }
        }
}

// ---------------------------------------------------------------------------
// Cross-attn partial scan over fp16 interleaved tables. grid (B, 8).
__global__ __launch_bounds__(256)
void cross_part_kernel(const int* __restrict__ seq,
                       const u16* __restrict__ HS12,
                       const float* __restrict__ h1v, const float* __restrict__ h2v,
                       float* __restrict__ Pc)   // [8][B][2][128]
{
    int b = blockIdx.x, s = blockIdx.y, t = threadIdx.x;
    int g = t >> 4, gl = t & 15;
    int d0 = gl * 8;
    float h1[8], h2[8];
    #pragma unroll
    for (int j = 0; j < 8; ++j) {
        h1[j] = h1v[(size_t)b * DIM + d0 + j];
        h2[j] = h2v[(size_t)b * DIM + d0 + j];
    }
    float m1[8], m2[8];
    #pragma unroll
    for (int j = 0; j < 8; ++j) { m1[j] = -INFINITY; m2[j] = -INFINITY; }
    const int* sq = seq + (size_t)b * LL + s * 256;
    for (int it = 0; it < 16; ++it) {
        int tok = sq[g + 16 * it];
        const u16* r12 = HS12 + (size_t)tok * 256 + d0;
        f16x8 va16 = *(const f16x8*)(r12);         // branch 0
        f16x8 vb16 = *(const f16x8*)(r12 + 128);   // branch 1
        float va[8], vb[8];
        float p1 = 0.f, p2 = 0.f;
        #pragma unroll
        for (int j = 0; j < 8; ++j) {
            va[j] = (float)va16[j];
            vb[j] = (float)vb16[j];
            p1 += h1[j] * va[j];
            p2 += h2[j] * vb[j];
        }
        #pragma unroll
        for (int off = 8; off; off >>= 1) {
            p1 += __shfl_xor(p1, off);
            p2 += __shfl_xor(p2, off);
        }
        float w1 = tanhf(p1), w2 = tanhf(p2);
        #pragma unroll
        for (int j = 0; j < 8; ++j) {
            m1[j] = fmaxf(m1[j], w1 * va[j]);
            m2[j] = fmaxf(m2[j], w2 * vb[j]);
        }
    }
    __shared__ float red[16][2][DIM];
    #pragma unroll
    for (int j = 0; j < 8; ++j) { red[g][0][d0 + j] = m1[j]; red[g][1][d0 + j] = m2[j]; }
    __syncthreads();
    int tb = t >> 7, d = t & 127;
    float mx = red[0][tb][d];
    #pragma unroll
    for (int gg = 1; gg < 16; ++gg) mx = fmaxf(mx, red[gg][tb][d]);
    Pc[(((size_t)s * BB + b) * 2 + tb) * DIM + d] = mx;
}

__global__ __launch_bounds__(256)
void cross_merge_kernel(const float* __restrict__ Pc,
                        float* __restrict__ IT1, float* __restrict__ IT2)
{
    int b = blockIdx.x, t = threadIdx.x;
    float m = -INFINITY;
    for (int s = 0; s < 8; ++s)
        m = fmaxf(m, Pc[((size_t)s * BB + b) * 256 + t]);
    if (t < DIM) IT1[(size_t)b * DIM + t] = m;
    else         IT2[(size_t)b * DIM + t - DIM] = m;
}

// ---------------------------------------------------------------------------
// MLP as batch GEMMs. Xh layout: [br][256 batch][256], values scaled 1/16.
__global__ __launch_bounds__(256)
void prepX_kernel(const float* __restrict__ FP2, const float* __restrict__ VR,
                  const float* __restrict__ IT1, const float* __restrict__ IT2,
                  u16* __restrict__ Xh)
{
    int b = blockIdx.x, br = blockIdx.y, t = threadIdx.x;
    const float* a0 = br ? VR : FP2;
    const float* a1 = br ? IT2 : IT1;
    float v = (t < 128) ? a0[(size_t)b * 128 + t] : a1[(size_t)b * 128 + t - 128];
    Xh[((size_t)br * BB + b) * 256 + t] = f2h_sat(v * SC);
}

// one MLP layer: Y = relu(X@W+b), in/out scaled 1/16. grid (2 mt, 2 ot, 2 br).
__global__ __launch_bounds__(256)
void mlpL_mfma(const u16* __restrict__ X, const u16* __restrict__ Wmlp,
               const float* __restrict__ m1b, const float* __restrict__ m2b,
               int Lr, u16* __restrict__ Y)
{
    __shared__ u16 As[128 * 40];
    __shared__ u16 Bs[128 * 40];
    int mt = blockIdx.x, ot = blockIdx.y, br = blockIdx.z;
    const u16* Ap = X + ((size_t)br * BB + mt * 128) * 256;
    const u16* Bp = Wmlp + (((size_t)(br * 3 + Lr)) * 256 + ot * 128) * 256;
    const float* bias = (br ? m2b : m1b) + (size_t)Lr * 256 + ot * 128;

    int t = threadIdx.x;
    int l = t & 63, wid = t >> 6;
    int rb = (wid >> 1) * 64, cb = (wid & 1) * 64;
    int ln = l & 15, q = l >> 4;

    f32x4 acc[4][4] = {};

    for (int kt = 0; kt < 8; ++kt) {
        #pragma unroll
        for (int i = 0; i < 2; ++i) {
            int id = t + i * 256;
            int row = id >> 2, qh = id & 3;
            *(uint4*)&As[row * 40 + qh * 8] =
                *(const uint4*)(Ap + (size_t)row * 256 + kt * 32 + qh * 8);
            *(uint4*)&Bs[row * 40 + qh * 8] =
                *(const uint4*)(Bp + (size_t)row * 256 + kt * 32 + qh * 8);
        }
        __syncthreads();
        f16x8 af[4], bfr[4];
        #pragma unroll
        for (int fr = 0; fr < 4; ++fr)
            af[fr] = *(const f16x8*)&As[(rb + fr * 16 + ln) * 40 + q * 8];
        #pragma unroll
        for (int fc = 0; fc < 4; ++fc)
            bfr[fc] = *(const f16x8*)&Bs[(cb + fc * 16 + ln) * 40 + q * 8];
        #pragma unroll
        for (int fr = 0; fr < 4; ++fr)
            #pragma unroll
            for (int fc = 0; fc < 4; ++fc)
                acc[fr][fc] = __builtin_amdgcn_mfma_f32_16x16x32_f16(
                    af[fr], bfr[fc], acc[fr][fc], 0, 0, 0);
        __syncthreads();
    }
    #pragma unroll
    for (int fr = 0; fr < 4; ++fr)
        #pragma unroll
        for (int fc = 0; fc < 4; ++fc) {
            int oc = cb + fc * 16 + ln;
            float bv = bias[oc] * SC;
            #pragma unroll
            for (int r = 0; r < 4; ++r) {
                int m = rb + fr * 16 + q * 4 + r;
                Y[((size_t)br * BB + (mt * 128 + m)) * 256 + ot * 128 + oc] =
                    f2h_sat(fmaxf(acc[fr][fc][r] + bv, 0.f));
            }
        }
}

// head + outputs. grid (BB), block 256.
__global__ __launch_bounds__(256)
void mlp_out_kernel(const u16* __restrict__ Y,
                    const float* __restrict__ o1W, const float* __restrict__ o1b,
                    const float* __restrict__ o2W, const float* __restrict__ o2b,
                    const int* __restrict__ label,
                    float* __restrict__ dout)
{
    int b = blockIdx.x, t = threadIdx.x;
    __shared__ float pl[2][128];
    const u16* y1 = Y + (size_t)b * 256;
    const u16* y2 = Y + ((size_t)BB + b) * 256;
    int j = t & 1, k2 = t >> 1;
    float p = USC * (h2f(y1[k2])       * o1W[k2 * 2 + j]
                   + h2f(y1[k2 + 128]) * o1W[(k2 + 128) * 2 + j]
                   + h2f(y2[k2])       * o2W[k2 * 2 + j]
                   + h2f(y2[k2 + 128]) * o2W[(k2 + 128) * 2 + j]);
    pl[j][k2] = p;
    __syncthreads();
    for (int s = 64; s > 0; s >>= 1) {
        if (k2 < s) pl[j][k2] += pl[j][k2 + s];
        __syncthreads();
    }
    if (t == 0) {
        float l0 = pl[0][0] + o1b[0] + o2b[0];
        float l1 = pl[1][0] + o1b[1] + o2b[1];
        dout[(size_t)b * 2 + 0] = l0;
        dout[(size_t)b * 2 + 1] = l1;
        dout[2 * BB + b] = (float)label[b];
        dout[3 * BB + b] = (float)((l1 > l0) ? 1 : 0);
        float mx = fmaxf(l0, l1);
        float e0 = expf(l0 - mx), e1 = expf(l1 - mx);
        dout[4 * BB + b] = e1 / (e0 + e1);
    }
}

// ---------------------------------------------------------------------------
extern "C" void kernel_launch(void* const* d_in, const int* in_sizes, int n_in,
                              void* d_out, int out_size, void* d_ws, size_t ws_size,
                              hipStream_t stream)
{
    const float* V    = (const float*)d_in[0];
    const float* A    = (const float*)d_in[1];
    const float* fp   = (const float*)d_in[2];
    const int*   msz  = (const int*)  d_in[3];
    const int*   seq  = (const int*)  d_in[4];
    const int*   lab  = (const int*)  d_in[5];
    const float* gcW1 = (const float*)d_in[6];  const float* gcb1 = (const float*)d_in[7];
    const float* gcW2 = (const float*)d_in[8];  const float* gcb2 = (const float*)d_in[9];
    const float* gcW3 = (const float*)d_in[10]; const float* gcb3 = (const float*)d_in[11];
    const float* fpW1 = (const float*)d_in[12]; const float* fpb1 = (const float*)d_in[13];
    const float* fpW2 = (const float*)d_in[14]; const float* fpb2 = (const float*)d_in[15];
    const float* attW = (const float*)d_in[16];
    const float* roW  = (const float*)d_in[17]; const float* rob  = (const float*)d_in[18];
    const float* emb  = (const float*)d_in[19];
    const float* mfpW = (const float*)d_in[20]; const float* mfpb = (const float*)d_in[21];
    const float* pfpW = (const float*)d_in[22]; const float* pfpb = (const float*)d_in[23];
    const float* mvW  = (const float*)d_in[24]; const float* mvb  = (const float*)d_in[25];
    const float* pvW  = (const float*)d_in[26]; const float* pvb  = (const float*)d_in[27];
    const float* m1W  = (const float*)d_in[28]; const float* m1b  = (const float*)d_in[29];
    const float* m2W  = (const float*)d_in[30]; const float* m2b  = (const float*)d_in[31];
    const float* o1W  = (const float*)d_in[32]; const float* o1b  = (const float*)d_in[33];
    const float* o2W  = (const float*)d_in[34]; const float* o2b  = (const float*)d_in[35];
    float* dout = (float*)d_out;

    // workspace layout
    char* ws = (char*)d_ws;
    size_t off = 0;
    auto alloc = [&](size_t bytes) -> char* {
        char* p = ws + off;
        off += (bytes + 255) & ~(size_t)255;
        return p;
    };
    u16*   Ah    = (u16*)  alloc((size_t)BB * AC * NN * NN * 2);   // 25.2 MB
    u16*   Vt    = (u16*)  alloc((size_t)BB * 80 * 128 * 2);       // 5.24 MB
    u16*   Wt1   = (u16*)  alloc((size_t)256 * 256 * 2);
    u16*   Wt2   = (u16*)  alloc((size_t)256 * KB * 2);
    u16*   Wt3   = (u16*)  alloc((size_t)256 * KB * 2);
    u16*   Ht    = (u16*)  alloc((size_t)BB * HID * NN * 2);       // 16.8 MB (written by gB mode 0)
    u16*   H3h   = (u16*)  alloc((size_t)BB * NN * HID * 2);       // 16.8 MB (fp16, scaled 1/16)
    u16*   fph   = (u16*)  alloc((size_t)BB * FPDP * 2);
    u16*   W1t   = (u16*)  alloc((size_t)DIM * FPDP * 2);
    u16*   W2t   = (u16*)  alloc((size_t)DIM * DIM * 2);
    u16*   FP1h  = (u16*)  alloc((size_t)BB * DIM * 2);
    float* FP2   = (float*)alloc((size_t)BB * DIM * 4);
    u16*   FP2h  = (u16*)  alloc((size_t)BB * DIM * 2);
    u16*   pWt12 = (u16*)  alloc((size_t)2 * 128 * 128 * 2);
    u16*   mWt12 = (u16*)  alloc((size_t)2 * 128 * 128 * 2);
    u16*   HS12  = (u16*)  alloc((size_t)NWP * 256 * 2);           // 4.45 MB
    float* PO    = (float*)alloc((size_t)BB * HID * NHEAD * 4);
    float* VR    = (float*)alloc((size_t)BB * DIM * 4);
    u16*   VRh   = (u16*)  alloc((size_t)BB * DIM * 2);
    float* H1V   = (float*)alloc((size_t)BB * DIM * 4);
    float* H2V   = (float*)alloc((size_t)BB * DIM * 4);
    float* IT1   = (float*)alloc((size_t)BB * DIM * 4);
    float* IT2   = (float*)alloc((size_t)BB * DIM * 4);
    float* Pc    = (float*)alloc((size_t)8 * BB * 2 * DIM * 4);
    float* Rp    = (float*)alloc((size_t)8 * BB * DIM * 4);
    u16*   Wmlp  = (u16*)  alloc((size_t)2 * 3 * 256 * 256 * 2);   // 786 KB
    u16*   Xa    = (u16*)  alloc((size_t)2 * BB * 256 * 2);        // 256 KB
    u16*   Xb    = (u16*)  alloc((size_t)2 * BB * 256 * 2);
    size_t fixedBytes = off;

    // AV tier (fp16, per-b 128*768*2 = 196608 B)
    int CB = 8;
    size_t perB = (size_t)NN * KB * 2;
    {
        const int tiers[] = {256, 128, 64, 32, 16, 8, 4, 2, 1};
        for (int i = 0; i < 9; ++i)
            if (fixedBytes + (size_t)tiers[i] * perB <= ws_size) { CB = tiers[i]; break; }
    }
    u16* AV = (u16*)(ws + fixedBytes);

    // prep + independent front-end
    prepA_kernel<<<BB * AC, 256, 0, stream>>>(A, Ah);
    prepVt_kernel<<<BB, 256, 0, stream>>>(V, Vt);
    prepW_kernel<<<dim3(256, 3), 256, 0, stream>>>(gcW1, gcW2, gcW3, Wt1, Wt2, Wt3);
    prepFp_kernel<<<BB, 256, 0, stream>>>(fp, fph);
    prepFpW_kernel<<<dim3(128, 2), 256, 0, stream>>>(fpW1, fpW2, W1t, W2t);
    prepCrossW_kernel<<<dim3(128, 4), 128, 0, stream>>>(pfpW, pvW, mfpW, mvW, pWt12, mWt12);
    prepMlpW_kernel<<<dim3(256, 3, 2), 256, 0, stream>>>(m1W, m2W, Wmlp);
    fp1_mfma<<<2, 256, 0, stream>>>(fph, W1t, fpb1, FP1h);
    fp2_mfma<<<2, 256, 0, stream>>>(FP1h, W2t, fpb2, FP2, FP2h);
    hs12_mfma<<<dim3(NWP / 128, 2), 256, 0, stream>>>(emb, pWt12, pfpb, pvb, HS12);

    // GConv layer 1 (F=75 padded to 80; gB writes Ht directly, transposed)
    for (int b0 = 0; b0 < BB; b0 += CB) {
        gA_mfma<<<dim3(1, AC, CB), 256, 0, stream>>>(Ah, Vt, AV, b0, 80 * 128, 80, 80);
        gB_mfma<<<dim3(2, CB), 256, 0, stream>>>(AV, Wt1, gcb1, Ht, b0, 8, 256, 0);
    }
    // layer 2
    for (int b0 = 0; b0 < BB; b0 += CB) {
        gA_mfma<<<dim3(2, AC, CB), 256, 0, stream>>>(Ah, Ht, AV, b0, HID * NN, 256, 128);
        gB_mfma<<<dim3(2, CB), 256, 0, stream>>>(AV, Wt2, gcb2, Ht, b0, 24, KB, 0);
    }
    // layer 3 -> H3h fp16 scaled 1/16 (max |H3|/16 ~ 4.7e3 << 65504)
    for (int b0 = 0; b0 < BB; b0 += CB) {
        gA_mfma<<<dim3(2, AC, CB), 256, 0, stream>>>(Ah, Ht, AV, b0, HID * NN, 256, 128);
        gB_mfma<<<dim3(2, CB), 256, 0, stream>>>(AV, Wt3, gcb3, H3h, b0, 24, KB, 1);
    }

    pool_kernel<<<BB, 256, 0, stream>>>(H3h, attW, msz, PO);
    readout_part<<<dim3(BB, 8), 128, 0, stream>>>(PO, roW, Rp);
    readout_merge<<<BB, 128, 0, stream>>>(Rp, rob, VR, VRh);
    atth_mfma<<<dim3(2, 2), 256, 0, stream>>>(FP2h, VRh, mWt12, mfpb, mvb, H1V, H2V);
    cross_part_kernel<<<dim3(BB, 8), 256, 0, stream>>>(seq, HS12, H1V, H2V, Pc);
    cross_merge_kernel<<<BB, 256, 0, stream>>>(Pc, IT1, IT2);
    prepX_kernel<<<dim3(BB, 2), 256, 0, stream>>>(FP2, VR, IT1, IT2, Xa);
    mlpL_mfma<<<dim3(2, 2, 2), 256, 0, stream>>>(Xa, Wmlp, m1b, m2b, 0, Xb);
    mlpL_mfma<<<dim3(2, 2, 2), 256, 0, stream>>>(Xb, Wmlp, m1b, m2b, 1, Xa);
    mlpL_mfma<<<dim3(2, 2, 2), 256, 0, stream>>>(Xa, Wmlp, m1b, m2b, 2, Xb);
    mlp_out_kernel<<<BB, 256, 0, stream>>>(Xb, o1W, o1b, o2W, o2b, lab, dout);
}

// Round 10
// 494.790 us; speedup vs baseline: 2.8948x; 1.0259x over previous
//
#include <hip/hip_runtime.h>
#include <math.h>

// Problem constants
static constexpr int BB   = 256;   // batch
static constexpr int NN   = 128;   // nodes
static constexpr int LL   = 2048;  // protein length
static constexpr int NF   = 75;
static constexpr int AC   = 3;
static constexpr int HID  = 256;
static constexpr int DIM  = 128;
static constexpr int NHEAD= 8;
static constexpr int FPD  = 679;
static constexpr int FPDP = 704;   // FPD padded to multiple of 32
static constexpr int NWORD= 8600;
static constexpr int NWP  = 8704;  // NWORD padded to 68*128
static constexpr int KB   = 768;   // AV row stride (3*256)

typedef __attribute__((ext_vector_type(8))) _Float16 f16x8;
typedef __attribute__((ext_vector_type(2))) _Float16 h2v;
typedef __attribute__((ext_vector_type(4))) float f32x4;
typedef unsigned int u32;
typedef unsigned short u16;

__device__ __forceinline__ u16 f2h(float x) {
    _Float16 h = (_Float16)x;       // RNE
    return *(u16*)&h;
}
// saturating fp32->fp16 (avoid inf from rare tail values)
__device__ __forceinline__ u16 f2h_sat(float x) {
    x = fminf(fmaxf(x, -65000.f), 65000.f);
    _Float16 h = (_Float16)x;
    return *(u16*)&h;
}
__device__ __forceinline__ float h2f(u16 x) {
    return (float)(*(_Float16*)&x);
}

// fp16-carried intermediates with large range are stored scaled by 1/16.
static constexpr float SC   = 0.0625f;
static constexpr float USC  = 16.0f;

// ---------------------------------------------------------------------------
// prep: A fp32 -> fp16, same layout. grid (BB*AC), block 256.
__global__ __launch_bounds__(256)
void prepA_kernel(const float* __restrict__ A, u16* __restrict__ Ah)
{
    size_t base = (size_t)blockIdx.x * (NN * NN);
    int t = threadIdx.x;
    #pragma unroll
    for (int i = 0; i < 16; ++i) {
        int id = t + i * 256;          // 0..4095 float4s
        float4 v = *(const float4*)(A + base + (size_t)id * 4);
        u32 p0 = (u32)f2h(v.x) | ((u32)f2h(v.y) << 16);
        u32 p1 = (u32)f2h(v.z) | ((u32)f2h(v.w) << 16);
        *(uint2*)(Ah + base + (size_t)id * 4) = make_uint2(p0, p1);
    }
}

// ---------------------------------------------------------------------------
// prep: fp fp32 [256][679] -> fph fp16 [256][704] (pad 0)
__global__ __launch_bounds__(256)
void prepFp_kernel(const float* __restrict__ fp, u16* __restrict__ fph)
{
    int b = blockIdx.x, t = threadIdx.x;
    for (int i = t; i < FPDP; i += 256) {
        float v = (i < FPD) ? fp[(size_t)b * FPD + i] : 0.f;
        fph[(size_t)b * FPDP + i] = f2h(v);
    }
}

// prep: W1t fp16 [128][704], W2t fp16 [128][128] (transposed from fpW1/fpW2)
__global__ __launch_bounds__(256)
void prepFpW_kernel(const float* __restrict__ fpW1, const float* __restrict__ fpW2,
                    u16* __restrict__ W1t, u16* __restrict__ W2t)
{
    int o = blockIdx.x, z = blockIdx.y, t = threadIdx.x;
    if (z == 0) {
        for (int k = t; k < FPDP; k += 256) {
            float v = (k < FPD) ? fpW1[(size_t)k * DIM + o] : 0.f;
            W1t[(size_t)o * FPDP + k] = f2h(v);
        }
    } else {
        if (t < 128) W2t[(size_t)o * 128 + t] = f2h(fpW2[(size_t)t * DIM + o]);
    }
}

// prep: 4x [128][128] transposes fp32->fp16 (pfpW, pvW, mfpW, mvW)
__global__ __launch_bounds__(128)
void prepCrossW_kernel(const float* __restrict__ pfpW, const float* __restrict__ pvW,
                       const float* __restrict__ mfpW, const float* __restrict__ mvW,
                       u16* __restrict__ pWt12, u16* __restrict__ mWt12)
{
    int o = blockIdx.x, z = blockIdx.y, t = threadIdx.x;
    const float* W = (z == 0) ? pfpW : (z == 1) ? pvW : (z == 2) ? mfpW : mvW;
    u16* Wt = (z < 2) ? (pWt12 + (size_t)z * 128 * 128)
                      : (mWt12 + (size_t)(z - 2) * 128 * 128);
    Wt[(size_t)o * 128 + t] = f2h(W[(size_t)t * 128 + o]);
}

// prep: MLP weights transposed fp16: Wmlp[br][Lr][o][k]
__global__ __launch_bounds__(256)
void prepMlpW_kernel(const float* __restrict__ m1W, const float* __restrict__ m2W,
                     u16* __restrict__ Wmlp)
{
    int o = blockIdx.x, Lr = blockIdx.y, br = blockIdx.z, t = threadIdx.x;
    const float* W = (br ? m2W : m1W) + (size_t)Lr * 256 * 256;
    Wmlp[(((size_t)(br * 3 + Lr)) * 256 + o) * 256 + t] = f2h(W[(size_t)t * 256 + o]);
}

// ---------------------------------------------------------------------------
// fp chain layer 1 (MFMA)
__global__ __launch_bounds__(256)
void fp1_mfma(const u16* __restrict__ fph, const u16* __restrict__ W1t,
              const float* __restrict__ b1, u16* __restrict__ FP1h)
{
    __shared__ u16 As[128 * 40];
    __shared__ u16 Bs[128 * 40];
    int mt = blockIdx.x;
    const u16* Ap = fph + (size_t)(mt * 128) * FPDP;

    int t = threadIdx.x;
    int l = t & 63, wid = t >> 6;
    int rb = (wid >> 1) * 64, cb = (wid & 1) * 64;
    int ln = l & 15, q = l >> 4;

    f32x4 acc[4][4] = {};

    for (int kt = 0; kt < FPDP / 32; ++kt) {
        #pragma unroll
        for (int i = 0; i < 2; ++i) {
            int id = t + i * 256;
            int row = id >> 2, qh = id & 3;
            *(uint4*)&As[row * 40 + qh * 8] =
                *(const uint4*)(Ap + (size_t)row * FPDP + kt * 32 + qh * 8);
            *(uint4*)&Bs[row * 40 + qh * 8] =
                *(const uint4*)(W1t + (size_t)row * FPDP + kt * 32 + qh * 8);
        }
        __syncthreads();
        f16x8 af[4], bfr[4];
        #pragma unroll
        for (int fr = 0; fr < 4; ++fr)
            af[fr] = *(const f16x8*)&As[(rb + fr * 16 + ln) * 40 + q * 8];
        #pragma unroll
        for (int fc = 0; fc < 4; ++fc)
            bfr[fc] = *(const f16x8*)&Bs[(cb + fc * 16 + ln) * 40 + q * 8];
        #pragma unroll
        for (int fr = 0; fr < 4; ++fr)
            #pragma unroll
            for (int fc = 0; fc < 4; ++fc)
                acc[fr][fc] = __builtin_amdgcn_mfma_f32_16x16x32_f16(
                    af[fr], bfr[fc], acc[fr][fc], 0, 0, 0);
        __syncthreads();
    }
    #pragma unroll
    for (int fr = 0; fr < 4; ++fr)
        #pragma unroll
        for (int fc = 0; fc < 4; ++fc) {
            int d = cb + fc * 16 + ln;
            float bv = b1[d];
            #pragma unroll
            for (int r = 0; r < 4; ++r) {
                int m = rb + fr * 16 + q * 4 + r;
                FP1h[(size_t)(mt * 128 + m) * 128 + d] = f2h(fmaxf(acc[fr][fc][r] + bv, 0.f));
            }
        }
}

// fp chain layer 2 (MFMA): FP2 fp32 + FP2h fp16
__global__ __launch_bounds__(256)
void fp2_mfma(const u16* __restrict__ FP1h, const u16* __restrict__ W2t,
              const float* __restrict__ b2, float* __restrict__ FP2,
              u16* __restrict__ FP2h)
{
    __shared__ u16 As[128 * 40];
    __shared__ u16 Bs[128 * 40];
    int mt = blockIdx.x;
    const u16* Ap = FP1h + (size_t)(mt * 128) * 128;

    int t = threadIdx.x;
    int l = t & 63, wid = t >> 6;
    int rb = (wid >> 1) * 64, cb = (wid & 1) * 64;
    int ln = l & 15, q = l >> 4;

    f32x4 acc[4][4] = {};

    for (int kt = 0; kt < 4; ++kt) {
        #pragma unroll
        for (int i = 0; i < 2; ++i) {
            int id = t + i * 256;
            int row = id >> 2, qh = id & 3;
            *(uint4*)&As[row * 40 + qh * 8] =
                *(const uint4*)(Ap + (size_t)row * 128 + kt * 32 + qh * 8);
            *(uint4*)&Bs[row * 40 + qh * 8] =
                *(const uint4*)(W2t + (size_t)row * 128 + kt * 32 + qh * 8);
        }
        __syncthreads();
        f16x8 af[4], bfr[4];
        #pragma unroll
        for (int fr = 0; fr < 4; ++fr)
            af[fr] = *(const f16x8*)&As[(rb + fr * 16 + ln) * 40 + q * 8];
        #pragma unroll
        for (int fc = 0; fc < 4; ++fc)
            bfr[fc] = *(const f16x8*)&Bs[(cb + fc * 16 + ln) * 40 + q * 8];
        #pragma unroll
        for (int fr = 0; fr < 4; ++fr)
            #pragma unroll
            for (int fc = 0; fc < 4; ++fc)
                acc[fr][fc] = __builtin_amdgcn_mfma_f32_16x16x32_f16(
                    af[fr], bfr[fc], acc[fr][fc], 0, 0, 0);
        __syncthreads();
    }
    #pragma unroll
    for (int fr = 0; fr < 4; ++fr)
        #pragma unroll
        for (int fc = 0; fc < 4; ++fc) {
            int d = cb + fc * 16 + ln;
            float bv = b2[d];
            #pragma unroll
            for (int r = 0; r < 4; ++r) {
                int m = rb + fr * 16 + q * 4 + r;
                float val = fmaxf(acc[fr][fc][r] + bv, 0.f);
                FP2 [(size_t)(mt * 128 + m) * 128 + d] = val;
                FP2h[(size_t)(mt * 128 + m) * 128 + d] = f2h(val);
            }
        }
}

// ---------------------------------------------------------------------------
// HS12 tables (MFMA): HS12[r][br*128+d] = fp16(relu(emb[r]@pW_br + b_br[d]))
__global__ __launch_bounds__(256)
void hs12_mfma(const float* __restrict__ emb, const u16* __restrict__ pWt12,
               const float* __restrict__ ba, const float* __restrict__ bb_,
               u16* __restrict__ HS12)
{
    __shared__ u16 As[128 * 40];
    __shared__ u16 Bs[128 * 40];
    int ft = blockIdx.x, br = blockIdx.y;
    const u16* Bp = pWt12 + (size_t)br * 128 * 128;
    const float* bias = br ? bb_ : ba;
    int r0 = ft * 128;

    int t = threadIdx.x;
    int l = t & 63, wid = t >> 6;
    int rb = (wid >> 1) * 64, cb = (wid & 1) * 64;
    int ln = l & 15, q = l >> 4;

    f32x4 acc[4][4] = {};

    for (int kt = 0; kt < 4; ++kt) {
        #pragma unroll
        for (int i = 0; i < 4; ++i) {
            int id = t + i * 256;
            int row = id >> 3, qf = id & 7;
            int r = r0 + row;
            float4 v = make_float4(0.f, 0.f, 0.f, 0.f);
            if (r < NWORD) v = *(const float4*)(emb + (size_t)r * 128 + kt * 32 + qf * 4);
            u32 p0 = (u32)f2h(v.x) | ((u32)f2h(v.y) << 16);
            u32 p1 = (u32)f2h(v.z) | ((u32)f2h(v.w) << 16);
            u32* dst = (u32*)&As[row * 40 + qf * 4];
            dst[0] = p0; dst[1] = p1;
        }
        #pragma unroll
        for (int i = 0; i < 2; ++i) {
            int id = t + i * 256;
            int row = id >> 2, qh = id & 3;
            *(uint4*)&Bs[row * 40 + qh * 8] =
                *(const uint4*)(Bp + (size_t)row * 128 + kt * 32 + qh * 8);
        }
        __syncthreads();
        f16x8 af[4], bfr[4];
        #pragma unroll
        for (int fr = 0; fr < 4; ++fr)
            af[fr] = *(const f16x8*)&As[(rb + fr * 16 + ln) * 40 + q * 8];
        #pragma unroll
        for (int fc = 0; fc < 4; ++fc)
            bfr[fc] = *(const f16x8*)&Bs[(cb + fc * 16 + ln) * 40 + q * 8];
        #pragma unroll
        for (int fr = 0; fr < 4; ++fr)
            #pragma unroll
            for (int fc = 0; fc < 4; ++fc)
                acc[fr][fc] = __builtin_amdgcn_mfma_f32_16x16x32_f16(
                    af[fr], bfr[fc], acc[fr][fc], 0, 0, 0);
        __syncthreads();
    }
    #pragma unroll
    for (int fr = 0; fr < 4; ++fr)
        #pragma unroll
        for (int fc = 0; fc < 4; ++fc) {
            int d = cb + fc * 16 + ln;
            float bv = bias[d];
            #pragma unroll
            for (int r = 0; r < 4; ++r) {
                int m = rb + fr * 16 + q * 4 + r;
                int rr = r0 + m;
                if (rr < NWORD)
                    HS12[(size_t)rr * 256 + br * 128 + d] = f2h(fmaxf(acc[fr][fc][r] + bv, 0.f));
            }
        }
}

// ---------------------------------------------------------------------------
// prep: V fp32 [b][128][75] -> Vt fp16 [b][80][128] (transposed, rows 75..79 = 0)
__global__ __launch_bounds__(256)
void prepVt_kernel(const float* __restrict__ V, u16* __restrict__ Vt)
{
    int b = blockIdx.x, t = threadIdx.x;
    __shared__ float sV[NN * NF];
    for (int i = t; i < NN * NF; i += 256) sV[i] = V[(size_t)b * (NN * NF) + i];
    __syncthreads();
    for (int i = t; i < 80 * 128; i += 256) {
        int f = i >> 7, n = i & 127;
        float v = (f < NF) ? sV[n * NF + f] : 0.f;
        Vt[(size_t)b * (80 * 128) + i] = f2h(v);
    }
}

// ---------------------------------------------------------------------------
// prep weights transposed fp16: Wt[o][k].
__global__ __launch_bounds__(256)
void prepW_kernel(const float* __restrict__ W1, const float* __restrict__ W2,
                  const float* __restrict__ W3, u16* __restrict__ Wt1,
                  u16* __restrict__ Wt2, u16* __restrict__ Wt3)
{
    int o = blockIdx.x, z = blockIdx.y, t = threadIdx.x;
    if (z == 0) {
        int k = t;   // 0..255
        int c = k / 80, f = k - c * 80;
        float v = (c < 3 && f < NF) ? W1[((size_t)c * NF + f) * HID + o] : 0.f;
        Wt1[(size_t)o * 256 + k] = f2h(v);
    } else {
        const float* W = (z == 1) ? W2 : W3;
        u16* Wt = (z == 1) ? Wt2 : Wt3;
        for (int k = t; k < KB; k += 256) {
            int c = k >> 8, f = k & 255;
            Wt[(size_t)o * KB + k] = f2h(W[((size_t)c * HID + f) * HID + o]);
        }
    }
}

// ---------------------------------------------------------------------------
// gA layer 1 (MFMA): AV[bl][n][c*80 + f] = (1/16)*sum_m Ah[b][c][n][m]*Vt[b][f][m]
__global__ __launch_bounds__(256)
void gA_mfma(const u16* __restrict__ Agr, const u16* __restrict__ Htr,
             u16* __restrict__ AV, int b0, int htStride, int fpMul, int Fvalid)
{
    __shared__ u16 As[128 * 40];
    __shared__ u16 Bs[128 * 40];
    int ft = blockIdx.x, c = blockIdx.y, bl = blockIdx.z;
    int b = b0 + bl;
    const u16* Ap = Agr + ((size_t)b * AC + c) * (NN * NN);
    const u16* Bp = Htr + (size_t)b * htStride + ft * (128 * 128);
    u16* Cp = AV + (size_t)bl * (NN * KB) + c * fpMul + ft * 128;

    int t = threadIdx.x;
    int l = t & 63, wid = t >> 6;
    int rb = (wid >> 1) * 64, cb = (wid & 1) * 64;
    int ln = l & 15, q = l >> 4;

    f32x4 acc[4][4] = {};

    for (int kt = 0; kt < 4; ++kt) {
        #pragma unroll
        for (int i = 0; i < 2; ++i) {
            int id = t + i * 256;
            int row = id >> 2, qh = id & 3;
            *(uint4*)&As[row * 40 + qh * 8] =
                *(const uint4*)(Ap + (size_t)row * NN + kt * 32 + qh * 8);
        }
        #pragma unroll
        for (int i = 0; i < 2; ++i) {
            int id = t + i * 256;
            int row = id >> 2, qh = id & 3;
            uint4 v = make_uint4(0, 0, 0, 0);
            if (row < Fvalid) v = *(const uint4*)(Bp + (size_t)row * 128 + kt * 32 + qh * 8);
            *(uint4*)&Bs[row * 40 + qh * 8] = v;
        }
        __syncthreads();
        f16x8 af[4], bfr[4];
        #pragma unroll
        for (int fr = 0; fr < 4; ++fr)
            af[fr] = *(const f16x8*)&As[(rb + fr * 16 + ln) * 40 + q * 8];
        #pragma unroll
        for (int fc = 0; fc < 4; ++fc)
            bfr[fc] = *(const f16x8*)&Bs[(cb + fc * 16 + ln) * 40 + q * 8];
        #pragma unroll
        for (int fr = 0; fr < 4; ++fr)
            #pragma unroll
            for (int fc = 0; fc < 4; ++fc)
                acc[fr][fc] = __builtin_amdgcn_mfma_f32_16x16x32_f16(
                    af[fr], bfr[fc], acc[fr][fc], 0, 0, 0);
        __syncthreads();
    }
    #pragma unroll
    for (int fr = 0; fr < 4; ++fr) {
        #pragma unroll
        for (int fc = 0; fc < 4; ++fc) {
            int fcol = cb + fc * 16 + ln;
            if (fcol < Fvalid) {
                #pragma unroll
                for (int r = 0; r < 4; ++r) {
                    int n = rb + fr * 16 + q * 4 + r;
                    Cp[(size_t)n * KB + fcol] = f2h_sat(acc[fr][fc][r] * SC);
                }
            }
        }
    }
}

// ---------------------------------------------------------------------------
// gA2 (layers 2/3): full A-tile staged once in LDS; both f-tiles computed in
// one block (halves Ah reads + block count). grid (AC, CB), block 256.
__global__ __launch_bounds__(256)
void gA2_mfma(const u16* __restrict__ Agr, const u16* __restrict__ Htr,
              u16* __restrict__ AV, int b0)
{
    __shared__ u16 As[4][128 * 40];   // 40 KB: all 4 k-subtiles of A
    __shared__ u16 Bs[128 * 40];      // 10 KB
    int c = blockIdx.x, bl = blockIdx.y;
    int b = b0 + bl;
    const u16* Ap = Agr + ((size_t)b * AC + c) * (NN * NN);
    u16* Cp0 = AV + (size_t)bl * (NN * KB) + c * 256;

    int t = threadIdx.x;
    int l = t & 63, wid = t >> 6;
    int rb = (wid >> 1) * 64, cb = (wid & 1) * 64;
    int ln = l & 15, q = l >> 4;

    // stage full A 128x128
    #pragma unroll
    for (int i = 0; i < 8; ++i) {
        int id = t + i * 256;          // 0..2047 uint4
        int row = id >> 4, kq = id & 15;
        int kt = kq >> 2, qh = kq & 3;
        *(uint4*)&As[kt][row * 40 + qh * 8] =
            *(const uint4*)(Ap + (size_t)row * NN + kt * 32 + qh * 8);
    }

    for (int ft = 0; ft < 2; ++ft) {
        const u16* Bp = Htr + (size_t)b * (HID * NN) + ft * (128 * 128);
        f32x4 acc[4][4] = {};
        for (int kt = 0; kt < 4; ++kt) {
            __syncthreads();   // A staged (1st iter) / previous mfma done reading Bs
            #pragma unroll
            for (int i = 0; i < 2; ++i) {
                int id = t + i * 256;
                int row = id >> 2, qh = id & 3;
                *(uint4*)&Bs[row * 40 + qh * 8] =
                    *(const uint4*)(Bp + (size_t)row * 128 + kt * 32 + qh * 8);
            }
            __syncthreads();
            f16x8 af[4], bfr[4];
            #pragma unroll
            for (int fr = 0; fr < 4; ++fr)
                af[fr] = *(const f16x8*)&As[kt][(rb + fr * 16 + ln) * 40 + q * 8];
            #pragma unroll
            for (int fc = 0; fc < 4; ++fc)
                bfr[fc] = *(const f16x8*)&Bs[(cb + fc * 16 + ln) * 40 + q * 8];
            #pragma unroll
            for (int fr = 0; fr < 4; ++fr)
                #pragma unroll
                for (int fc = 0; fc < 4; ++fc)
                    acc[fr][fc] = __builtin_amdgcn_mfma_f32_16x16x32_f16(
                        af[fr], bfr[fc], acc[fr][fc], 0, 0, 0);
        }
        #pragma unroll
        for (int fr = 0; fr < 4; ++fr)
            #pragma unroll
            for (int fc = 0; fc < 4; ++fc) {
                int fcol = ft * 128 + cb + fc * 16 + ln;
                #pragma unroll
                for (int r = 0; r < 4; ++r) {
                    int n = rb + fr * 16 + q * 4 + r;
                    Cp0[(size_t)n * KB + fcol] = f2h_sat(acc[fr][fc][r] * SC);
                }
            }
    }
}

// ---------------------------------------------------------------------------
// gB (MFMA): val[n][o] = relu( 16 * sum_k AVs[bl][n][k] * Wt[o][k] + bias[o] )
// mode 0 (layers 1-2): write TRANSPOSED fp16 to Ht [b][256][128].
// mode 1 (layer 3): write fp16 scaled 1/16 to H3h [b][n][256].
__global__ __launch_bounds__(256)
void gB_mfma(const u16* __restrict__ AV, const u16* __restrict__ Wt,
             const float* __restrict__ bias, u16* __restrict__ Hout,
             int b0, int kTiles, int Ks, int mode)
{
    __shared__ u16 As[128 * 40];
    __shared__ u16 Bs[128 * 40];
    __shared__ u16 sLT[128][136];
    int ot = blockIdx.x, bl = blockIdx.y;
    int b = b0 + bl;
    const u16* Ap = AV + (size_t)bl * (NN * KB);
    const u16* Bp = Wt + (size_t)ot * 128 * Ks;

    int t = threadIdx.x;
    int l = t & 63, wid = t >> 6;
    int rb = (wid >> 1) * 64, cb = (wid & 1) * 64;
    int ln = l & 15, q = l >> 4;

    f32x4 acc[4][4] = {};

    for (int kt = 0; kt < kTiles; ++kt) {
        #pragma unroll
        for (int i = 0; i < 2; ++i) {
            int id = t + i * 256;
            int row = id >> 2, qh = id & 3;
            *(uint4*)&As[row * 40 + qh * 8] =
                *(const uint4*)(Ap + (size_t)row * KB + kt * 32 + qh * 8);
            *(uint4*)&Bs[row * 40 + qh * 8] =
                *(const uint4*)(Bp + (size_t)row * Ks + kt * 32 + qh * 8);
        }
        __syncthreads();
        f16x8 af[4], bfr[4];
        #pragma unroll
        for (int fr = 0; fr < 4; ++fr)
            af[fr] = *(const f16x8*)&As[(rb + fr * 16 + ln) * 40 + q * 8];
        #pragma unroll
        for (int fc = 0; fc < 4; ++fc)
            bfr[fc] = *(const f16x8*)&Bs[(cb + fc * 16 + ln) * 40 + q * 8];
        #pragma unroll
        for (int fr = 0; fr < 4; ++fr)
            #pragma unroll
            for (int fc = 0; fc < 4; ++fc)
                acc[fr][fc] = __builtin_amdgcn_mfma_f32_16x16x32_f16(
                    af[fr], bfr[fc], acc[fr][fc], 0, 0, 0);
        __syncthreads();
    }
    if (mode == 0) {
        #pragma unroll
        for (int fr = 0; fr < 4; ++fr)
            #pragma unroll
            for (int fc = 0; fc < 4; ++fc) {
                int oc = cb + fc * 16 + ln;
                float bv = bias[ot * 128 + oc];
                #pragma unroll
                for (int r = 0; r < 4; ++r) {
                    int n = rb + fr * 16 + q * 4 + r;
                    sLT[oc][n] = f2h_sat(fmaxf(acc[fr][fc][r] * USC + bv, 0.f));
                }
            }
        __syncthreads();
        int row = t >> 1, half = t & 1;
        u16* dst = Hout + ((size_t)b * HID + ot * 128 + row) * NN + half * 64;
        #pragma unroll
        for (int j = 0; j < 8; ++j)
            *(uint4*)(dst + j * 8) = *(const uint4*)&sLT[row][half * 64 + j * 8];
    } else {
        #pragma unroll
        for (int fr = 0; fr < 4; ++fr)
            #pragma unroll
            for (int fc = 0; fc < 4; ++fc) {
                int oc = cb + fc * 16 + ln;
                float bv = bias[ot * 128 + oc];
                #pragma unroll
                for (int r = 0; r < 4; ++r) {
                    int n = rb + fr * 16 + q * 4 + r;
                    float val = fmaxf(acc[fr][fc][r] * USC + bv, 0.f);
                    Hout[((size_t)b * NN + n) * HID + ot * 128 + oc] = f2h_sat(val * SC);
                }
            }
    }
}

// ---------------------------------------------------------------------------
// Masked multi-head attention pooling. H3h fp16 scaled 1/16; single-pass.
__global__ __launch_bounds__(256)
void pool_kernel(const u16* __restrict__ H3h,
                 const float* __restrict__ attW,
                 const int* __restrict__ msz,
                 float* __restrict__ pooled)
{
    int b = blockIdx.x, t = threadIdx.x;
    __shared__ u16  sTh[128][264];
    __shared__ float sW[HID * NHEAD];
    __shared__ float sS[NN * NHEAD];
    __shared__ float sP[16][NHEAD][2];
    for (int i = t; i < HID * NHEAD; i += 256) sW[i] = attW[i];
    const u16* Hb = H3h + (size_t)b * NN * HID;
    for (int i = t; i < 128 * 32; i += 256) {
        int row = i >> 5, fq = (i & 31) * 8;
        *(uint4*)&sTh[row][fq] = *(const uint4*)(Hb + (size_t)row * HID + fq);
    }
    __syncthreads();
    for (int n0 = 0; n0 < NN; n0 += 16) {
        int nl = t >> 4, h = (t >> 1) & 7, fh = t & 1;
        float s = 0.f;
        for (int f = fh * 128; f < fh * 128 + 128; ++f)
            s += h2f(sTh[n0 + nl][f]) * sW[f * NHEAD + h];
        sP[nl][h][fh] = s;
        __syncthreads();
        if (t < 128) {
            int n2 = t >> 3, h2 = t & 7;
            sS[(n0 + n2) * NHEAD + h2] = USC * (sP[n2][h2][0] + sP[n2][h2][1]);
        }
        __syncthreads();
    }
    int ms = msz[b];
    int h = t >> 5, ln = t & 31;
    float mx = -1e9f;
    for (int n = ln; n < NN; n += 32) {
        float s = (n < ms) ? sS[n * NHEAD + h] : -1e9f;
        mx = fmaxf(mx, s);
    }
    #pragma unroll
    for (int off = 16; off; off >>= 1) mx = fmaxf(mx, __shfl_xor(mx, off, 32));
    float sum = 0.f;
    for (int n = ln; n < NN; n += 32) {
        float s = (n < ms) ? sS[n * NHEAD + h] : -1e9f;
        sum += expf(s - mx);
    }
    #pragma unroll
    for (int off = 16; off; off >>= 1) sum += __shfl_xor(sum, off, 32);
    float inv = 1.f / sum;
    for (int n = ln; n < NN; n += 32) {
        float s = (n < ms) ? sS[n * NHEAD + h] : -1e9f;
        sS[n * NHEAD + h] = expf(s - mx) * inv;
    }
    __syncthreads();
    float accp[NHEAD] = {};
    for (int n = 0; n < NN; ++n) {
        float hv = h2f(sTh[n][t]);
        #pragma unroll
        for (int hh = 0; hh < NHEAD; ++hh) accp[hh] += sS[n * NHEAD + hh] * hv;
    }
    #pragma unroll
    for (int hh = 0; hh < NHEAD; ++hh)
        pooled[(size_t)b * (HID * NHEAD) + hh * HID + t] = USC * accp[hh];
}

// ---------------------------------------------------------------------------
// Readout, k-split
__global__ __launch_bounds__(128)
void readout_part(const float* __restrict__ pooled,
                  const float* __restrict__ roW,
                  float* __restrict__ Rp)
{
    int b = blockIdx.x, s = blockIdx.y, t = threadIdx.x;
    __shared__ float sx[256];
    const float* sp = pooled + (size_t)b * (HID * NHEAD) + s * 256;
    sx[t] = sp[t];
    sx[t + 128] = sp[t + 128];
    __syncthreads();
    float acc = 0.f;
    const float* W = roW + (size_t)(s * 256) * DIM + t;
    for (int k = 0; k < 256; ++k) acc += sx[k] * W[(size_t)k * DIM];
    Rp[((size_t)s * BB + b) * DIM + t] = acc;
}

__global__ __launch_bounds__(128)
void readout_merge(const float* __restrict__ Rp,
                   const float* __restrict__ rob,
                   float* __restrict__ Vr, u16* __restrict__ Vrh)
{
    int b = blockIdx.x, t = threadIdx.x;
    float a = rob[t];
    #pragma unroll
    for (int s = 0; s < 8; ++s) a += Rp[((size_t)s * BB + b) * DIM + t];
    float v = fmaxf(a, 0.f);
    Vr [(size_t)b * DIM + t] = v;
    Vrh[(size_t)b * DIM + t] = f2h_sat(v * SC);   // scaled 1/16
}

// ---------------------------------------------------------------------------
// atth (MFMA): h_br = relu(X_br @ W_br + b_br) -> fp16 out. grid (2 mt, 2 br).
__global__ __launch_bounds__(256)
void atth_mfma(const u16* __restrict__ FP2h, const u16* __restrict__ VRh,
               const u16* __restrict__ mWt12,
               const float* __restrict__ mfpb, const float* __restrict__ mvb,
               u16* __restrict__ h1h, u16* __restrict__ h2h)
{
    __shared__ u16 As[128 * 40];
    __shared__ u16 Bs[128 * 40];
    int mt = blockIdx.x, br = blockIdx.y;
    const u16* Ap = (br ? VRh : FP2h) + (size_t)(mt * 128) * 128;
    const u16* Bp = mWt12 + (size_t)br * 128 * 128;
    const float* bias = br ? mvb : mfpb;
    float unsc = br ? USC : 1.f;
    u16* out = br ? h2h : h1h;

    int t = threadIdx.x;
    int l = t & 63, wid = t >> 6;
    int rb = (wid >> 1) * 64, cb = (wid & 1) * 64;
    int ln = l & 15, q = l >> 4;

    f32x4 acc[4][4] = {};

    for (int kt = 0; kt < 4; ++kt) {
        #pragma unroll
        for (int i = 0; i < 2; ++i) {
            int id = t + i * 256;
            int row = id >> 2, qh = id & 3;
            *(uint4*)&As[row * 40 + qh * 8] =
                *(const uint4*)(Ap + (size_t)row * 128 + kt * 32 + qh * 8);
            *(uint4*)&Bs[row * 40 + qh * 8] =
                *(const uint4*)(Bp + (size_t)row * 128 + kt * 32 + qh * 8);
        }
        __syncthreads();
        f16x8 af[4], bfr[4];
        #pragma unroll
        for (int fr = 0; fr < 4; ++fr)
            af[fr] = *(const f16x8*)&As[(rb + fr * 16 + ln) * 40 + q * 8];
        #pragma unroll
        for (int fc = 0; fc < 4; ++fc)
            bfr[fc] = *(const f16x8*)&Bs[(cb + fc * 16 + ln) * 40 + q * 8];
        #pragma unroll
        for (int fr = 0; fr < 4; ++fr)
            #pragma unroll
            for (int fc = 0; fc < 4; ++fc)
                acc[fr][fc] = __builtin_amdgcn_mfma_f32_16x16x32_f16(
                    af[fr], bfr[fc], acc[fr][fc], 0, 0, 0);
        __syncthreads();
    }
    #pragma unroll
    for (int fr = 0; fr < 4; ++fr)
        #pragma unroll
        for (int fc = 0; fc < 4; ++fc) {
            int d = cb + fc * 16 + ln;
            float bv = bias[d];
            #pragma unroll
            for (int r = 0; r < 4; ++r) {
                int m = rb + fr * 16 + q * 4 + r;
                out[(size_t)(mt * 128 + m) * 128 + d] =
                    f2h_sat(fmaxf(acc[fr][fc][r] * unsc + bv, 0.f));
            }
        }
}

// ---------------------------------------------------------------------------
// Cross-attn partial scan: fdot2 dot products, packed-fp16 max, fast tanh.
// grid (B, 8), block 256 (16 groups of 16 lanes; lane owns 8 dims).
__global__ __launch_bounds__(256)
void cross_part_kernel(const int* __restrict__ seq,
                       const u16* __restrict__ HS12,
                       const u16* __restrict__ h1h, const u16* __restrict__ h2h,
                       float* __restrict__ Pc)   // [8][B][2][128]
{
    int b = blockIdx.x, s = blockIdx.y, t = threadIdx.x;
    int g = t >> 4, gl = t & 15;
    int d0 = gl * 8;
    f16x8 h1 = *(const f16x8*)(h1h + (size_t)b * DIM + d0);
    f16x8 h2 = *(const f16x8*)(h2h + (size_t)b * DIM + d0);
    const h2v* h1p = (const h2v*)&h1;
    const h2v* h2p = (const h2v*)&h2;
    h2v m1[4], m2[4];
    _Float16 NEGBIG = (_Float16)(-65504.f);
    #pragma unroll
    for (int k = 0; k < 4; ++k) { m1[k] = (h2v){NEGBIG, NEGBIG}; m2[k] = (h2v){NEGBIG, NEGBIG}; }
    const int* sq = seq + (size_t)b * LL + s * 256;
    for (int it = 0; it < 16; ++it) {
        int tok = sq[g + 16 * it];
        const u16* r12 = HS12 + (size_t)tok * 256 + d0;
        f16x8 va = *(const f16x8*)(r12);
        f16x8 vb = *(const f16x8*)(r12 + 128);
        const h2v* vap = (const h2v*)&va;
        const h2v* vbp = (const h2v*)&vb;
        float p1 = 0.f, p2 = 0.f;
        #pragma unroll
        for (int k = 0; k < 4; ++k) {
            p1 = __builtin_amdgcn_fdot2(vap[k], h1p[k], p1, false);
            p2 = __builtin_amdgcn_fdot2(vbp[k], h2p[k], p2, false);
        }
        #pragma unroll
        for (int off = 8; off; off >>= 1) {
            p1 += __shfl_xor(p1, off);
            p2 += __shfl_xor(p2, off);
        }
        // tanh(x) = 1 - 2/(e^{2x}+1); safe at both extremes (inf -> 1, 0 -> -1)
        float w1 = 1.f - 2.f / (__expf(2.f * p1) + 1.f);
        float w2 = 1.f - 2.f / (__expf(2.f * p2) + 1.f);
        _Float16 w1s = (_Float16)w1, w2s = (_Float16)w2;
        h2v w1p = (h2v){w1s, w1s}, w2p = (h2v){w2s, w2s};
        #pragma unroll
        for (int k = 0; k < 4; ++k) {
            h2v pr1 = w1p * vap[k];
            h2v pr2 = w2p * vbp[k];
            m1[k] = (h2v){ m1[k][0] > pr1[0] ? m1[k][0] : pr1[0],
                           m1[k][1] > pr1[1] ? m1[k][1] : pr1[1] };
            m2[k] = (h2v){ m2[k][0] > pr2[0] ? m2[k][0] : pr2[0],
                           m2[k][1] > pr2[1] ? m2[k][1] : pr2[1] };
        }
    }
    __shared__ float red[16][2][DIM];
    #pragma unroll
    for (int k = 0; k < 4; ++k) {
        red[g][0][d0 + 2 * k]     = (float)m1[k][0];
        red[g][0][d0 + 2 * k + 1] = (float)m1[k][1];
        red[g][1][d0 + 2 * k]     = (float)m2[k][0];
        red[g][1][d0 + 2 * k + 1] = (float)m2[k][1];
    }
    __syncthreads();
    int tb = t >> 7, d = t & 127;
    float mx = red[0][tb][d];
    #pragma unroll
    for (int gg = 1; gg < 16; ++gg) mx = fmaxf(mx, red[gg][tb][d]);
    Pc[(((size_t)s * BB + b) * 2 + tb) * DIM + d] = mx;
}

// ---------------------------------------------------------------------------
// prepX: build MLP input (merges cross_merge). Xh [br][256][256], scaled 1/16.
__global__ __launch_bounds__(256)
void prepX_kernel(const float* __restrict__ FP2, const float* __restrict__ VR,
                  const float* __restrict__ Pc, u16* __restrict__ Xh)
{
    int b = blockIdx.x, br = blockIdx.y, t = threadIdx.x;
    float v;
    if (t < 128) {
        v = (br ? VR : FP2)[(size_t)b * 128 + t];
    } else {
        int d = t - 128;
        float m = -INFINITY;
        #pragma unroll
        for (int s = 0; s < 8; ++s)
            m = fmaxf(m, Pc[(((size_t)s * BB + b) * 2 + br) * DIM + d]);
        v = m;
    }
    Xh[((size_t)br * BB + b) * 256 + t] = f2h_sat(v * SC);
}

// one MLP layer: Y = relu(X@W+b), in/out scaled 1/16. grid (2 mt, 2 ot, 2 br).
__global__ __launch_bounds__(256)
void mlpL_mfma(const u16* __restrict__ X, const u16* __restrict__ Wmlp,
               const float* __restrict__ m1b, const float* __restrict__ m2b,
               int Lr, u16* __restrict__ Y)
{
    __shared__ u16 As[128 * 40];
    __shared__ u16 Bs[128 * 40];
    int mt = blockIdx.x, ot = blockIdx.y, br = blockIdx.z;
    const u16* Ap = X + ((size_t)br * BB + mt * 128) * 256;
    const u16* Bp = Wmlp + (((size_t)(br * 3 + Lr)) * 256 + ot * 128) * 256;
    const float* bias = (br ? m2b : m1b) + (size_t)Lr * 256 + ot * 128;

    int t = threadIdx.x;
    int l = t & 63, wid = t >> 6;
    int rb = (wid >> 1) * 64, cb = (wid & 1) * 64;
    int ln = l & 15, q = l >> 4;

    f32x4 acc[4][4] = {};

    for (int kt = 0; kt < 8; ++kt) {
        #pragma unroll
        for (int i = 0; i < 2; ++i) {
            int id = t + i * 256;
            int row = id >> 2, qh = id & 3;
            *(uint4*)&As[row * 40 + qh * 8] =
                *(const uint4*)(Ap + (size_t)row * 256 + kt * 32 + qh * 8);
            *(uint4*)&Bs[row * 40 + qh * 8] =
                *(const uint4*)(Bp + (size_t)row * 256 + kt * 32 + qh * 8);
        }
        __syncthreads();
        f16x8 af[4], bfr[4];
        #pragma unroll
        for (int fr = 0; fr < 4; ++fr)
            af[fr] = *(const f16x8*)&As[(rb + fr * 16 + ln) * 40 + q * 8];
        #pragma unroll
        for (int fc = 0; fc < 4; ++fc)
            bfr[fc] = *(const f16x8*)&Bs[(cb + fc * 16 + ln) * 40 + q * 8];
        #pragma unroll
        for (int fr = 0; fr < 4; ++fr)
            #pragma unroll
            for (int fc = 0; fc < 4; ++fc)
                acc[fr][fc] = __builtin_amdgcn_mfma_f32_16x16x32_f16(
                    af[fr], bfr[fc], acc[fr][fc], 0, 0, 0);
        __syncthreads();
    }
    #pragma unroll
    for (int fr = 0; fr < 4; ++fr)
        #pragma unroll
        for (int fc = 0; fc < 4; ++fc) {
            int oc = cb + fc * 16 + ln;
            float bv = bias[oc] * SC;
            #pragma unroll
            for (int r = 0; r < 4; ++r) {
                int m = rb + fr * 16 + q * 4 + r;
                Y[((size_t)br * BB + (mt * 128 + m)) * 256 + ot * 128 + oc] =
                    f2h_sat(fmaxf(acc[fr][fc][r] + bv, 0.f));
            }
        }
}

// head + outputs. grid (BB), block 256.
__global__ __launch_bounds__(256)
void mlp_out_kernel(const u16* __restrict__ Y,
                    const float* __restrict__ o1W, const float* __restrict__ o1b,
                    const float* __restrict__ o2W, const float* __restrict__ o2b,
                    const int* __restrict__ label,
                    float* __restrict__ dout)
{
    int b = blockIdx.x, t = threadIdx.x;
    __shared__ float pl[2][128];
    const u16* y1 = Y + (size_t)b * 256;
    const u16* y2 = Y + ((size_t)BB + b) * 256;
    int j = t & 1, k2 = t >> 1;
    float p = USC * (h2f(y1[k2])       * o1W[k2 * 2 + j]
                   + h2f(y1[k2 + 128]) * o1W[(k2 + 128) * 2 + j]
                   + h2f(y2[k2])       * o2W[k2 * 2 + j]
                   + h2f(y2[k2 + 128]) * o2W[(k2 + 128) * 2 + j]);
    pl[j][k2] = p;
    __syncthreads();
    for (int s = 64; s > 0; s >>= 1) {
        if (k2 < s) pl[j][k2] += pl[j][k2 + s];
        __syncthreads();
    }
    if (t == 0) {
        float l0 = pl[0][0] + o1b[0] + o2b[0];
        float l1 = pl[1][0] + o1b[1] + o2b[1];
        dout[(size_t)b * 2 + 0] = l0;
        dout[(size_t)b * 2 + 1] = l1;
        dout[2 * BB + b] = (float)label[b];
        dout[3 * BB + b] = (float)((l1 > l0) ? 1 : 0);
        float mx = fmaxf(l0, l1);
        float e0 = expf(l0 - mx), e1 = expf(l1 - mx);
        dout[4 * BB + b] = e1 / (e0 + e1);
    }
}

// ---------------------------------------------------------------------------
extern "C" void kernel_launch(void* const* d_in, const int* in_sizes, int n_in,
                              void* d_out, int out_size, void* d_ws, size_t ws_size,
                              hipStream_t stream)
{
    const float* V    = (const float*)d_in[0];
    const float* A    = (const float*)d_in[1];
    const float* fp   = (const float*)d_in[2];
    const int*   msz  = (const int*)  d_in[3];
    const int*   seq  = (const int*)  d_in[4];
    const int*   lab  = (const int*)  d_in[5];
    const float* gcW1 = (const float*)d_in[6];  const float* gcb1 = (const float*)d_in[7];
    const float* gcW2 = (const float*)d_in[8];  const float* gcb2 = (const float*)d_in[9];
    const float* gcW3 = (const float*)d_in[10]; const float* gcb3 = (const float*)d_in[11];
    const float* fpW1 = (const float*)d_in[12]; const float* fpb1 = (const float*)d_in[13];
    const float* fpW2 = (const float*)d_in[14]; const float* fpb2 = (const float*)d_in[15];
    const float* attW = (const float*)d_in[16];
    const float* roW  = (const float*)d_in[17]; const float* rob  = (const float*)d_in[18];
    const float* emb  = (const float*)d_in[19];
    const float* mfpW = (const float*)d_in[20]; const float* mfpb = (const float*)d_in[21];
    const float* pfpW = (const float*)d_in[22]; const float* pfpb = (const float*)d_in[23];
    const float* mvW  = (const float*)d_in[24]; const float* mvb  = (const float*)d_in[25];
    const float* pvW  = (const float*)d_in[26]; const float* pvb  = (const float*)d_in[27];
    const float* m1W  = (const float*)d_in[28]; const float* m1b  = (const float*)d_in[29];
    const float* m2W  = (const float*)d_in[30]; const float* m2b  = (const float*)d_in[31];
    const float* o1W  = (const float*)d_in[32]; const float* o1b  = (const float*)d_in[33];
    const float* o2W  = (const float*)d_in[34]; const float* o2b  = (const float*)d_in[35];
    float* dout = (float*)d_out;

    // workspace layout
    char* ws = (char*)d_ws;
    size_t off = 0;
    auto alloc = [&](size_t bytes) -> char* {
        char* p = ws + off;
        off += (bytes + 255) & ~(size_t)255;
        return p;
    };
    u16*   Ah    = (u16*)  alloc((size_t)BB * AC * NN * NN * 2);   // 25.2 MB
    u16*   Vt    = (u16*)  alloc((size_t)BB * 80 * 128 * 2);       // 5.24 MB
    u16*   Wt1   = (u16*)  alloc((size_t)256 * 256 * 2);
    u16*   Wt2   = (u16*)  alloc((size_t)256 * KB * 2);
    u16*   Wt3   = (u16*)  alloc((size_t)256 * KB * 2);
    u16*   Ht    = (u16*)  alloc((size_t)BB * HID * NN * 2);       // 16.8 MB
    u16*   H3h   = (u16*)  alloc((size_t)BB * NN * HID * 2);       // 16.8 MB (fp16, 1/16)
    u16*   fph   = (u16*)  alloc((size_t)BB * FPDP * 2);
    u16*   W1t   = (u16*)  alloc((size_t)DIM * FPDP * 2);
    u16*   W2t   = (u16*)  alloc((size_t)DIM * DIM * 2);
    u16*   FP1h  = (u16*)  alloc((size_t)BB * DIM * 2);
    float* FP2   = (float*)alloc((size_t)BB * DIM * 4);
    u16*   FP2h  = (u16*)  alloc((size_t)BB * DIM * 2);
    u16*   pWt12 = (u16*)  alloc((size_t)2 * 128 * 128 * 2);
    u16*   mWt12 = (u16*)  alloc((size_t)2 * 128 * 128 * 2);
    u16*   HS12  = (u16*)  alloc((size_t)NWP * 256 * 2);           // 4.45 MB
    float* PO    = (float*)alloc((size_t)BB * HID * NHEAD * 4);
    float* VR    = (float*)alloc((size_t)BB * DIM * 4);
    u16*   VRh   = (u16*)  alloc((size_t)BB * DIM * 2);
    u16*   h1h   = (u16*)  alloc((size_t)BB * DIM * 2);
    u16*   h2h   = (u16*)  alloc((size_t)BB * DIM * 2);
    float* Pc    = (float*)alloc((size_t)8 * BB * 2 * DIM * 4);
    float* Rp    = (float*)alloc((size_t)8 * BB * DIM * 4);
    u16*   Wmlp  = (u16*)  alloc((size_t)2 * 3 * 256 * 256 * 2);   // 786 KB
    u16*   Xa    = (u16*)  alloc((size_t)2 * BB * 256 * 2);        // 256 KB
    u16*   Xb    = (u16*)  alloc((size_t)2 * BB * 256 * 2);
    size_t fixedBytes = off;

    // AV tier (fp16, per-b 128*768*2 = 196608 B)
    int CB = 8;
    size_t perB = (size_t)NN * KB * 2;
    {
        const int tiers[] = {256, 128, 64, 32, 16, 8, 4, 2, 1};
        for (int i = 0; i < 9; ++i)
            if (fixedBytes + (size_t)tiers[i] * perB <= ws_size) { CB = tiers[i]; break; }
    }
    u16* AV = (u16*)(ws + fixedBytes);

    // prep + independent front-end
    prepA_kernel<<<BB * AC, 256, 0, stream>>>(A, Ah);
    prepVt_kernel<<<BB, 256, 0, stream>>>(V, Vt);
    prepW_kernel<<<dim3(256, 3), 256, 0, stream>>>(gcW1, gcW2, gcW3, Wt1, Wt2, Wt3);
    prepFp_kernel<<<BB, 256, 0, stream>>>(fp, fph);
    prepFpW_kernel<<<dim3(128, 2), 256, 0, stream>>>(fpW1, fpW2, W1t, W2t);
    prepCrossW_kernel<<<dim3(128, 4), 128, 0, stream>>>(pfpW, pvW, mfpW, mvW, pWt12, mWt12);
    prepMlpW_kernel<<<dim3(256, 3, 2), 256, 0, stream>>>(m1W, m2W, Wmlp);
    fp1_mfma<<<2, 256, 0, stream>>>(fph, W1t, fpb1, FP1h);
    fp2_mfma<<<2, 256, 0, stream>>>(FP1h, W2t, fpb2, FP2, FP2h);
    hs12_mfma<<<dim3(NWP / 128, 2), 256, 0, stream>>>(emb, pWt12, pfpb, pvb, HS12);

    // GConv layer 1 (F=75 padded to 80; gB writes Ht directly, transposed)
    for (int b0 = 0; b0 < BB; b0 += CB) {
        gA_mfma<<<dim3(1, AC, CB), 256, 0, stream>>>(Ah, Vt, AV, b0, 80 * 128, 80, 80);
        gB_mfma<<<dim3(2, CB), 256, 0, stream>>>(AV, Wt1, gcb1, Ht, b0, 8, 256, 0);
    }
    // layer 2 (gA2: A staged once, both f-tiles per block)
    for (int b0 = 0; b0 < BB; b0 += CB) {
        gA2_mfma<<<dim3(AC, CB), 256, 0, stream>>>(Ah, Ht, AV, b0);
        gB_mfma<<<dim3(2, CB), 256, 0, stream>>>(AV, Wt2, gcb2, Ht, b0, 24, KB, 0);
    }
    // layer 3 -> H3h fp16 scaled 1/16
    for (int b0 = 0; b0 < BB; b0 += CB) {
        gA2_mfma<<<dim3(AC, CB), 256, 0, stream>>>(Ah, Ht, AV, b0);
        gB_mfma<<<dim3(2, CB), 256, 0, stream>>>(AV, Wt3, gcb3, H3h, b0, 24, KB, 1);
    }

    pool_kernel<<<BB, 256, 0, stream>>>(H3h, attW, msz, PO);
    readout_part<<<dim3(BB, 8), 128, 0, stream>>>(PO, roW, Rp);
    readout_merge<<<BB, 128, 0, stream>>>(Rp, rob, VR, VRh);
    atth_mfma<<<dim3(2, 2), 256, 0, stream>>>(FP2h, VRh, mWt12, mfpb, mvb, h1h, h2h);
    cross_part_kernel<<<dim3(BB, 8), 256, 0, stream>>>(seq, HS12, h1h, h2h, Pc);
    prepX_kernel<<<dim3(BB, 2), 256, 0, stream>>>(FP2, VR, Pc, Xa);
    mlpL_mfma<<<dim3(2, 2, 2), 256, 0, stream>>>(Xa, Wmlp, m1b, m2b, 0, Xb);
    mlpL_mfma<<<dim3(2, 2, 2), 256, 0, stream>>>(Xb, Wmlp, m1b, m2b, 1, Xa);
    mlpL_mfma<<<dim3(2, 2, 2), 256, 0, stream>>>(Xa, Wmlp, m1b, m2b, 2, Xb);
    mlp_out_kernel<<<BB, 256, 0, stream>>>(Xb, o1W, o1b, o2W, o2b, lab, dout);
}